// Round 1
// baseline (2123.361 us; speedup 1.0000x reference)
//
#include <hip/hip_runtime.h>
#include <math.h>

#define BB 4
#define NC 4096
#define NT 1024
#define NN (NC + NT)      // 5120
#define NODES (BB * NN)   // 20480
#define DD 64
#define KNN 10
#define NBLK 6
#define BIGF 3.0e38f

__device__ __forceinline__ float gelu_f(float x) {
    const float c0 = 0.7978845608028654f;
    float x3 = x * x * x;
    return 0.5f * x * (1.0f + tanhf(c0 * (x + 0.044715f * x3)));
}

__device__ __forceinline__ float wave_sum(float v) {
#pragma unroll
    for (int off = 32; off > 0; off >>= 1) v += __shfl_xor(v, off, 64);
    return v;
}

// ---------------- embed: 11 -> 256 -> 128 -> 64 + LN ----------------
__global__ __launch_bounds__(256) void k_embed(
    const float* __restrict__ s_ctx, const float* __restrict__ f_ctx,
    const float* __restrict__ s_test, const float* __restrict__ emb_obs,
    const float* __restrict__ W0, const float* __restrict__ b0,
    const float* __restrict__ W1, const float* __restrict__ b1,
    const float* __restrict__ W2, const float* __restrict__ b2,
    const float* __restrict__ g, const float* __restrict__ bta,
    float* __restrict__ nodes)
{
    int node = blockIdx.x;
    int b = node / NN, n = node % NN;
    int t = threadIdx.x;
    __shared__ float x[16];
    __shared__ float h0[256];
    __shared__ float h1[128];
    __shared__ float h2[64];
    if (t < 11) {
        float v;
        if (n < NC) {
            if (t < 4)      v = emb_obs[4 + t];
            else if (t < 7) v = s_ctx[(b * NC + n) * 3 + (t - 4)];
            else            v = f_ctx[(b * NC + n) * 4 + (t - 7)];
        } else {
            int nt = n - NC;
            if (t < 4)      v = emb_obs[t];
            else if (t < 7) v = s_test[(b * NT + nt) * 3 + (t - 4)];
            else            v = 0.0f;
        }
        x[t] = v;
    }
    __syncthreads();
    {   // 11 -> 256
        float acc = b0[t];
#pragma unroll
        for (int d = 0; d < 11; ++d) acc += x[d] * W0[d * 256 + t];
        h0[t] = gelu_f(acc);
    }
    __syncthreads();
    if (t < 128) {  // 256 -> 128
        float acc = b1[t];
        for (int d = 0; d < 256; ++d) acc += h0[d] * W1[d * 128 + t];
        h1[t] = gelu_f(acc);
    }
    __syncthreads();
    if (t < 64) {   // 128 -> 64
        float acc = b2[t];
        for (int d = 0; d < 128; ++d) acc += h1[d] * W2[d * 64 + t];
        h2[t] = acc;
    }
    __syncthreads();
    if (t < 64) {   // LN (threads 0..63 = full wave 0)
        float v = h2[t];
        float m = wave_sum(v) * (1.0f / 64.0f);
        float dv = v - m;
        float var = wave_sum(dv * dv) * (1.0f / 64.0f);
        nodes[(size_t)node * DD + t] = dv * rsqrtf(var + 1e-6f) * g[t] + bta[t];
    }
}

// ---------------- top-K: one wave per receiver ----------------
__global__ __launch_bounds__(256) void k_topk(
    const float* __restrict__ s_ctx, const float* __restrict__ s_test,
    const int* __restrict__ valid_lens,
    float* __restrict__ dists, int* __restrict__ senders, float* __restrict__ wout)
{
    __shared__ float cd[4 * 64 * KNN];
    __shared__ int   ci[4 * 64 * KNN];
    int wave = threadIdx.x >> 6;
    int lane = threadIdx.x & 63;
    int r = blockIdx.x * 4 + wave;
    if (r >= NODES) return;
    int b = r / NN, n = r % NN;
    float px, py, pz;
    if (n < NC) {
        const float* p = &s_ctx[(size_t)(b * NC + n) * 3];
        px = p[0]; py = p[1]; pz = p[2];
    } else {
        const float* p = &s_test[(size_t)(b * NT + (n - NC)) * 3];
        px = p[0]; py = p[1]; pz = p[2];
    }
    int vl = valid_lens[b];
    float best[KNN];
    int bidx[KNN];
#pragma unroll
    for (int k = 0; k < KNN; ++k) { best[k] = BIGF; bidx[k] = 0; }
    const float* sc = &s_ctx[(size_t)b * NC * 3];
    for (int j = lane; j < vl; j += 64) {
        float dx = px - sc[j * 3 + 0];
        float dy = py - sc[j * 3 + 1];
        float dz = pz - sc[j * 3 + 2];
        float d2 = dx * dx + dy * dy + dz * dz;
        if (d2 < best[KNN - 1]) {
            // fully-unrolled sorted insert (static indexing only)
#pragma unroll
            for (int k = KNN - 1; k >= 0; --k) {
                float prev = (k > 0) ? best[k - 1] : -1.0f;
                int previ = (k > 0) ? bidx[k - 1] : 0;
                if (prev > d2)         { best[k] = prev; bidx[k] = previ; }
                else if (best[k] > d2) { best[k] = d2;   bidx[k] = j; }
            }
        }
    }
    // dump local lists to LDS (each lane reads back only its own slots)
    int base = (wave * 64 + lane) * KNN;
#pragma unroll
    for (int k = 0; k < KNN; ++k) { cd[base + k] = best[k]; ci[base + k] = bidx[k]; }
    int head = 0;
    float myd = 0.0f; int myidx = 0;
#pragma unroll
    for (int rr = 0; rr < KNN; ++rr) {
        float v = cd[base + head];
        int vi = ci[base + head];
        float mv = v;
#pragma unroll
        for (int off = 32; off > 0; off >>= 1) mv = fminf(mv, __shfl_xor(mv, off, 64));
        unsigned long long ball = __ballot(v == mv);
        int win = __ffsll(ball) - 1;
        int widx = __shfl(vi, win, 64);
        if (lane == win) head++;
        if (lane == rr) { myd = mv; myidx = widx; }
    }
    float d = sqrtf(myd);
    float d0 = __shfl(d, 0, 64);
    float e = (lane < KNN) ? expf(-(d - d0)) : 0.0f;
    float s = wave_sum(e);
    if (lane < KNN) {
        size_t o = (size_t)r * KNN + lane;
        dists[o] = d;
        senders[o] = myidx;
        wout[o] = e / s;
    }
}

// ---------------- one GNN block, one node per workgroup ----------------
__global__ __launch_bounds__(256) void k_block(
    const float* __restrict__ nodes_in, float* __restrict__ nodes_out,
    const float* __restrict__ dists, const int* __restrict__ senders,
    const float* __restrict__ w,
    const float* __restrict__ Wm0, const float* __restrict__ bm0,
    const float* __restrict__ Wm1, const float* __restrict__ bm1,
    const float* __restrict__ Wu0, const float* __restrict__ bu0,
    const float* __restrict__ Wu1, const float* __restrict__ bu1,
    const float* __restrict__ lng, const float* __restrict__ lnb)
{
    int node = blockIdx.x;
    int b = node / NN;
    int t = threadIdx.x;
    __shared__ float sfd[KNN][65];   // sender feats + dist
    __shared__ float hh[KNN][128];
    __shared__ float mm[KNN][64];
    __shared__ float u[128];         // [x | agg]
    __shared__ float h2[128];
    __shared__ float wsh[KNN];
    __shared__ int ssh[KNN];
    size_t nbase = (size_t)node * DD;
    if (t < KNN) {
        size_t eo = (size_t)node * KNN + t;
        ssh[t] = senders[eo];
        sfd[t][64] = dists[eo];
        wsh[t] = w[eo];
    }
    if (t < 64) u[t] = nodes_in[nbase + t];
    __syncthreads();
    for (int o = t; o < KNN * 64; o += 256) {
        int e = o >> 6, dd = o & 63;
        sfd[e][dd] = nodes_in[((size_t)(b * NN + ssh[e])) * DD + dd];
    }
    __syncthreads();
    // message layer 0: 65 -> 128, gelu
    for (int o = t; o < KNN * 128; o += 256) {
        int e = o >> 7, j = o & 127;
        float acc = bm0[j];
#pragma unroll
        for (int d = 0; d < 65; ++d) acc += sfd[e][d] * Wm0[d * 128 + j];
        hh[e][j] = gelu_f(acc);
    }
    __syncthreads();
    // message layer 1: 128 -> 64
    for (int o = t; o < KNN * 64; o += 256) {
        int e = o >> 6, dd = o & 63;
        float acc = bm1[dd];
        for (int d = 0; d < 128; ++d) acc += hh[e][d] * Wm1[d * 64 + dd];
        mm[e][dd] = acc;
    }
    __syncthreads();
    if (t < 64) {   // weighted agg
        float acc = 0.0f;
#pragma unroll
        for (int e = 0; e < KNN; ++e) acc += wsh[e] * mm[e][t];
        u[64 + t] = acc;
    }
    __syncthreads();
    if (t < 128) {  // update layer 0: 128 -> 128, gelu
        float acc = bu0[t];
        for (int d = 0; d < 128; ++d) acc += u[d] * Wu0[d * 128 + t];
        h2[t] = gelu_f(acc);
    }
    __syncthreads();
    if (t < 64) {   // update layer 1 + residual + LN
        float acc = bu1[t];
        for (int d = 0; d < 128; ++d) acc += h2[d] * Wu1[d * 64 + t];
        float y = u[t] + acc;
        float m = wave_sum(y) * (1.0f / 64.0f);
        float dv = y - m;
        float var = wave_sum(dv * dv) * (1.0f / 64.0f);
        nodes_out[nbase + t] = dv * rsqrtf(var + 1e-6f) * lng[t] + lnb[t];
    }
}

// ---------------- head: 64 -> 256 -> 64 -> 2 ----------------
__global__ __launch_bounds__(256) void k_head(
    const float* __restrict__ nodes,
    const float* __restrict__ W0, const float* __restrict__ b0,
    const float* __restrict__ W1, const float* __restrict__ b1,
    const float* __restrict__ W2, const float* __restrict__ b2,
    float* __restrict__ out)
{
    int idx = blockIdx.x;
    int b = idx / NT, n = idx % NT;
    int t = threadIdx.x;
    __shared__ float x[64];
    __shared__ float h0[256];
    __shared__ float h1[64];
    size_t nbase = ((size_t)(b * NN + NC + n)) * DD;
    if (t < 64) x[t] = nodes[nbase + t];
    __syncthreads();
    {
        float acc = b0[t];
#pragma unroll
        for (int d = 0; d < 64; ++d) acc += x[d] * W0[d * 256 + t];
        h0[t] = gelu_f(acc);
    }
    __syncthreads();
    if (t < 64) {
        float acc = b1[t];
        for (int d = 0; d < 256; ++d) acc += h0[d] * W1[d * 64 + t];
        h1[t] = gelu_f(acc);
    }
    __syncthreads();
    if (t < 2) {
        float acc = b2[t];
        for (int d = 0; d < 64; ++d) acc += h1[d] * W2[d * 2 + t];
        if (t == 0) out[b * NT + n] = acc;
        else        out[BB * NT + b * NT + n] = expf(0.5f * acc);
    }
}

extern "C" void kernel_launch(void* const* d_in, const int* in_sizes, int n_in,
                              void* d_out, int out_size, void* d_ws, size_t ws_size,
                              hipStream_t stream)
{
    (void)in_sizes; (void)n_in; (void)out_size; (void)ws_size;
    const float* s_ctx   = (const float*)d_in[0];
    const float* f_ctx   = (const float*)d_in[1];
    const float* s_test  = (const float*)d_in[2];
    const int*   valid   = (const int*)d_in[3];
    const float* emb_obs = (const float*)d_in[4];
    const float* ea_W0   = (const float*)d_in[5];
    const float* ea_b0   = (const float*)d_in[6];
    const float* ea_W1   = (const float*)d_in[7];
    const float* ea_b1   = (const float*)d_in[8];
    const float* ea_W2   = (const float*)d_in[9];
    const float* ea_b2   = (const float*)d_in[10];
    const float* ln_g    = (const float*)d_in[11];
    const float* ln_b    = (const float*)d_in[12];
    const float* blk_Wm0 = (const float*)d_in[13];
    const float* blk_bm0 = (const float*)d_in[14];
    const float* blk_Wm1 = (const float*)d_in[15];
    const float* blk_bm1 = (const float*)d_in[16];
    const float* blk_Wu0 = (const float*)d_in[17];
    const float* blk_bu0 = (const float*)d_in[18];
    const float* blk_Wu1 = (const float*)d_in[19];
    const float* blk_bu1 = (const float*)d_in[20];
    const float* blk_lng = (const float*)d_in[21];
    const float* blk_lnb = (const float*)d_in[22];
    const float* hd_W0   = (const float*)d_in[23];
    const float* hd_b0   = (const float*)d_in[24];
    const float* hd_W1   = (const float*)d_in[25];
    const float* hd_b1   = (const float*)d_in[26];
    const float* hd_W2   = (const float*)d_in[27];
    const float* hd_b2   = (const float*)d_in[28];

    float* ws = (float*)d_ws;
    float* nodesA = ws;                        // NODES*64
    float* nodesB = nodesA + (size_t)NODES * DD;
    float* dists  = nodesB + (size_t)NODES * DD;
    float* wbuf   = dists + (size_t)NODES * KNN;
    int*   senders = (int*)(wbuf + (size_t)NODES * KNN);

    k_embed<<<NODES, 256, 0, stream>>>(s_ctx, f_ctx, s_test, emb_obs,
        ea_W0, ea_b0, ea_W1, ea_b1, ea_W2, ea_b2, ln_g, ln_b, nodesA);

    k_topk<<<NODES / 4, 256, 0, stream>>>(s_ctx, s_test, valid, dists, senders, wbuf);

    float* nin = nodesA; float* nout = nodesB;
    for (int i = 0; i < NBLK; ++i) {
        k_block<<<NODES, 256, 0, stream>>>(nin, nout, dists, senders, wbuf,
            blk_Wm0 + (size_t)i * 65 * 128, blk_bm0 + (size_t)i * 128,
            blk_Wm1 + (size_t)i * 128 * 64, blk_bm1 + (size_t)i * 64,
            blk_Wu0 + (size_t)i * 128 * 128, blk_bu0 + (size_t)i * 128,
            blk_Wu1 + (size_t)i * 128 * 64, blk_bu1 + (size_t)i * 64,
            blk_lng + (size_t)i * 64, blk_lnb + (size_t)i * 64);
        float* tmp = nin; nin = nout; nout = tmp;
    }

    k_head<<<BB * NT, 256, 0, stream>>>(nin, hd_W0, hd_b0, hd_W1, hd_b1, hd_W2, hd_b2,
                                        (float*)d_out);
}

// Round 2
// 759.655 us; speedup vs baseline: 2.7952x; 2.7952x over previous
//
#include <hip/hip_runtime.h>
#include <math.h>

#define BB 4
#define NC 4096
#define NT 1024
#define NN (NC + NT)      // 5120
#define NODES (BB * NN)   // 20480
#define DD 64
#define KNN 10
#define NBLK 6
#define BIGF 3.0e38f
#define EPW 80            // edges per k_msg workgroup (= 8 nodes)
#define NPW 8

typedef __attribute__((ext_vector_type(8))) short short8;
typedef __attribute__((ext_vector_type(4))) float f32x4;
typedef __attribute__((ext_vector_type(4))) int int4v;

__device__ __forceinline__ unsigned short f2bf(float f) {
    unsigned int u = __float_as_uint(f);
    unsigned int r = (u + 0x7fffu + ((u >> 16) & 1u)) >> 16;
    return (unsigned short)r;
}
__device__ __forceinline__ float bf2f(unsigned short h) {
    return __uint_as_float(((unsigned int)h) << 16);
}

// fast tanh-gelu: gelu(x) = x * (1 - 1/(1+e^{2z})), z = c0*(x + 0.044715 x^3)
__device__ __forceinline__ float gelu_f(float x) {
    const float c0 = 0.7978845608028654f;
    float x3 = x * x * x;
    float z2 = 2.0f * c0 * (x + 0.044715f * x3);
    float e = __expf(z2);
    float r = __builtin_amdgcn_rcpf(1.0f + e);
    return x - x * r;
}

__device__ __forceinline__ float wave_sum(float v) {
#pragma unroll
    for (int off = 32; off > 0; off >>= 1) v += __shfl_xor(v, off, 64);
    return v;
}

__device__ __forceinline__ f32x4 mfma_bf16(short8 a, short8 b, f32x4 c) {
    asm("v_mfma_f32_16x16x32_bf16 %0, %1, %2, %0" : "+v"(c) : "v"(a), "v"(b));
    return c;
}

// ---------------- weight convert: f32 -> bf16 transposed [N][K] ----------------
__global__ __launch_bounds__(256) void k_convw(
    const float* __restrict__ Wm0, const float* __restrict__ Wm1,
    const float* __restrict__ Wu0, const float* __restrict__ Wu1,
    unsigned short* __restrict__ wtm0, unsigned short* __restrict__ wtm1,
    unsigned short* __restrict__ wtu0, unsigned short* __restrict__ wtu1,
    float* __restrict__ wd)
{
    int t = blockIdx.x * 256 + threadIdx.x;
    if (t < 49152) {                 // wtm0 [6][128][64] <- Wm0[i][k][n], k<64
        int i = t / 8192, r = t % 8192, n = r / 64, k = r % 64;
        wtm0[t] = f2bf(Wm0[(i * 65 + k) * 128 + n]);
    } else if (t < 98304) {          // wtm1 [6][64][128] <- Wm1[i][k][n]
        int u = t - 49152;
        int i = u / 8192, r = u % 8192, n = r / 128, k = r % 128;
        wtm1[u] = f2bf(Wm1[(i * 128 + k) * 64 + n]);
    } else if (t < 196608) {         // wtu0 [6][128][128] <- Wu0[i][k][n]
        int u = t - 98304;
        int i = u / 16384, r = u % 16384, n = r / 128, k = r % 128;
        wtu0[u] = f2bf(Wu0[(i * 128 + k) * 128 + n]);
    } else if (t < 245760) {         // wtu1 [6][64][128] <- Wu1[i][k][n]
        int u = t - 196608;
        int i = u / 8192, r = u % 8192, n = r / 128, k = r % 128;
        wtu1[u] = f2bf(Wu1[(i * 128 + k) * 64 + n]);
    } else if (t < 246528) {         // wd [6][128] f32 <- Wm0[i][64][n]
        int u = t - 245760;
        int i = u / 128, n = u % 128;
        wd[u] = Wm0[(i * 65 + 64) * 128 + n];
    }
}

// ---------------- embed: 11 -> 256 -> 128 -> 64 + LN (bf16 out) ----------------
__global__ __launch_bounds__(256) void k_embed(
    const float* __restrict__ s_ctx, const float* __restrict__ f_ctx,
    const float* __restrict__ s_test, const float* __restrict__ emb_obs,
    const float* __restrict__ W0, const float* __restrict__ b0,
    const float* __restrict__ W1, const float* __restrict__ b1,
    const float* __restrict__ W2, const float* __restrict__ b2,
    const float* __restrict__ g, const float* __restrict__ bta,
    unsigned short* __restrict__ nodes)
{
    int node = blockIdx.x;
    int b = node / NN, n = node % NN;
    int t = threadIdx.x;
    __shared__ float x[16];
    __shared__ float h0[256];
    __shared__ float h1[128];
    __shared__ float h2[64];
    if (t < 11) {
        float v;
        if (n < NC) {
            if (t < 4)      v = emb_obs[4 + t];
            else if (t < 7) v = s_ctx[(b * NC + n) * 3 + (t - 4)];
            else            v = f_ctx[(b * NC + n) * 4 + (t - 7)];
        } else {
            int nt = n - NC;
            if (t < 4)      v = emb_obs[t];
            else if (t < 7) v = s_test[(b * NT + nt) * 3 + (t - 4)];
            else            v = 0.0f;
        }
        x[t] = v;
    }
    __syncthreads();
    {
        float acc = b0[t];
#pragma unroll
        for (int d = 0; d < 11; ++d) acc += x[d] * W0[d * 256 + t];
        h0[t] = gelu_f(acc);
    }
    __syncthreads();
    if (t < 128) {
        float acc = b1[t];
        for (int d = 0; d < 256; ++d) acc += h0[d] * W1[d * 128 + t];
        h1[t] = gelu_f(acc);
    }
    __syncthreads();
    if (t < 64) {
        float acc = b2[t];
        for (int d = 0; d < 128; ++d) acc += h1[d] * W2[d * 64 + t];
        h2[t] = acc;
    }
    __syncthreads();
    if (t < 64) {
        float v = h2[t];
        float m = wave_sum(v) * (1.0f / 64.0f);
        float dv = v - m;
        float var = wave_sum(dv * dv) * (1.0f / 64.0f);
        nodes[(size_t)node * DD + t] = f2bf(dv * rsqrtf(var + 1e-6f) * g[t] + bta[t]);
    }
}

// ---------------- top-K: one wave per receiver ----------------
__global__ __launch_bounds__(256) void k_topk(
    const float* __restrict__ s_ctx, const float* __restrict__ s_test,
    const int* __restrict__ valid_lens,
    float* __restrict__ dists, int* __restrict__ senders, float* __restrict__ wout)
{
    __shared__ float cd[4 * 64 * KNN];
    __shared__ int   ci[4 * 64 * KNN];
    int wave = threadIdx.x >> 6;
    int lane = threadIdx.x & 63;
    int r = blockIdx.x * 4 + wave;
    if (r >= NODES) return;
    int b = r / NN, n = r % NN;
    float px, py, pz;
    if (n < NC) {
        const float* p = &s_ctx[(size_t)(b * NC + n) * 3];
        px = p[0]; py = p[1]; pz = p[2];
    } else {
        const float* p = &s_test[(size_t)(b * NT + (n - NC)) * 3];
        px = p[0]; py = p[1]; pz = p[2];
    }
    int vl = valid_lens[b];
    float best[KNN];
    int bidx[KNN];
#pragma unroll
    for (int k = 0; k < KNN; ++k) { best[k] = BIGF; bidx[k] = 0; }
    const float* sc = &s_ctx[(size_t)b * NC * 3];
    for (int j = lane; j < vl; j += 64) {
        float dx = px - sc[j * 3 + 0];
        float dy = py - sc[j * 3 + 1];
        float dz = pz - sc[j * 3 + 2];
        float d2 = dx * dx + dy * dy + dz * dz;
        if (d2 < best[KNN - 1]) {
#pragma unroll
            for (int k = KNN - 1; k >= 0; --k) {
                float prev = (k > 0) ? best[k - 1] : -1.0f;
                int previ = (k > 0) ? bidx[k - 1] : 0;
                if (prev > d2)         { best[k] = prev; bidx[k] = previ; }
                else if (best[k] > d2) { best[k] = d2;   bidx[k] = j; }
            }
        }
    }
    int base = (wave * 64 + lane) * KNN;
#pragma unroll
    for (int k = 0; k < KNN; ++k) { cd[base + k] = best[k]; ci[base + k] = bidx[k]; }
    int head = 0;
    float myd = 0.0f; int myidx = 0;
#pragma unroll
    for (int rr = 0; rr < KNN; ++rr) {
        float v = cd[base + head];
        int vi = ci[base + head];
        float mv = v;
#pragma unroll
        for (int off = 32; off > 0; off >>= 1) mv = fminf(mv, __shfl_xor(mv, off, 64));
        unsigned long long ball = __ballot(v == mv);
        int win = __ffsll(ball) - 1;
        int widx = __shfl(vi, win, 64);
        if (lane == win) head++;
        if (lane == rr) { myd = mv; myidx = widx; }
    }
    float d = sqrtf(myd);
    float d0 = __shfl(d, 0, 64);
    float e = (lane < KNN) ? expf(-(d - d0)) : 0.0f;
    float s = wave_sum(e);
    if (lane < KNN) {
        size_t o = (size_t)r * KNN + lane;
        dists[o] = d;
        senders[o] = myidx;
        wout[o] = e / s;
    }
}

// ---------------- message MLP + aggregate: 8 nodes (80 edges) per WG ----------------
__global__ __launch_bounds__(320) void k_msg(
    const unsigned short* __restrict__ nodes,   // bf16 [NODES][64]
    const float* __restrict__ dists, const int* __restrict__ senders,
    const float* __restrict__ w,
    const unsigned short* __restrict__ WT0,     // [128][64] bf16 (Wm0[0:64]^T)
    const float* __restrict__ wd,               // [128] f32 (Wm0[64])
    const float* __restrict__ bm0,
    const unsigned short* __restrict__ WT1,     // [64][128] bf16
    const float* __restrict__ bm1,
    unsigned short* __restrict__ agg)           // bf16 [NODES][64]
{
    __shared__ unsigned short A[EPW * 64];      // gathered sender feats, swizzled 16B units
    __shared__ unsigned short H[5][16 * 128];   // per-wave h, swizzled
    __shared__ float MW[EPW * 64];              // weighted messages
    __shared__ int   sid[EPW];
    __shared__ float sdist[EPW], sw[EPW];

    int t = threadIdx.x;
    int node0 = blockIdx.x * NPW;
    int b = node0 / NN;
    int e0 = node0 * KNN;
    if (t < EPW) {
        sid[t]   = senders[e0 + t];
        sdist[t] = dists[e0 + t];
        sw[t]    = w[e0 + t];
    }
    __syncthreads();
    // gather: 80 rows x 8 x 16B chunks
    for (int c = t; c < EPW * 8; c += 320) {
        int row = c >> 3, u = c & 7;
        int4v v = *(const int4v*)(nodes + ((size_t)(b * NN + sid[row])) * 64 + u * 8);
        int su = u ^ (row & 7);
        *(int4v*)(&A[row * 64 + su * 8]) = v;
    }
    __syncthreads();

    int wave = t >> 6, lane = t & 63;
    int rb = wave * 16;
    int lr = lane & 15, lk = lane >> 4;

    // GEMM1: A[16x64] @ Wm0 -> [16x128]
    f32x4 acc[8];
#pragma unroll
    for (int nt = 0; nt < 8; ++nt) acc[nt] = (f32x4){0.f, 0.f, 0.f, 0.f};
#pragma unroll
    for (int ks = 0; ks < 2; ++ks) {
        int row = rb + lr;
        int u = (ks * 4 + lk) ^ (row & 7);
        short8 a = *(const short8*)(&A[row * 64 + u * 8]);
#pragma unroll
        for (int nt = 0; nt < 8; ++nt) {
            short8 bb = *(const short8*)(WT0 + (nt * 16 + lr) * 64 + ks * 32 + lk * 8);
            acc[nt] = mfma_bf16(a, bb, acc[nt]);
        }
    }
    // epilogue: + bias + dist*wd, gelu, -> H (swizzled row-major [16][128])
    unsigned short* h = &H[wave][0];
    float sd[4];
#pragma unroll
    for (int j = 0; j < 4; ++j) sd[j] = sdist[rb + lk * 4 + j];
#pragma unroll
    for (int nt = 0; nt < 8; ++nt) {
        int colg = nt * 16 + lr;
        float bias = bm0[colg];
        float wdc = wd[colg];
#pragma unroll
        for (int j = 0; j < 4; ++j) {
            int lrow = lk * 4 + j;
            float v = acc[nt][j] + bias + sd[j] * wdc;
            v = gelu_f(v);
            int un = (colg >> 3) ^ lrow;
            h[lrow * 128 + un * 8 + (colg & 7)] = f2bf(v);
        }
    }
    // GEMM2: h[16x128] @ Wm1 -> m[16x64]; weight by w; store MW
    f32x4 acc2[4];
#pragma unroll
    for (int nt = 0; nt < 4; ++nt) acc2[nt] = (f32x4){0.f, 0.f, 0.f, 0.f};
#pragma unroll
    for (int ks = 0; ks < 4; ++ks) {
        int un = (ks * 4 + lk) ^ lr;
        short8 a = *(const short8*)(&h[lr * 128 + un * 8]);
#pragma unroll
        for (int nt = 0; nt < 4; ++nt) {
            short8 bb = *(const short8*)(WT1 + (nt * 16 + lr) * 128 + ks * 32 + lk * 8);
            acc2[nt] = mfma_bf16(a, bb, acc2[nt]);
        }
    }
    float swr[4];
#pragma unroll
    for (int j = 0; j < 4; ++j) swr[j] = sw[rb + lk * 4 + j];
#pragma unroll
    for (int nt = 0; nt < 4; ++nt) {
        int colg = nt * 16 + lr;
        float bias = bm1[colg];
#pragma unroll
        for (int j = 0; j < 4; ++j) {
            int row = rb + lk * 4 + j;
            MW[row * 64 + colg] = (acc2[nt][j] + bias) * swr[j];
        }
    }
    __syncthreads();
    // aggregate: agg[n][c] = sum_k MW[n*10+k][c]
    for (int o = t; o < NPW * 64; o += 320) {
        int n = o >> 6, c = o & 63;
        float s = 0.0f;
#pragma unroll
        for (int k = 0; k < KNN; ++k) s += MW[(n * KNN + k) * 64 + c];
        agg[((size_t)(node0 + n)) * 64 + c] = f2bf(s);
    }
}

// ---------------- update MLP + residual + LN: 64 nodes per WG ----------------
__global__ __launch_bounds__(256) void k_upd(
    const unsigned short* __restrict__ nodes_in,  // bf16 [NODES][64]
    const unsigned short* __restrict__ agg,       // bf16 [NODES][64]
    const unsigned short* __restrict__ WTu0,      // [128][128]
    const float* __restrict__ bu0,
    const unsigned short* __restrict__ WTu1,      // [64][128]
    const float* __restrict__ bu1,
    const float* __restrict__ lng, const float* __restrict__ lnb,
    unsigned short* __restrict__ nodes_out)
{
    __shared__ unsigned short U[64 * 128];       // u_in, swizzled 16B units
    __shared__ unsigned short H[4][16 * 128];
    int t = threadIdx.x;
    int wave = t >> 6, lane = t & 63;
    int n0 = blockIdx.x * 64;
    for (int c = t; c < 64 * 16; c += 256) {
        int row = c >> 4, u = c & 15;
        int4v v;
        if (u < 8) v = *(const int4v*)(nodes_in + ((size_t)(n0 + row)) * 64 + u * 8);
        else       v = *(const int4v*)(agg + ((size_t)(n0 + row)) * 64 + (u - 8) * 8);
        *(int4v*)(&U[row * 128 + (u ^ (row & 15)) * 8]) = v;
    }
    __syncthreads();
    int rb = wave * 16;
    int lr = lane & 15, lk = lane >> 4;
    // GEMM3: U[16x128] @ Wu0 -> [16x128], gelu -> H
    f32x4 acc[8];
#pragma unroll
    for (int nt = 0; nt < 8; ++nt) acc[nt] = (f32x4){0.f, 0.f, 0.f, 0.f};
#pragma unroll
    for (int ks = 0; ks < 4; ++ks) {
        int row = rb + lr;
        int un = (ks * 4 + lk) ^ (row & 15);
        short8 a = *(const short8*)(&U[row * 128 + un * 8]);
#pragma unroll
        for (int nt = 0; nt < 8; ++nt) {
            short8 bb = *(const short8*)(WTu0 + (nt * 16 + lr) * 128 + ks * 32 + lk * 8);
            acc[nt] = mfma_bf16(a, bb, acc[nt]);
        }
    }
    unsigned short* h = &H[wave][0];
#pragma unroll
    for (int nt = 0; nt < 8; ++nt) {
        int colg = nt * 16 + lr;
        float bias = bu0[colg];
#pragma unroll
        for (int j = 0; j < 4; ++j) {
            int lrow = lk * 4 + j;
            float v = gelu_f(acc[nt][j] + bias);
            int un = (colg >> 3) ^ lrow;
            h[lrow * 128 + un * 8 + (colg & 7)] = f2bf(v);
        }
    }
    // GEMM4: h[16x128] @ Wu1 -> [16x64]
    f32x4 acc2[4];
#pragma unroll
    for (int nt = 0; nt < 4; ++nt) acc2[nt] = (f32x4){0.f, 0.f, 0.f, 0.f};
#pragma unroll
    for (int ks = 0; ks < 4; ++ks) {
        int un = (ks * 4 + lk) ^ lr;
        short8 a = *(const short8*)(&h[lr * 128 + un * 8]);
#pragma unroll
        for (int nt = 0; nt < 4; ++nt) {
            short8 bb = *(const short8*)(WTu1 + (nt * 16 + lr) * 128 + ks * 32 + lk * 8);
            acc2[nt] = mfma_bf16(a, bb, acc2[nt]);
        }
    }
    // residual + LN; lane holds rows rb+lk*4+j, cols nt*16+lr
    float vals[4][4];
#pragma unroll
    for (int j = 0; j < 4; ++j) {
        int row = rb + lk * 4 + j;
#pragma unroll
        for (int nt = 0; nt < 4; ++nt) {
            int col = nt * 16 + lr;
            int un = (col >> 3) ^ (row & 15);
            float x = bf2f(U[row * 128 + un * 8 + (col & 7)]);
            vals[j][nt] = x + acc2[nt][j] + bu1[col];
        }
    }
#pragma unroll
    for (int j = 0; j < 4; ++j) {
        int row = rb + lk * 4 + j;
        float s = vals[j][0] + vals[j][1] + vals[j][2] + vals[j][3];
#pragma unroll
        for (int m = 1; m < 16; m <<= 1) s += __shfl_xor(s, m, 64);
        float mean = s * (1.0f / 64.0f);
        float vs = 0.0f;
#pragma unroll
        for (int nt = 0; nt < 4; ++nt) { float d = vals[j][nt] - mean; vs += d * d; }
#pragma unroll
        for (int m = 1; m < 16; m <<= 1) vs += __shfl_xor(vs, m, 64);
        float inv = rsqrtf(vs * (1.0f / 64.0f) + 1e-6f);
#pragma unroll
        for (int nt = 0; nt < 4; ++nt) {
            int col = nt * 16 + lr;
            float o = (vals[j][nt] - mean) * inv * lng[col] + lnb[col];
            nodes_out[((size_t)(n0 + row)) * 64 + col] = f2bf(o);
        }
    }
}

// ---------------- head: 64 -> 256 -> 64 -> 2 ----------------
__global__ __launch_bounds__(256) void k_head(
    const unsigned short* __restrict__ nodes,
    const float* __restrict__ W0, const float* __restrict__ b0,
    const float* __restrict__ W1, const float* __restrict__ b1,
    const float* __restrict__ W2, const float* __restrict__ b2,
    float* __restrict__ out)
{
    int idx = blockIdx.x;
    int b = idx / NT, n = idx % NT;
    int t = threadIdx.x;
    __shared__ float x[64];
    __shared__ float h0[256];
    __shared__ float h1[64];
    size_t nbase = ((size_t)(b * NN + NC + n)) * DD;
    if (t < 64) x[t] = bf2f(nodes[nbase + t]);
    __syncthreads();
    {
        float acc = b0[t];
#pragma unroll
        for (int d = 0; d < 64; ++d) acc += x[d] * W0[d * 256 + t];
        h0[t] = gelu_f(acc);
    }
    __syncthreads();
    if (t < 64) {
        float acc = b1[t];
        for (int d = 0; d < 256; ++d) acc += h0[d] * W1[d * 64 + t];
        h1[t] = gelu_f(acc);
    }
    __syncthreads();
    if (t < 2) {
        float acc = b2[t];
        for (int d = 0; d < 64; ++d) acc += h1[d] * W2[d * 2 + t];
        if (t == 0) out[b * NT + n] = acc;
        else        out[BB * NT + b * NT + n] = expf(0.5f * acc);
    }
}

extern "C" void kernel_launch(void* const* d_in, const int* in_sizes, int n_in,
                              void* d_out, int out_size, void* d_ws, size_t ws_size,
                              hipStream_t stream)
{
    (void)in_sizes; (void)n_in; (void)out_size; (void)ws_size;
    const float* s_ctx   = (const float*)d_in[0];
    const float* f_ctx   = (const float*)d_in[1];
    const float* s_test  = (const float*)d_in[2];
    const int*   valid   = (const int*)d_in[3];
    const float* emb_obs = (const float*)d_in[4];
    const float* ea_W0   = (const float*)d_in[5];
    const float* ea_b0   = (const float*)d_in[6];
    const float* ea_W1   = (const float*)d_in[7];
    const float* ea_b1   = (const float*)d_in[8];
    const float* ea_W2   = (const float*)d_in[9];
    const float* ea_b2   = (const float*)d_in[10];
    const float* ln_g    = (const float*)d_in[11];
    const float* ln_b    = (const float*)d_in[12];
    const float* blk_Wm0 = (const float*)d_in[13];
    const float* blk_bm0 = (const float*)d_in[14];
    const float* blk_Wm1 = (const float*)d_in[15];
    const float* blk_bm1 = (const float*)d_in[16];
    const float* blk_Wu0 = (const float*)d_in[17];
    const float* blk_bu0 = (const float*)d_in[18];
    const float* blk_Wu1 = (const float*)d_in[19];
    const float* blk_bu1 = (const float*)d_in[20];
    const float* blk_lng = (const float*)d_in[21];
    const float* blk_lnb = (const float*)d_in[22];
    const float* hd_W0   = (const float*)d_in[23];
    const float* hd_b0   = (const float*)d_in[24];
    const float* hd_W1   = (const float*)d_in[25];
    const float* hd_b1   = (const float*)d_in[26];
    const float* hd_W2   = (const float*)d_in[27];
    const float* hd_b2   = (const float*)d_in[28];

    char* p = (char*)d_ws;
    auto alloc = [&](size_t bytes) { char* r = p; p += (bytes + 255) & ~(size_t)255; return r; };
    unsigned short* nodesA = (unsigned short*)alloc((size_t)NODES * 64 * 2);
    unsigned short* nodesB = (unsigned short*)alloc((size_t)NODES * 64 * 2);
    unsigned short* aggb   = (unsigned short*)alloc((size_t)NODES * 64 * 2);
    float* dists   = (float*)alloc((size_t)NODES * KNN * 4);
    float* wbuf    = (float*)alloc((size_t)NODES * KNN * 4);
    int*   senders = (int*)alloc((size_t)NODES * KNN * 4);
    unsigned short* wtm0 = (unsigned short*)alloc((size_t)6 * 8192 * 2);
    unsigned short* wtm1 = (unsigned short*)alloc((size_t)6 * 8192 * 2);
    unsigned short* wtu0 = (unsigned short*)alloc((size_t)6 * 16384 * 2);
    unsigned short* wtu1 = (unsigned short*)alloc((size_t)6 * 8192 * 2);
    float* wdbuf = (float*)alloc((size_t)6 * 128 * 4);

    k_convw<<<(246528 + 255) / 256, 256, 0, stream>>>(
        blk_Wm0, blk_Wm1, blk_Wu0, blk_Wu1, wtm0, wtm1, wtu0, wtu1, wdbuf);

    k_embed<<<NODES, 256, 0, stream>>>(s_ctx, f_ctx, s_test, emb_obs,
        ea_W0, ea_b0, ea_W1, ea_b1, ea_W2, ea_b2, ln_g, ln_b, nodesA);

    k_topk<<<NODES / 4, 256, 0, stream>>>(s_ctx, s_test, valid, dists, senders, wbuf);

    unsigned short* nin = nodesA; unsigned short* nout = nodesB;
    for (int i = 0; i < NBLK; ++i) {
        k_msg<<<NODES / NPW, 320, 0, stream>>>(nin, dists, senders, wbuf,
            wtm0 + (size_t)i * 8192, wdbuf + (size_t)i * 128, blk_bm0 + (size_t)i * 128,
            wtm1 + (size_t)i * 8192, blk_bm1 + (size_t)i * 64, aggb);
        k_upd<<<NODES / 64, 256, 0, stream>>>(nin, aggb,
            wtu0 + (size_t)i * 16384, blk_bu0 + (size_t)i * 128,
            wtu1 + (size_t)i * 8192, blk_bu1 + (size_t)i * 64,
            blk_lng + (size_t)i * 64, blk_lnb + (size_t)i * 64, nout);
        unsigned short* tmp = nin; nin = nout; nout = tmp;
    }

    k_head<<<BB * NT, 256, 0, stream>>>(nin, hd_W0, hd_b0, hd_W1, hd_b1, hd_W2, hd_b2,
                                        (float*)d_out);
}

// Round 3
// 666.342 us; speedup vs baseline: 3.1866x; 1.1400x over previous
//
#include <hip/hip_runtime.h>
#include <math.h>

#define BB 4
#define NC 4096
#define NT 1024
#define NN (NC + NT)      // 5120
#define NODES (BB * NN)   // 20480
#define DD 64
#define KNN 10
#define NBLK 6
#define BIGF 3.0e38f
#define EPW 80            // edges per k_msg workgroup (= 8 nodes)
#define NPW 8

typedef __attribute__((ext_vector_type(8))) short short8;
typedef __attribute__((ext_vector_type(4))) float f32x4;
typedef __attribute__((ext_vector_type(4))) int int4v;

__device__ __forceinline__ unsigned short f2bf(float f) {
    unsigned int u = __float_as_uint(f);
    unsigned int r = (u + 0x7fffu + ((u >> 16) & 1u)) >> 16;
    return (unsigned short)r;
}
__device__ __forceinline__ float bf2f(unsigned short h) {
    return __uint_as_float(((unsigned int)h) << 16);
}

// fast tanh-gelu: gelu(x) = x * (1 - 1/(1+e^{2z})), z = c0*(x + 0.044715 x^3)
__device__ __forceinline__ float gelu_f(float x) {
    const float c0 = 0.7978845608028654f;
    float x3 = x * x * x;
    float z2 = 2.0f * c0 * (x + 0.044715f * x3);
    float e = __expf(z2);
    float r = __builtin_amdgcn_rcpf(1.0f + e);
    return x - x * r;
}

__device__ __forceinline__ float wave_sum(float v) {
#pragma unroll
    for (int off = 32; off > 0; off >>= 1) v += __shfl_xor(v, off, 64);
    return v;
}

__device__ __forceinline__ f32x4 mfma_bf16(short8 a, short8 b, f32x4 c) {
    asm("v_mfma_f32_16x16x32_bf16 %0, %1, %2, %0" : "+v"(c) : "v"(a), "v"(b));
    return c;
}

// ---------------- weight convert: f32 -> bf16 transposed [N][K] ----------------
__global__ __launch_bounds__(256) void k_convw(
    const float* __restrict__ Wm0, const float* __restrict__ Wm1,
    const float* __restrict__ Wu0, const float* __restrict__ Wu1,
    const float* __restrict__ eW0, const float* __restrict__ eW1,
    const float* __restrict__ eW2,
    const float* __restrict__ hW0, const float* __restrict__ hW1,
    unsigned short* __restrict__ wtm0, unsigned short* __restrict__ wtm1,
    unsigned short* __restrict__ wtu0, unsigned short* __restrict__ wtu1,
    float* __restrict__ wd,
    unsigned short* __restrict__ wte0, unsigned short* __restrict__ wte1,
    unsigned short* __restrict__ wte2,
    unsigned short* __restrict__ wth0, unsigned short* __restrict__ wth1)
{
    int t = blockIdx.x * 256 + threadIdx.x;
    if (t < 49152) {                 // wtm0 [6][128][64] <- Wm0[i][k][n], k<64
        int i = t / 8192, r = t % 8192, n = r / 64, k = r % 64;
        wtm0[t] = f2bf(Wm0[(i * 65 + k) * 128 + n]);
    } else if (t < 98304) {          // wtm1 [6][64][128]
        int u = t - 49152;
        int i = u / 8192, r = u % 8192, n = r / 128, k = r % 128;
        wtm1[u] = f2bf(Wm1[(i * 128 + k) * 64 + n]);
    } else if (t < 196608) {         // wtu0 [6][128][128]
        int u = t - 98304;
        int i = u / 16384, r = u % 16384, n = r / 128, k = r % 128;
        wtu0[u] = f2bf(Wu0[(i * 128 + k) * 128 + n]);
    } else if (t < 245760) {         // wtu1 [6][64][128]
        int u = t - 196608;
        int i = u / 8192, r = u % 8192, n = r / 128, k = r % 128;
        wtu1[u] = f2bf(Wu1[(i * 128 + k) * 64 + n]);
    } else if (t < 246528) {         // wd [6][128] f32 <- Wm0[i][64][n]
        int u = t - 245760;
        int i = u / 128, n = u % 128;
        wd[u] = Wm0[(i * 65 + 64) * 128 + n];
    } else if (t < 254720) {         // wte0 [256][32], k<11 else 0
        int u = t - 246528;
        int n = u / 32, k = u % 32;
        wte0[u] = (k < 11) ? f2bf(eW0[k * 256 + n]) : 0;
    } else if (t < 287488) {         // wte1 [128][256]
        int u = t - 254720;
        int n = u / 256, k = u % 256;
        wte1[u] = f2bf(eW1[k * 128 + n]);
    } else if (t < 295680) {         // wte2 [64][128]
        int u = t - 287488;
        int n = u / 128, k = u % 128;
        wte2[u] = f2bf(eW2[k * 64 + n]);
    } else if (t < 312064) {         // wth0 [256][64]
        int u = t - 295680;
        int n = u / 64, k = u % 64;
        wth0[u] = f2bf(hW0[k * 256 + n]);
    } else if (t < 328448) {         // wth1 [64][256]
        int u = t - 312064;
        int n = u / 256, k = u % 256;
        wth1[u] = f2bf(hW1[k * 64 + n]);
    }
}

// ---------------- embed (MFMA): 64 nodes per WG, 4 waves, barrier-free ----------------
__global__ __launch_bounds__(256) void k_embed2(
    const float* __restrict__ s_ctx, const float* __restrict__ f_ctx,
    const float* __restrict__ s_test, const float* __restrict__ emb_obs,
    const unsigned short* __restrict__ WT0, const float* __restrict__ b0,
    const unsigned short* __restrict__ WT1, const float* __restrict__ b1,
    const unsigned short* __restrict__ WT2, const float* __restrict__ b2,
    const float* __restrict__ g, const float* __restrict__ bta,
    unsigned short* __restrict__ nodes)
{
    __shared__ unsigned short H0[4][16 * 256];
    __shared__ unsigned short H1[4][16 * 128];
    int t = threadIdx.x;
    int wave = t >> 6, lane = t & 63, lr = lane & 15, lk = lane >> 4;
    int rb = wave * 16;
    int n0 = blockIdx.x * 64;
    int bq = n0 / NN, nloc0 = n0 % NN;
    bool is_ctx = nloc0 < NC;
    int nr = nloc0 + rb + lr;
    // A fragment (row=lr, k=lk*8+j), K padded 11->32 with zeros
    float xv[8];
#pragma unroll
    for (int j = 0; j < 8; ++j) xv[j] = 0.0f;
    if (lk == 0) {
        const float* eb = emb_obs + (is_ctx ? 4 : 0);
        xv[0] = eb[0]; xv[1] = eb[1]; xv[2] = eb[2]; xv[3] = eb[3];
        if (is_ctx) {
            const float* sp = s_ctx + ((size_t)(bq * NC + nr)) * 3;
            const float* fp = f_ctx + ((size_t)(bq * NC + nr)) * 4;
            xv[4] = sp[0]; xv[5] = sp[1]; xv[6] = sp[2]; xv[7] = fp[0];
        } else {
            const float* sp = s_test + ((size_t)(bq * NT + nr - NC)) * 3;
            xv[4] = sp[0]; xv[5] = sp[1]; xv[6] = sp[2];
        }
    } else if (lk == 1 && is_ctx) {
        const float* fp = f_ctx + ((size_t)(bq * NC + nr)) * 4;
        xv[0] = fp[1]; xv[1] = fp[2]; xv[2] = fp[3];
    }
    short8 a;
#pragma unroll
    for (int j = 0; j < 8; ++j) a[j] = (short)f2bf(xv[j]);

    // GEMM1: [64x32] @ [32x256], single K-step
    f32x4 acc0[16];
#pragma unroll
    for (int nt = 0; nt < 16; ++nt) {
        short8 bb = *(const short8*)(WT0 + (nt * 16 + lr) * 32 + lk * 8);
        f32x4 z = (f32x4){0.f, 0.f, 0.f, 0.f};
        acc0[nt] = mfma_bf16(a, bb, z);
    }
    unsigned short* h0 = &H0[wave][0];
#pragma unroll
    for (int nt = 0; nt < 16; ++nt) {
        int col = nt * 16 + lr;
        float bias = b0[col];
        int u = col >> 3;
#pragma unroll
        for (int j = 0; j < 4; ++j) {
            int row = lk * 4 + j;
            float v = gelu_f(acc0[nt][j] + bias);
            int us = (u & 16) | ((u ^ row) & 15);
            h0[row * 256 + us * 8 + (col & 7)] = f2bf(v);
        }
    }
    // GEMM2: [64x256] @ [256x128]
    f32x4 acc1[8];
#pragma unroll
    for (int nt = 0; nt < 8; ++nt) acc1[nt] = (f32x4){0.f, 0.f, 0.f, 0.f};
#pragma unroll
    for (int ks = 0; ks < 8; ++ks) {
        int u = ks * 4 + lk;
        int us = (u & 16) | ((u ^ lr) & 15);
        short8 aa = *(const short8*)(&h0[lr * 256 + us * 8]);
#pragma unroll
        for (int nt = 0; nt < 8; ++nt) {
            short8 bb = *(const short8*)(WT1 + (nt * 16 + lr) * 256 + ks * 32 + lk * 8);
            acc1[nt] = mfma_bf16(aa, bb, acc1[nt]);
        }
    }
    unsigned short* h1 = &H1[wave][0];
#pragma unroll
    for (int nt = 0; nt < 8; ++nt) {
        int col = nt * 16 + lr;
        float bias = b1[col];
        int u = col >> 3;
#pragma unroll
        for (int j = 0; j < 4; ++j) {
            int row = lk * 4 + j;
            float v = gelu_f(acc1[nt][j] + bias);
            int us = (u ^ row) & 15;
            h1[row * 128 + us * 8 + (col & 7)] = f2bf(v);
        }
    }
    // GEMM3: [64x128] @ [128x64] + LN
    f32x4 acc2[4];
#pragma unroll
    for (int nt = 0; nt < 4; ++nt) acc2[nt] = (f32x4){0.f, 0.f, 0.f, 0.f};
#pragma unroll
    for (int ks = 0; ks < 4; ++ks) {
        int u = ks * 4 + lk;
        int us = (u ^ lr) & 15;
        short8 aa = *(const short8*)(&h1[lr * 128 + us * 8]);
#pragma unroll
        for (int nt = 0; nt < 4; ++nt) {
            short8 bb = *(const short8*)(WT2 + (nt * 16 + lr) * 128 + ks * 32 + lk * 8);
            acc2[nt] = mfma_bf16(aa, bb, acc2[nt]);
        }
    }
    float vals[4][4];
#pragma unroll
    for (int j = 0; j < 4; ++j)
#pragma unroll
        for (int nt = 0; nt < 4; ++nt)
            vals[j][nt] = acc2[nt][j] + b2[nt * 16 + lr];
#pragma unroll
    for (int j = 0; j < 4; ++j) {
        float s = vals[j][0] + vals[j][1] + vals[j][2] + vals[j][3];
#pragma unroll
        for (int m = 1; m < 16; m <<= 1) s += __shfl_xor(s, m, 64);
        float mean = s * (1.0f / 64.0f);
        float vs = 0.0f;
#pragma unroll
        for (int nt = 0; nt < 4; ++nt) { float d = vals[j][nt] - mean; vs += d * d; }
#pragma unroll
        for (int m = 1; m < 16; m <<= 1) vs += __shfl_xor(vs, m, 64);
        float inv = rsqrtf(vs * (1.0f / 64.0f) + 1e-6f);
        int node = n0 + rb + lk * 4 + j;
#pragma unroll
        for (int nt = 0; nt < 4; ++nt) {
            int col = nt * 16 + lr;
            float o = (vals[j][nt] - mean) * inv * g[col] + bta[col];
            nodes[(size_t)node * 64 + col] = f2bf(o);
        }
    }
}

// ---------------- top-K: one wave per receiver ----------------
__global__ __launch_bounds__(256) void k_topk(
    const float* __restrict__ s_ctx, const float* __restrict__ s_test,
    const int* __restrict__ valid_lens,
    float* __restrict__ dists, int* __restrict__ senders, float* __restrict__ wout)
{
    __shared__ float cd[4 * 64 * KNN];
    __shared__ int   ci[4 * 64 * KNN];
    int wave = threadIdx.x >> 6;
    int lane = threadIdx.x & 63;
    int r = blockIdx.x * 4 + wave;
    if (r >= NODES) return;
    int b = r / NN, n = r % NN;
    float px, py, pz;
    if (n < NC) {
        const float* p = &s_ctx[(size_t)(b * NC + n) * 3];
        px = p[0]; py = p[1]; pz = p[2];
    } else {
        const float* p = &s_test[(size_t)(b * NT + (n - NC)) * 3];
        px = p[0]; py = p[1]; pz = p[2];
    }
    int vl = valid_lens[b];
    float best[KNN];
    int bidx[KNN];
#pragma unroll
    for (int k = 0; k < KNN; ++k) { best[k] = BIGF; bidx[k] = 0; }
    const float* sc = &s_ctx[(size_t)b * NC * 3];
    for (int j = lane; j < vl; j += 64) {
        float dx = px - sc[j * 3 + 0];
        float dy = py - sc[j * 3 + 1];
        float dz = pz - sc[j * 3 + 2];
        float d2 = dx * dx + dy * dy + dz * dz;
        if (d2 < best[KNN - 1]) {
#pragma unroll
            for (int k = KNN - 1; k >= 0; --k) {
                float prev = (k > 0) ? best[k - 1] : -1.0f;
                int previ = (k > 0) ? bidx[k - 1] : 0;
                if (prev > d2)         { best[k] = prev; bidx[k] = previ; }
                else if (best[k] > d2) { best[k] = d2;   bidx[k] = j; }
            }
        }
    }
    int base = (wave * 64 + lane) * KNN;
#pragma unroll
    for (int k = 0; k < KNN; ++k) { cd[base + k] = best[k]; ci[base + k] = bidx[k]; }
    int head = 0;
    float myd = 0.0f; int myidx = 0;
#pragma unroll
    for (int rr = 0; rr < KNN; ++rr) {
        float v = cd[base + head];
        int vi = ci[base + head];
        float mv = v;
#pragma unroll
        for (int off = 32; off > 0; off >>= 1) mv = fminf(mv, __shfl_xor(mv, off, 64));
        unsigned long long ball = __ballot(v == mv);
        int win = __ffsll(ball) - 1;
        int widx = __shfl(vi, win, 64);
        if (lane == win) head++;
        if (lane == rr) { myd = mv; myidx = widx; }
    }
    float d = sqrtf(myd);
    float d0 = __shfl(d, 0, 64);
    float e = (lane < KNN) ? expf(-(d - d0)) : 0.0f;
    float s = wave_sum(e);
    if (lane < KNN) {
        size_t o = (size_t)r * KNN + lane;
        dists[o] = d;
        senders[o] = myidx;
        wout[o] = e / s;
    }
}

// ---------------- message MLP + aggregate: 8 nodes (80 edges) per WG ----------------
__global__ __launch_bounds__(320) void k_msg(
    const unsigned short* __restrict__ nodes,
    const float* __restrict__ dists, const int* __restrict__ senders,
    const float* __restrict__ w,
    const unsigned short* __restrict__ WT0,     // [128][64]
    const float* __restrict__ wd,               // [128]
    const float* __restrict__ bm0,
    const unsigned short* __restrict__ WT1,     // [64][128]
    const float* __restrict__ bm1,
    unsigned short* __restrict__ agg)
{
    __shared__ unsigned short A[EPW * 64];
    __shared__ unsigned short H[5][16 * 128];
    __shared__ float MW[EPW * 64];
    __shared__ int   sid[EPW];
    __shared__ float sdist[EPW], sw[EPW];

    int t = threadIdx.x;
    int node0 = blockIdx.x * NPW;
    int b = node0 / NN;
    int e0 = node0 * KNN;
    if (t < EPW) {
        sid[t]   = senders[e0 + t];
        sdist[t] = dists[e0 + t];
        sw[t]    = w[e0 + t];
    }
    __syncthreads();
    for (int c = t; c < EPW * 8; c += 320) {
        int row = c >> 3, u = c & 7;
        int4v v = *(const int4v*)(nodes + ((size_t)(b * NN + sid[row])) * 64 + u * 8);
        int su = u ^ (row & 7);
        *(int4v*)(&A[row * 64 + su * 8]) = v;
    }
    __syncthreads();

    int wave = t >> 6, lane = t & 63;
    int rb = wave * 16;
    int lr = lane & 15, lk = lane >> 4;

    f32x4 acc[8];
#pragma unroll
    for (int nt = 0; nt < 8; ++nt) acc[nt] = (f32x4){0.f, 0.f, 0.f, 0.f};
#pragma unroll
    for (int ks = 0; ks < 2; ++ks) {
        int row = rb + lr;
        int u = (ks * 4 + lk) ^ (row & 7);
        short8 a = *(const short8*)(&A[row * 64 + u * 8]);
#pragma unroll
        for (int nt = 0; nt < 8; ++nt) {
            short8 bb = *(const short8*)(WT0 + (nt * 16 + lr) * 64 + ks * 32 + lk * 8);
            acc[nt] = mfma_bf16(a, bb, acc[nt]);
        }
    }
    unsigned short* h = &H[wave][0];
    float sd[4];
#pragma unroll
    for (int j = 0; j < 4; ++j) sd[j] = sdist[rb + lk * 4 + j];
#pragma unroll
    for (int nt = 0; nt < 8; ++nt) {
        int colg = nt * 16 + lr;
        float bias = bm0[colg];
        float wdc = wd[colg];
#pragma unroll
        for (int j = 0; j < 4; ++j) {
            int lrow = lk * 4 + j;
            float v = acc[nt][j] + bias + sd[j] * wdc;
            v = gelu_f(v);
            int un = (colg >> 3) ^ lrow;
            h[lrow * 128 + un * 8 + (colg & 7)] = f2bf(v);
        }
    }
    f32x4 acc2[4];
#pragma unroll
    for (int nt = 0; nt < 4; ++nt) acc2[nt] = (f32x4){0.f, 0.f, 0.f, 0.f};
#pragma unroll
    for (int ks = 0; ks < 4; ++ks) {
        int un = (ks * 4 + lk) ^ lr;
        short8 a = *(const short8*)(&h[lr * 128 + un * 8]);
#pragma unroll
        for (int nt = 0; nt < 4; ++nt) {
            short8 bb = *(const short8*)(WT1 + (nt * 16 + lr) * 128 + ks * 32 + lk * 8);
            acc2[nt] = mfma_bf16(a, bb, acc2[nt]);
        }
    }
    float swr[4];
#pragma unroll
    for (int j = 0; j < 4; ++j) swr[j] = sw[rb + lk * 4 + j];
#pragma unroll
    for (int nt = 0; nt < 4; ++nt) {
        int colg = nt * 16 + lr;
        float bias = bm1[colg];
#pragma unroll
        for (int j = 0; j < 4; ++j) {
            int row = rb + lk * 4 + j;
            MW[row * 64 + colg] = (acc2[nt][j] + bias) * swr[j];
        }
    }
    __syncthreads();
    for (int o = t; o < NPW * 64; o += 320) {
        int n = o >> 6, c = o & 63;
        float s = 0.0f;
#pragma unroll
        for (int k = 0; k < KNN; ++k) s += MW[(n * KNN + k) * 64 + c];
        agg[((size_t)(node0 + n)) * 64 + c] = f2bf(s);
    }
}

// ---------------- update MLP + residual + LN: 64 nodes per WG ----------------
__global__ __launch_bounds__(256) void k_upd(
    const unsigned short* __restrict__ nodes_in,
    const unsigned short* __restrict__ agg,
    const unsigned short* __restrict__ WTu0,      // [128][128]
    const float* __restrict__ bu0,
    const unsigned short* __restrict__ WTu1,      // [64][128]
    const float* __restrict__ bu1,
    const float* __restrict__ lng, const float* __restrict__ lnb,
    unsigned short* __restrict__ nodes_out)
{
    __shared__ unsigned short U[64 * 128];
    __shared__ unsigned short H[4][16 * 128];
    int t = threadIdx.x;
    int wave = t >> 6, lane = t & 63;
    int n0 = blockIdx.x * 64;
    for (int c = t; c < 64 * 16; c += 256) {
        int row = c >> 4, u = c & 15;
        int4v v;
        if (u < 8) v = *(const int4v*)(nodes_in + ((size_t)(n0 + row)) * 64 + u * 8);
        else       v = *(const int4v*)(agg + ((size_t)(n0 + row)) * 64 + (u - 8) * 8);
        *(int4v*)(&U[row * 128 + (u ^ (row & 15)) * 8]) = v;
    }
    __syncthreads();
    int rb = wave * 16;
    int lr = lane & 15, lk = lane >> 4;
    f32x4 acc[8];
#pragma unroll
    for (int nt = 0; nt < 8; ++nt) acc[nt] = (f32x4){0.f, 0.f, 0.f, 0.f};
#pragma unroll
    for (int ks = 0; ks < 4; ++ks) {
        int row = rb + lr;
        int un = (ks * 4 + lk) ^ (row & 15);
        short8 a = *(const short8*)(&U[row * 128 + un * 8]);
#pragma unroll
        for (int nt = 0; nt < 8; ++nt) {
            short8 bb = *(const short8*)(WTu0 + (nt * 16 + lr) * 128 + ks * 32 + lk * 8);
            acc[nt] = mfma_bf16(a, bb, acc[nt]);
        }
    }
    unsigned short* h = &H[wave][0];
#pragma unroll
    for (int nt = 0; nt < 8; ++nt) {
        int colg = nt * 16 + lr;
        float bias = bu0[colg];
#pragma unroll
        for (int j = 0; j < 4; ++j) {
            int lrow = lk * 4 + j;
            float v = gelu_f(acc[nt][j] + bias);
            int un = (colg >> 3) ^ lrow;
            h[lrow * 128 + un * 8 + (colg & 7)] = f2bf(v);
        }
    }
    f32x4 acc2[4];
#pragma unroll
    for (int nt = 0; nt < 4; ++nt) acc2[nt] = (f32x4){0.f, 0.f, 0.f, 0.f};
#pragma unroll
    for (int ks = 0; ks < 4; ++ks) {
        int un = (ks * 4 + lk) ^ lr;
        short8 a = *(const short8*)(&h[lr * 128 + un * 8]);
#pragma unroll
        for (int nt = 0; nt < 4; ++nt) {
            short8 bb = *(const short8*)(WTu1 + (nt * 16 + lr) * 128 + ks * 32 + lk * 8);
            acc2[nt] = mfma_bf16(a, bb, acc2[nt]);
        }
    }
    float vals[4][4];
#pragma unroll
    for (int j = 0; j < 4; ++j) {
        int row = rb + lk * 4 + j;
#pragma unroll
        for (int nt = 0; nt < 4; ++nt) {
            int col = nt * 16 + lr;
            int un = (col >> 3) ^ (row & 15);
            float x = bf2f(U[row * 128 + un * 8 + (col & 7)]);
            vals[j][nt] = x + acc2[nt][j] + bu1[col];
        }
    }
#pragma unroll
    for (int j = 0; j < 4; ++j) {
        int row = rb + lk * 4 + j;
        float s = vals[j][0] + vals[j][1] + vals[j][2] + vals[j][3];
#pragma unroll
        for (int m = 1; m < 16; m <<= 1) s += __shfl_xor(s, m, 64);
        float mean = s * (1.0f / 64.0f);
        float vs = 0.0f;
#pragma unroll
        for (int nt = 0; nt < 4; ++nt) { float d = vals[j][nt] - mean; vs += d * d; }
#pragma unroll
        for (int m = 1; m < 16; m <<= 1) vs += __shfl_xor(vs, m, 64);
        float inv = rsqrtf(vs * (1.0f / 64.0f) + 1e-6f);
#pragma unroll
        for (int nt = 0; nt < 4; ++nt) {
            int col = nt * 16 + lr;
            float o = (vals[j][nt] - mean) * inv * lng[col] + lnb[col];
            nodes_out[((size_t)(n0 + row)) * 64 + col] = f2bf(o);
        }
    }
}

// ---------------- head (MFMA): 64 test nodes per WG ----------------
__global__ __launch_bounds__(256) void k_head2(
    const unsigned short* __restrict__ nodes,
    const unsigned short* __restrict__ WT0, const float* __restrict__ b0,
    const unsigned short* __restrict__ WT1, const float* __restrict__ b1,
    const float* __restrict__ W2, const float* __restrict__ b2,
    float* __restrict__ out)
{
    __shared__ unsigned short H0[4][16 * 256];
    __shared__ unsigned short H1[4][16 * 72];
    int t = threadIdx.x;
    int wave = t >> 6, lane = t & 63, lr = lane & 15, lk = lane >> 4;
    int rb = wave * 16;
    int n0 = blockIdx.x * 64;
    int bq = n0 / NT, nloc0 = n0 % NT;
    size_t grow = (size_t)(bq * NN + NC + nloc0 + rb);
    short8 a0 = *(const short8*)(nodes + (grow + lr) * 64 + lk * 8);
    short8 a1 = *(const short8*)(nodes + (grow + lr) * 64 + 32 + lk * 8);
    // GEMM1: [64x64] @ [64x256]
    f32x4 acc0[16];
#pragma unroll
    for (int nt = 0; nt < 16; ++nt) {
        short8 bb0 = *(const short8*)(WT0 + (nt * 16 + lr) * 64 + lk * 8);
        short8 bb1 = *(const short8*)(WT0 + (nt * 16 + lr) * 64 + 32 + lk * 8);
        f32x4 z = (f32x4){0.f, 0.f, 0.f, 0.f};
        z = mfma_bf16(a0, bb0, z);
        acc0[nt] = mfma_bf16(a1, bb1, z);
    }
    unsigned short* h0 = &H0[wave][0];
#pragma unroll
    for (int nt = 0; nt < 16; ++nt) {
        int col = nt * 16 + lr;
        float bias = b0[col];
        int u = col >> 3;
#pragma unroll
        for (int j = 0; j < 4; ++j) {
            int row = lk * 4 + j;
            float v = gelu_f(acc0[nt][j] + bias);
            int us = (u & 16) | ((u ^ row) & 15);
            h0[row * 256 + us * 8 + (col & 7)] = f2bf(v);
        }
    }
    // GEMM2: [64x256] @ [256x64]
    f32x4 acc1[4];
#pragma unroll
    for (int nt = 0; nt < 4; ++nt) acc1[nt] = (f32x4){0.f, 0.f, 0.f, 0.f};
#pragma unroll
    for (int ks = 0; ks < 8; ++ks) {
        int u = ks * 4 + lk;
        int us = (u & 16) | ((u ^ lr) & 15);
        short8 aa = *(const short8*)(&h0[lr * 256 + us * 8]);
#pragma unroll
        for (int nt = 0; nt < 4; ++nt) {
            short8 bb = *(const short8*)(WT1 + (nt * 16 + lr) * 256 + ks * 32 + lk * 8);
            acc1[nt] = mfma_bf16(aa, bb, acc1[nt]);
        }
    }
    unsigned short* h1 = &H1[wave][0];
#pragma unroll
    for (int nt = 0; nt < 4; ++nt) {
        int col = nt * 16 + lr;
        float bias = b1[col];
#pragma unroll
        for (int j = 0; j < 4; ++j) {
            int row = lk * 4 + j;
            h1[row * 72 + col] = f2bf(gelu_f(acc1[nt][j] + bias));
        }
    }
    // final 64 -> 2: lane pairs split the dot
    int task = lane >> 1;          // 0..31
    int row = task >> 1;           // 0..15
    int o = task & 1;
    int t2 = lane & 1;
    float p = 0.0f;
#pragma unroll
    for (int d = 0; d < 32; ++d) {
        int dd = t2 * 32 + d;
        p += bf2f(h1[row * 72 + dd]) * W2[dd * 2 + o];
    }
    p += __shfl_xor(p, 1, 64);
    if (t2 == 0) {
        int gg = n0 + rb + row;
        if (o == 0) out[gg] = p + b2[0];
        else        out[BB * NT + gg] = __expf(0.5f * (p + b2[1]));
    }
}

extern "C" void kernel_launch(void* const* d_in, const int* in_sizes, int n_in,
                              void* d_out, int out_size, void* d_ws, size_t ws_size,
                              hipStream_t stream)
{
    (void)in_sizes; (void)n_in; (void)out_size; (void)ws_size;
    const float* s_ctx   = (const float*)d_in[0];
    const float* f_ctx   = (const float*)d_in[1];
    const float* s_test  = (const float*)d_in[2];
    const int*   valid   = (const int*)d_in[3];
    const float* emb_obs = (const float*)d_in[4];
    const float* ea_W0   = (const float*)d_in[5];
    const float* ea_b0   = (const float*)d_in[6];
    const float* ea_W1   = (const float*)d_in[7];
    const float* ea_b1   = (const float*)d_in[8];
    const float* ea_W2   = (const float*)d_in[9];
    const float* ea_b2   = (const float*)d_in[10];
    const float* ln_g    = (const float*)d_in[11];
    const float* ln_b    = (const float*)d_in[12];
    const float* blk_Wm0 = (const float*)d_in[13];
    const float* blk_bm0 = (const float*)d_in[14];
    const float* blk_Wm1 = (const float*)d_in[15];
    const float* blk_bm1 = (const float*)d_in[16];
    const float* blk_Wu0 = (const float*)d_in[17];
    const float* blk_bu0 = (const float*)d_in[18];
    const float* blk_Wu1 = (const float*)d_in[19];
    const float* blk_bu1 = (const float*)d_in[20];
    const float* blk_lng = (const float*)d_in[21];
    const float* blk_lnb = (const float*)d_in[22];
    const float* hd_W0   = (const float*)d_in[23];
    const float* hd_b0   = (const float*)d_in[24];
    const float* hd_W1   = (const float*)d_in[25];
    const float* hd_b1   = (const float*)d_in[26];
    const float* hd_W2   = (const float*)d_in[27];
    const float* hd_b2   = (const float*)d_in[28];

    char* p = (char*)d_ws;
    auto alloc = [&](size_t bytes) { char* r = p; p += (bytes + 255) & ~(size_t)255; return r; };
    unsigned short* nodesA = (unsigned short*)alloc((size_t)NODES * 64 * 2);
    unsigned short* nodesB = (unsigned short*)alloc((size_t)NODES * 64 * 2);
    unsigned short* aggb   = (unsigned short*)alloc((size_t)NODES * 64 * 2);
    float* dists   = (float*)alloc((size_t)NODES * KNN * 4);
    float* wbuf    = (float*)alloc((size_t)NODES * KNN * 4);
    int*   senders = (int*)alloc((size_t)NODES * KNN * 4);
    unsigned short* wtm0 = (unsigned short*)alloc((size_t)6 * 8192 * 2);
    unsigned short* wtm1 = (unsigned short*)alloc((size_t)6 * 8192 * 2);
    unsigned short* wtu0 = (unsigned short*)alloc((size_t)6 * 16384 * 2);
    unsigned short* wtu1 = (unsigned short*)alloc((size_t)6 * 8192 * 2);
    float* wdbuf = (float*)alloc((size_t)6 * 128 * 4);
    unsigned short* wte0 = (unsigned short*)alloc((size_t)8192 * 2);
    unsigned short* wte1 = (unsigned short*)alloc((size_t)32768 * 2);
    unsigned short* wte2 = (unsigned short*)alloc((size_t)8192 * 2);
    unsigned short* wth0 = (unsigned short*)alloc((size_t)16384 * 2);
    unsigned short* wth1 = (unsigned short*)alloc((size_t)16384 * 2);

    k_convw<<<1283, 256, 0, stream>>>(
        blk_Wm0, blk_Wm1, blk_Wu0, blk_Wu1,
        ea_W0, ea_W1, ea_W2, hd_W0, hd_W1,
        wtm0, wtm1, wtu0, wtu1, wdbuf, wte0, wte1, wte2, wth0, wth1);

    k_embed2<<<NODES / 64, 256, 0, stream>>>(s_ctx, f_ctx, s_test, emb_obs,
        wte0, ea_b0, wte1, ea_b1, wte2, ea_b2, ln_g, ln_b, nodesA);

    k_topk<<<NODES / 4, 256, 0, stream>>>(s_ctx, s_test, valid, dists, senders, wbuf);

    unsigned short* nin = nodesA; unsigned short* nout = nodesB;
    for (int i = 0; i < NBLK; ++i) {
        k_msg<<<NODES / NPW, 320, 0, stream>>>(nin, dists, senders, wbuf,
            wtm0 + (size_t)i * 8192, wdbuf + (size_t)i * 128, blk_bm0 + (size_t)i * 128,
            wtm1 + (size_t)i * 8192, blk_bm1 + (size_t)i * 64, aggb);
        k_upd<<<NODES / 64, 256, 0, stream>>>(nin, aggb,
            wtu0 + (size_t)i * 16384, blk_bu0 + (size_t)i * 128,
            wtu1 + (size_t)i * 8192, blk_bu1 + (size_t)i * 64,
            blk_lng + (size_t)i * 64, blk_lnb + (size_t)i * 64, nout);
        unsigned short* tmp = nin; nin = nout; nout = tmp;
    }

    k_head2<<<BB * NT / 64, 256, 0, stream>>>(nin, wth0, hd_b0, wth1, hd_b1,
                                              hd_W2, hd_b2, (float*)d_out);
}

// Round 4
// 636.627 us; speedup vs baseline: 3.3353x; 1.0467x over previous
//
#include <hip/hip_runtime.h>
#include <math.h>

#define BB 4
#define NC 4096
#define NT 1024
#define NN (NC + NT)      // 5120
#define NODES (BB * NN)   // 20480
#define DD 64
#define KNN 10
#define NBLK 6
#define BIGF 3.0e38f
#define EPW 80            // edges per k_msg workgroup (= 8 nodes)
#define NPW 8

typedef __attribute__((ext_vector_type(8))) short short8;
typedef __attribute__((ext_vector_type(4))) float f32x4;
typedef __attribute__((ext_vector_type(4))) int int4v;

__device__ __forceinline__ unsigned short f2bf(float f) {
    unsigned int u = __float_as_uint(f);
    unsigned int r = (u + 0x7fffu + ((u >> 16) & 1u)) >> 16;
    return (unsigned short)r;
}
__device__ __forceinline__ float bf2f(unsigned short h) {
    return __uint_as_float(((unsigned int)h) << 16);
}

// fast tanh-gelu: gelu(x) = x * (1 - 1/(1+e^{2z})), z = c0*(x + 0.044715 x^3)
__device__ __forceinline__ float gelu_f(float x) {
    const float c0 = 0.7978845608028654f;
    float x3 = x * x * x;
    float z2 = 2.0f * c0 * (x + 0.044715f * x3);
    float e = __expf(z2);
    float r = __builtin_amdgcn_rcpf(1.0f + e);
    return x - x * r;
}

__device__ __forceinline__ float wave_sum(float v) {
#pragma unroll
    for (int off = 32; off > 0; off >>= 1) v += __shfl_xor(v, off, 64);
    return v;
}

__device__ __forceinline__ f32x4 mfma_bf16(short8 a, short8 b, f32x4 c) {
    asm("v_mfma_f32_16x16x32_bf16 %0, %1, %2, %0" : "+v"(c) : "v"(a), "v"(b));
    return c;
}

// ---------------- weight convert: f32 -> bf16 transposed [N][K] ----------------
__global__ __launch_bounds__(256) void k_convw(
    const float* __restrict__ Wm0, const float* __restrict__ Wm1,
    const float* __restrict__ Wu0, const float* __restrict__ Wu1,
    const float* __restrict__ eW0, const float* __restrict__ eW1,
    const float* __restrict__ eW2,
    const float* __restrict__ hW0, const float* __restrict__ hW1,
    unsigned short* __restrict__ wtm0, unsigned short* __restrict__ wtm1,
    unsigned short* __restrict__ wtu0, unsigned short* __restrict__ wtu1,
    float* __restrict__ wd,
    unsigned short* __restrict__ wte0, unsigned short* __restrict__ wte1,
    unsigned short* __restrict__ wte2,
    unsigned short* __restrict__ wth0, unsigned short* __restrict__ wth1)
{
    int t = blockIdx.x * 256 + threadIdx.x;
    if (t < 49152) {                 // wtm0 [6][128][64] <- Wm0[i][k][n], k<64
        int i = t / 8192, r = t % 8192, n = r / 64, k = r % 64;
        wtm0[t] = f2bf(Wm0[(i * 65 + k) * 128 + n]);
    } else if (t < 98304) {          // wtm1 [6][64][128]
        int u = t - 49152;
        int i = u / 8192, r = u % 8192, n = r / 128, k = r % 128;
        wtm1[u] = f2bf(Wm1[(i * 128 + k) * 64 + n]);
    } else if (t < 196608) {         // wtu0 [6][128][128]
        int u = t - 98304;
        int i = u / 16384, r = u % 16384, n = r / 128, k = r % 128;
        wtu0[u] = f2bf(Wu0[(i * 128 + k) * 128 + n]);
    } else if (t < 245760) {         // wtu1 [6][64][128]
        int u = t - 196608;
        int i = u / 8192, r = u % 8192, n = r / 128, k = r % 128;
        wtu1[u] = f2bf(Wu1[(i * 128 + k) * 64 + n]);
    } else if (t < 246528) {         // wd [6][128] f32 <- Wm0[i][64][n]
        int u = t - 245760;
        int i = u / 128, n = u % 128;
        wd[u] = Wm0[(i * 65 + 64) * 128 + n];
    } else if (t < 254720) {         // wte0 [256][32], k<11 else 0
        int u = t - 246528;
        int n = u / 32, k = u % 32;
        wte0[u] = (k < 11) ? f2bf(eW0[k * 256 + n]) : 0;
    } else if (t < 287488) {         // wte1 [128][256]
        int u = t - 254720;
        int n = u / 256, k = u % 256;
        wte1[u] = f2bf(eW1[k * 128 + n]);
    } else if (t < 295680) {         // wte2 [64][128]
        int u = t - 287488;
        int n = u / 128, k = u % 128;
        wte2[u] = f2bf(eW2[k * 64 + n]);
    } else if (t < 312064) {         // wth0 [256][64]
        int u = t - 295680;
        int n = u / 64, k = u % 64;
        wth0[u] = f2bf(hW0[k * 256 + n]);
    } else if (t < 328448) {         // wth1 [64][256]
        int u = t - 312064;
        int n = u / 256, k = u % 256;
        wth1[u] = f2bf(hW1[k * 64 + n]);
    }
}

// ---------------- prep: pack sender coords into aligned float4 ----------------
__global__ __launch_bounds__(256) void k_prep(
    const float* __restrict__ sctx, float4* __restrict__ s4)
{
    int t = blockIdx.x * 256 + threadIdx.x;
    if (t < BB * NC) {
        float x = sctx[t * 3], y = sctx[t * 3 + 1], z = sctx[t * 3 + 2];
        s4[t] = make_float4(x, y, z, 0.0f);
    }
}

// ---------------- embed (MFMA): 64 nodes per WG, 4 waves, barrier-free ----------------
__global__ __launch_bounds__(256) void k_embed2(
    const float* __restrict__ s_ctx, const float* __restrict__ f_ctx,
    const float* __restrict__ s_test, const float* __restrict__ emb_obs,
    const unsigned short* __restrict__ WT0, const float* __restrict__ b0,
    const unsigned short* __restrict__ WT1, const float* __restrict__ b1,
    const unsigned short* __restrict__ WT2, const float* __restrict__ b2,
    const float* __restrict__ g, const float* __restrict__ bta,
    unsigned short* __restrict__ nodes)
{
    __shared__ unsigned short H0[4][16 * 256];
    __shared__ unsigned short H1[4][16 * 128];
    int t = threadIdx.x;
    int wave = t >> 6, lane = t & 63, lr = lane & 15, lk = lane >> 4;
    int rb = wave * 16;
    int n0 = blockIdx.x * 64;
    int bq = n0 / NN, nloc0 = n0 % NN;
    bool is_ctx = nloc0 < NC;
    int nr = nloc0 + rb + lr;
    float xv[8];
#pragma unroll
    for (int j = 0; j < 8; ++j) xv[j] = 0.0f;
    if (lk == 0) {
        const float* eb = emb_obs + (is_ctx ? 4 : 0);
        xv[0] = eb[0]; xv[1] = eb[1]; xv[2] = eb[2]; xv[3] = eb[3];
        if (is_ctx) {
            const float* sp = s_ctx + ((size_t)(bq * NC + nr)) * 3;
            const float* fp = f_ctx + ((size_t)(bq * NC + nr)) * 4;
            xv[4] = sp[0]; xv[5] = sp[1]; xv[6] = sp[2]; xv[7] = fp[0];
        } else {
            const float* sp = s_test + ((size_t)(bq * NT + nr - NC)) * 3;
            xv[4] = sp[0]; xv[5] = sp[1]; xv[6] = sp[2];
        }
    } else if (lk == 1 && is_ctx) {
        const float* fp = f_ctx + ((size_t)(bq * NC + nr)) * 4;
        xv[0] = fp[1]; xv[1] = fp[2]; xv[2] = fp[3];
    }
    short8 a;
#pragma unroll
    for (int j = 0; j < 8; ++j) a[j] = (short)f2bf(xv[j]);

    f32x4 acc0[16];
#pragma unroll
    for (int nt = 0; nt < 16; ++nt) {
        short8 bb = *(const short8*)(WT0 + (nt * 16 + lr) * 32 + lk * 8);
        f32x4 z = (f32x4){0.f, 0.f, 0.f, 0.f};
        acc0[nt] = mfma_bf16(a, bb, z);
    }
    unsigned short* h0 = &H0[wave][0];
#pragma unroll
    for (int nt = 0; nt < 16; ++nt) {
        int col = nt * 16 + lr;
        float bias = b0[col];
        int u = col >> 3;
#pragma unroll
        for (int j = 0; j < 4; ++j) {
            int row = lk * 4 + j;
            float v = gelu_f(acc0[nt][j] + bias);
            int us = (u & 16) | ((u ^ row) & 15);
            h0[row * 256 + us * 8 + (col & 7)] = f2bf(v);
        }
    }
    f32x4 acc1[8];
#pragma unroll
    for (int nt = 0; nt < 8; ++nt) acc1[nt] = (f32x4){0.f, 0.f, 0.f, 0.f};
#pragma unroll
    for (int ks = 0; ks < 8; ++ks) {
        int u = ks * 4 + lk;
        int us = (u & 16) | ((u ^ lr) & 15);
        short8 aa = *(const short8*)(&h0[lr * 256 + us * 8]);
#pragma unroll
        for (int nt = 0; nt < 8; ++nt) {
            short8 bb = *(const short8*)(WT1 + (nt * 16 + lr) * 256 + ks * 32 + lk * 8);
            acc1[nt] = mfma_bf16(aa, bb, acc1[nt]);
        }
    }
    unsigned short* h1 = &H1[wave][0];
#pragma unroll
    for (int nt = 0; nt < 8; ++nt) {
        int col = nt * 16 + lr;
        float bias = b1[col];
        int u = col >> 3;
#pragma unroll
        for (int j = 0; j < 4; ++j) {
            int row = lk * 4 + j;
            float v = gelu_f(acc1[nt][j] + bias);
            int us = (u ^ row) & 15;
            h1[row * 128 + us * 8 + (col & 7)] = f2bf(v);
        }
    }
    f32x4 acc2[4];
#pragma unroll
    for (int nt = 0; nt < 4; ++nt) acc2[nt] = (f32x4){0.f, 0.f, 0.f, 0.f};
#pragma unroll
    for (int ks = 0; ks < 4; ++ks) {
        int u = ks * 4 + lk;
        int us = (u ^ lr) & 15;
        short8 aa = *(const short8*)(&h1[lr * 128 + us * 8]);
#pragma unroll
        for (int nt = 0; nt < 4; ++nt) {
            short8 bb = *(const short8*)(WT2 + (nt * 16 + lr) * 128 + ks * 32 + lk * 8);
            acc2[nt] = mfma_bf16(aa, bb, acc2[nt]);
        }
    }
    float vals[4][4];
#pragma unroll
    for (int j = 0; j < 4; ++j)
#pragma unroll
        for (int nt = 0; nt < 4; ++nt)
            vals[j][nt] = acc2[nt][j] + b2[nt * 16 + lr];
#pragma unroll
    for (int j = 0; j < 4; ++j) {
        float s = vals[j][0] + vals[j][1] + vals[j][2] + vals[j][3];
#pragma unroll
        for (int m = 1; m < 16; m <<= 1) s += __shfl_xor(s, m, 64);
        float mean = s * (1.0f / 64.0f);
        float vs = 0.0f;
#pragma unroll
        for (int nt = 0; nt < 4; ++nt) { float d = vals[j][nt] - mean; vs += d * d; }
#pragma unroll
        for (int m = 1; m < 16; m <<= 1) vs += __shfl_xor(vs, m, 64);
        float inv = rsqrtf(vs * (1.0f / 64.0f) + 1e-6f);
        int node = n0 + rb + lk * 4 + j;
#pragma unroll
        for (int nt = 0; nt < 4; ++nt) {
            int col = nt * 16 + lr;
            float o = (vals[j][nt] - mean) * inv * g[col] + bta[col];
            nodes[(size_t)node * 64 + col] = f2bf(o);
        }
    }
}

// ---------------- top-K: one wave per receiver, branchless med3 insert ----------------
__global__ __launch_bounds__(256) void k_topk(
    const float4* __restrict__ s4, const float* __restrict__ s_ctx,
    const float* __restrict__ s_test, const int* __restrict__ valid_lens,
    float* __restrict__ dists, int* __restrict__ senders, float* __restrict__ wout)
{
    __shared__ float cd[4 * 64 * KNN];
    __shared__ float seld[4][12];
    __shared__ int   seli[4][12];
    __shared__ int   eqis[4][12];
    int wave = threadIdx.x >> 6;
    int lane = threadIdx.x & 63;
    int r = blockIdx.x * 4 + wave;
    int b = r / NN, n = r % NN;
    float px, py, pz;
    if (n < NC) {
        const float* p = &s_ctx[(size_t)(b * NC + n) * 3];
        px = p[0]; py = p[1]; pz = p[2];
    } else {
        const float* p = &s_test[(size_t)(b * NT + (n - NC)) * 3];
        px = p[0]; py = p[1]; pz = p[2];
    }
    int vl = valid_lens[b];
    const float4* sc = s4 + (size_t)b * NC;
    float v_[64];
    float b_[KNN];
#pragma unroll
    for (int k = 0; k < KNN; ++k) b_[k] = BIGF;
#pragma unroll
    for (int i = 0; i < 64; ++i) {
        int j = lane + (i << 6);
        float4 s = sc[j];
        float dx = px - s.x, dy = py - s.y, dz = pz - s.z;
        float d2 = fmaf(dx, dx, fmaf(dy, dy, dz * dz));
        d2 = (j < vl) ? d2 : BIGF;
        v_[i] = d2;
        // branchless sorted insert: new[k] = med3(old[k-1], old[k], d2)
#pragma unroll
        for (int k = KNN - 1; k >= 1; --k)
            b_[k] = __builtin_amdgcn_fmed3f(b_[k - 1], b_[k], d2);
        b_[0] = fminf(b_[0], d2);
    }
    // merge per-lane sorted lists (values only) to get the global 10 smallest
    int base = (wave * 64 + lane) * KNN;
#pragma unroll
    for (int k = 0; k < KNN; ++k) cd[base + k] = b_[k];
    __builtin_amdgcn_wave_barrier();
    int head = 0;
    float myd = 0.0f;
#pragma unroll
    for (int rr = 0; rr < KNN; ++rr) {
        float v = cd[base + head];
        float mv = v;
#pragma unroll
        for (int off = 32; off > 0; off >>= 1) mv = fminf(mv, __shfl_xor(mv, off, 64));
        unsigned long long ball = __ballot(v == mv);
        int win = __ffsll(ball) - 1;
        if (lane == win) head++;
        if (lane == rr) myd = mv;
    }
    float T = __shfl(myd, 9, 64);           // 10th smallest value
    float d2min = __shfl(myd, 0, 64);       // smallest value
    int m = __popcll(__ballot(lane < KNN && myd < T));   // # strictly below T
    // pass B: collect indices. strictly-less always selected; ==T ties in index order
    unsigned long long below = (lane == 63) ? 0x7FFFFFFFFFFFFFFFull
                                            : ((1ull << lane) - 1);
    int cless = 0, ceq = 0;
#pragma unroll
    for (int i = 0; i < 64; ++i) {
        float v = v_[i];
        unsigned long long ml = __ballot(v < T);
        unsigned long long me = __ballot(v == T);
        if (v < T) {
            int slot = cless + __popcll(ml & below);
            seld[wave][slot] = v;
            seli[wave][slot] = lane + (i << 6);
        }
        if (v == T) {
            int q = ceq + __popcll(me & below);
            if (q < 12) eqis[wave][q] = lane + (i << 6);
        }
        cless += __popcll(ml);
        ceq += __popcll(me);
    }
    __builtin_amdgcn_wave_barrier();
    float e = 0.0f, d = 0.0f;
    int isel = 0;
    float dmin = sqrtf(d2min);
    if (lane < KNN) {
        float vsel;
        if (lane < m) { vsel = seld[wave][lane]; isel = seli[wave][lane]; }
        else          { vsel = T;                isel = eqis[wave][lane - m]; }
        d = sqrtf(vsel);
        e = __expf(-(d - dmin));
    }
    float ssum = wave_sum(e);
    if (lane < KNN) {
        size_t o = (size_t)r * KNN + lane;
        dists[o] = d;
        senders[o] = isel;
        wout[o] = e / ssum;
    }
}

// ---------------- message MLP + aggregate: 8 nodes (80 edges) per WG ----------------
__global__ __launch_bounds__(320) void k_msg(
    const unsigned short* __restrict__ nodes,
    const float* __restrict__ dists, const int* __restrict__ senders,
    const float* __restrict__ w,
    const unsigned short* __restrict__ WT0,     // [128][64]
    const float* __restrict__ wd,               // [128]
    const float* __restrict__ bm0,
    const unsigned short* __restrict__ WT1,     // [64][128]
    const float* __restrict__ bm1,
    unsigned short* __restrict__ agg)
{
    __shared__ unsigned short A[EPW * 64];
    __shared__ unsigned short H[5][16 * 128];
    __shared__ float MW[EPW * 64];
    __shared__ int   sid[EPW];
    __shared__ float sdist[EPW], sw[EPW];

    int t = threadIdx.x;
    int node0 = blockIdx.x * NPW;
    int b = node0 / NN;
    int e0 = node0 * KNN;
    if (t < EPW) {
        sid[t]   = senders[e0 + t];
        sdist[t] = dists[e0 + t];
        sw[t]    = w[e0 + t];
    }
    __syncthreads();
    for (int c = t; c < EPW * 8; c += 320) {
        int row = c >> 3, u = c & 7;
        int4v v = *(const int4v*)(nodes + ((size_t)(b * NN + sid[row])) * 64 + u * 8);
        int su = u ^ (row & 7);
        *(int4v*)(&A[row * 64 + su * 8]) = v;
    }
    __syncthreads();

    int wave = t >> 6, lane = t & 63;
    int rb = wave * 16;
    int lr = lane & 15, lk = lane >> 4;

    f32x4 acc[8];
#pragma unroll
    for (int nt = 0; nt < 8; ++nt) acc[nt] = (f32x4){0.f, 0.f, 0.f, 0.f};
#pragma unroll
    for (int ks = 0; ks < 2; ++ks) {
        int row = rb + lr;
        int u = (ks * 4 + lk) ^ (row & 7);
        short8 a = *(const short8*)(&A[row * 64 + u * 8]);
#pragma unroll
        for (int nt = 0; nt < 8; ++nt) {
            short8 bb = *(const short8*)(WT0 + (nt * 16 + lr) * 64 + ks * 32 + lk * 8);
            acc[nt] = mfma_bf16(a, bb, acc[nt]);
        }
    }
    unsigned short* h = &H[wave][0];
    float sd[4];
#pragma unroll
    for (int j = 0; j < 4; ++j) sd[j] = sdist[rb + lk * 4 + j];
#pragma unroll
    for (int nt = 0; nt < 8; ++nt) {
        int colg = nt * 16 + lr;
        float bias = bm0[colg];
        float wdc = wd[colg];
#pragma unroll
        for (int j = 0; j < 4; ++j) {
            int lrow = lk * 4 + j;
            float v = acc[nt][j] + bias + sd[j] * wdc;
            v = gelu_f(v);
            int un = (colg >> 3) ^ lrow;
            h[lrow * 128 + un * 8 + (colg & 7)] = f2bf(v);
        }
    }
    f32x4 acc2[4];
#pragma unroll
    for (int nt = 0; nt < 4; ++nt) acc2[nt] = (f32x4){0.f, 0.f, 0.f, 0.f};
#pragma unroll
    for (int ks = 0; ks < 4; ++ks) {
        int un = (ks * 4 + lk) ^ lr;
        short8 a = *(const short8*)(&h[lr * 128 + un * 8]);
#pragma unroll
        for (int nt = 0; nt < 4; ++nt) {
            short8 bb = *(const short8*)(WT1 + (nt * 16 + lr) * 128 + ks * 32 + lk * 8);
            acc2[nt] = mfma_bf16(a, bb, acc2[nt]);
        }
    }
    float swr[4];
#pragma unroll
    for (int j = 0; j < 4; ++j) swr[j] = sw[rb + lk * 4 + j];
#pragma unroll
    for (int nt = 0; nt < 4; ++nt) {
        int colg = nt * 16 + lr;
        float bias = bm1[colg];
#pragma unroll
        for (int j = 0; j < 4; ++j) {
            int row = rb + lk * 4 + j;
            MW[row * 64 + colg] = (acc2[nt][j] + bias) * swr[j];
        }
    }
    __syncthreads();
    for (int o = t; o < NPW * 64; o += 320) {
        int n = o >> 6, c = o & 63;
        float s = 0.0f;
#pragma unroll
        for (int k = 0; k < KNN; ++k) s += MW[(n * KNN + k) * 64 + c];
        agg[((size_t)(node0 + n)) * 64 + c] = f2bf(s);
    }
}

// ---------------- update MLP + residual + LN: 64 nodes per WG ----------------
__global__ __launch_bounds__(256) void k_upd(
    const unsigned short* __restrict__ nodes_in,
    const unsigned short* __restrict__ agg,
    const unsigned short* __restrict__ WTu0,      // [128][128]
    const float* __restrict__ bu0,
    const unsigned short* __restrict__ WTu1,      // [64][128]
    const float* __restrict__ bu1,
    const float* __restrict__ lng, const float* __restrict__ lnb,
    unsigned short* __restrict__ nodes_out)
{
    __shared__ unsigned short U[64 * 128];
    __shared__ unsigned short H[4][16 * 128];
    int t = threadIdx.x;
    int wave = t >> 6, lane = t & 63;
    int n0 = blockIdx.x * 64;
    for (int c = t; c < 64 * 16; c += 256) {
        int row = c >> 4, u = c & 15;
        int4v v;
        if (u < 8) v = *(const int4v*)(nodes_in + ((size_t)(n0 + row)) * 64 + u * 8);
        else       v = *(const int4v*)(agg + ((size_t)(n0 + row)) * 64 + (u - 8) * 8);
        *(int4v*)(&U[row * 128 + (u ^ (row & 15)) * 8]) = v;
    }
    __syncthreads();
    int rb = wave * 16;
    int lr = lane & 15, lk = lane >> 4;
    f32x4 acc[8];
#pragma unroll
    for (int nt = 0; nt < 8; ++nt) acc[nt] = (f32x4){0.f, 0.f, 0.f, 0.f};
#pragma unroll
    for (int ks = 0; ks < 4; ++ks) {
        int row = rb + lr;
        int un = (ks * 4 + lk) ^ (row & 15);
        short8 a = *(const short8*)(&U[row * 128 + un * 8]);
#pragma unroll
        for (int nt = 0; nt < 8; ++nt) {
            short8 bb = *(const short8*)(WTu0 + (nt * 16 + lr) * 128 + ks * 32 + lk * 8);
            acc[nt] = mfma_bf16(a, bb, acc[nt]);
        }
    }
    unsigned short* h = &H[wave][0];
#pragma unroll
    for (int nt = 0; nt < 8; ++nt) {
        int colg = nt * 16 + lr;
        float bias = bu0[colg];
#pragma unroll
        for (int j = 0; j < 4; ++j) {
            int lrow = lk * 4 + j;
            float v = gelu_f(acc[nt][j] + bias);
            int un = (colg >> 3) ^ lrow;
            h[lrow * 128 + un * 8 + (colg & 7)] = f2bf(v);
        }
    }
    f32x4 acc2[4];
#pragma unroll
    for (int nt = 0; nt < 4; ++nt) acc2[nt] = (f32x4){0.f, 0.f, 0.f, 0.f};
#pragma unroll
    for (int ks = 0; ks < 4; ++ks) {
        int un = (ks * 4 + lk) ^ lr;
        short8 a = *(const short8*)(&h[lr * 128 + un * 8]);
#pragma unroll
        for (int nt = 0; nt < 4; ++nt) {
            short8 bb = *(const short8*)(WTu1 + (nt * 16 + lr) * 128 + ks * 32 + lk * 8);
            acc2[nt] = mfma_bf16(a, bb, acc2[nt]);
        }
    }
    float vals[4][4];
#pragma unroll
    for (int j = 0; j < 4; ++j) {
        int row = rb + lk * 4 + j;
#pragma unroll
        for (int nt = 0; nt < 4; ++nt) {
            int col = nt * 16 + lr;
            int un = (col >> 3) ^ (row & 15);
            float x = bf2f(U[row * 128 + un * 8 + (col & 7)]);
            vals[j][nt] = x + acc2[nt][j] + bu1[col];
        }
    }
#pragma unroll
    for (int j = 0; j < 4; ++j) {
        int row = rb + lk * 4 + j;
        float s = vals[j][0] + vals[j][1] + vals[j][2] + vals[j][3];
#pragma unroll
        for (int m = 1; m < 16; m <<= 1) s += __shfl_xor(s, m, 64);
        float mean = s * (1.0f / 64.0f);
        float vs = 0.0f;
#pragma unroll
        for (int nt = 0; nt < 4; ++nt) { float d = vals[j][nt] - mean; vs += d * d; }
#pragma unroll
        for (int m = 1; m < 16; m <<= 1) vs += __shfl_xor(vs, m, 64);
        float inv = rsqrtf(vs * (1.0f / 64.0f) + 1e-6f);
#pragma unroll
        for (int nt = 0; nt < 4; ++nt) {
            int col = nt * 16 + lr;
            float o = (vals[j][nt] - mean) * inv * lng[col] + lnb[col];
            nodes_out[((size_t)(n0 + row)) * 64 + col] = f2bf(o);
        }
    }
}

// ---------------- head (MFMA): 64 test nodes per WG ----------------
__global__ __launch_bounds__(256) void k_head2(
    const unsigned short* __restrict__ nodes,
    const unsigned short* __restrict__ WT0, const float* __restrict__ b0,
    const unsigned short* __restrict__ WT1, const float* __restrict__ b1,
    const float* __restrict__ W2, const float* __restrict__ b2,
    float* __restrict__ out)
{
    __shared__ unsigned short H0[4][16 * 256];
    __shared__ unsigned short H1[4][16 * 72];
    int t = threadIdx.x;
    int wave = t >> 6, lane = t & 63, lr = lane & 15, lk = lane >> 4;
    int rb = wave * 16;
    int n0 = blockIdx.x * 64;
    int bq = n0 / NT, nloc0 = n0 % NT;
    size_t grow = (size_t)(bq * NN + NC + nloc0 + rb);
    short8 a0 = *(const short8*)(nodes + (grow + lr) * 64 + lk * 8);
    short8 a1 = *(const short8*)(nodes + (grow + lr) * 64 + 32 + lk * 8);
    f32x4 acc0[16];
#pragma unroll
    for (int nt = 0; nt < 16; ++nt) {
        short8 bb0 = *(const short8*)(WT0 + (nt * 16 + lr) * 64 + lk * 8);
        short8 bb1 = *(const short8*)(WT0 + (nt * 16 + lr) * 64 + 32 + lk * 8);
        f32x4 z = (f32x4){0.f, 0.f, 0.f, 0.f};
        z = mfma_bf16(a0, bb0, z);
        acc0[nt] = mfma_bf16(a1, bb1, z);
    }
    unsigned short* h0 = &H0[wave][0];
#pragma unroll
    for (int nt = 0; nt < 16; ++nt) {
        int col = nt * 16 + lr;
        float bias = b0[col];
        int u = col >> 3;
#pragma unroll
        for (int j = 0; j < 4; ++j) {
            int row = lk * 4 + j;
            float v = gelu_f(acc0[nt][j] + bias);
            int us = (u & 16) | ((u ^ row) & 15);
            h0[row * 256 + us * 8 + (col & 7)] = f2bf(v);
        }
    }
    f32x4 acc1[4];
#pragma unroll
    for (int nt = 0; nt < 4; ++nt) acc1[nt] = (f32x4){0.f, 0.f, 0.f, 0.f};
#pragma unroll
    for (int ks = 0; ks < 8; ++ks) {
        int u = ks * 4 + lk;
        int us = (u & 16) | ((u ^ lr) & 15);
        short8 aa = *(const short8*)(&h0[lr * 256 + us * 8]);
#pragma unroll
        for (int nt = 0; nt < 4; ++nt) {
            short8 bb = *(const short8*)(WT1 + (nt * 16 + lr) * 256 + ks * 32 + lk * 8);
            acc1[nt] = mfma_bf16(aa, bb, acc1[nt]);
        }
    }
    unsigned short* h1 = &H1[wave][0];
#pragma unroll
    for (int nt = 0; nt < 4; ++nt) {
        int col = nt * 16 + lr;
        float bias = b1[col];
#pragma unroll
        for (int j = 0; j < 4; ++j) {
            int row = lk * 4 + j;
            h1[row * 72 + col] = f2bf(gelu_f(acc1[nt][j] + bias));
        }
    }
    int task = lane >> 1;
    int row = task >> 1;
    int o = task & 1;
    int t2 = lane & 1;
    float p = 0.0f;
#pragma unroll
    for (int d = 0; d < 32; ++d) {
        int dd = t2 * 32 + d;
        p += bf2f(h1[row * 72 + dd]) * W2[dd * 2 + o];
    }
    p += __shfl_xor(p, 1, 64);
    if (t2 == 0) {
        int gg = n0 + rb + row;
        if (o == 0) out[gg] = p + b2[0];
        else        out[BB * NT + gg] = __expf(0.5f * (p + b2[1]));
    }
}

extern "C" void kernel_launch(void* const* d_in, const int* in_sizes, int n_in,
                              void* d_out, int out_size, void* d_ws, size_t ws_size,
                              hipStream_t stream)
{
    (void)in_sizes; (void)n_in; (void)out_size; (void)ws_size;
    const float* s_ctx   = (const float*)d_in[0];
    const float* f_ctx   = (const float*)d_in[1];
    const float* s_test  = (const float*)d_in[2];
    const int*   valid   = (const int*)d_in[3];
    const float* emb_obs = (const float*)d_in[4];
    const float* ea_W0   = (const float*)d_in[5];
    const float* ea_b0   = (const float*)d_in[6];
    const float* ea_W1   = (const float*)d_in[7];
    const float* ea_b1   = (const float*)d_in[8];
    const float* ea_W2   = (const float*)d_in[9];
    const float* ea_b2   = (const float*)d_in[10];
    const float* ln_g    = (const float*)d_in[11];
    const float* ln_b    = (const float*)d_in[12];
    const float* blk_Wm0 = (const float*)d_in[13];
    const float* blk_bm0 = (const float*)d_in[14];
    const float* blk_Wm1 = (const float*)d_in[15];
    const float* blk_bm1 = (const float*)d_in[16];
    const float* blk_Wu0 = (const float*)d_in[17];
    const float* blk_bu0 = (const float*)d_in[18];
    const float* blk_Wu1 = (const float*)d_in[19];
    const float* blk_bu1 = (const float*)d_in[20];
    const float* blk_lng = (const float*)d_in[21];
    const float* blk_lnb = (const float*)d_in[22];
    const float* hd_W0   = (const float*)d_in[23];
    const float* hd_b0   = (const float*)d_in[24];
    const float* hd_W1   = (const float*)d_in[25];
    const float* hd_b1   = (const float*)d_in[26];
    const float* hd_W2   = (const float*)d_in[27];
    const float* hd_b2   = (const float*)d_in[28];

    char* p = (char*)d_ws;
    auto alloc = [&](size_t bytes) { char* r = p; p += (bytes + 255) & ~(size_t)255; return r; };
    unsigned short* nodesA = (unsigned short*)alloc((size_t)NODES * 64 * 2);
    unsigned short* nodesB = (unsigned short*)alloc((size_t)NODES * 64 * 2);
    unsigned short* aggb   = (unsigned short*)alloc((size_t)NODES * 64 * 2);
    float* dists   = (float*)alloc((size_t)NODES * KNN * 4);
    float* wbuf    = (float*)alloc((size_t)NODES * KNN * 4);
    int*   senders = (int*)alloc((size_t)NODES * KNN * 4);
    unsigned short* wtm0 = (unsigned short*)alloc((size_t)6 * 8192 * 2);
    unsigned short* wtm1 = (unsigned short*)alloc((size_t)6 * 8192 * 2);
    unsigned short* wtu0 = (unsigned short*)alloc((size_t)6 * 16384 * 2);
    unsigned short* wtu1 = (unsigned short*)alloc((size_t)6 * 8192 * 2);
    float* wdbuf = (float*)alloc((size_t)6 * 128 * 4);
    unsigned short* wte0 = (unsigned short*)alloc((size_t)8192 * 2);
    unsigned short* wte1 = (unsigned short*)alloc((size_t)32768 * 2);
    unsigned short* wte2 = (unsigned short*)alloc((size_t)8192 * 2);
    unsigned short* wth0 = (unsigned short*)alloc((size_t)16384 * 2);
    unsigned short* wth1 = (unsigned short*)alloc((size_t)16384 * 2);
    float4* s4 = (float4*)alloc((size_t)BB * NC * 16);

    k_convw<<<1283, 256, 0, stream>>>(
        blk_Wm0, blk_Wm1, blk_Wu0, blk_Wu1,
        ea_W0, ea_W1, ea_W2, hd_W0, hd_W1,
        wtm0, wtm1, wtu0, wtu1, wdbuf, wte0, wte1, wte2, wth0, wth1);

    k_prep<<<(BB * NC + 255) / 256, 256, 0, stream>>>(s_ctx, s4);

    k_embed2<<<NODES / 64, 256, 0, stream>>>(s_ctx, f_ctx, s_test, emb_obs,
        wte0, ea_b0, wte1, ea_b1, wte2, ea_b2, ln_g, ln_b, nodesA);

    k_topk<<<NODES / 4, 256, 0, stream>>>(s4, s_ctx, s_test, valid,
                                          dists, senders, wbuf);

    unsigned short* nin = nodesA; unsigned short* nout = nodesB;
    for (int i = 0; i < NBLK; ++i) {
        k_msg<<<NODES / NPW, 320, 0, stream>>>(nin, dists, senders, wbuf,
            wtm0 + (size_t)i * 8192, wdbuf + (size_t)i * 128, blk_bm0 + (size_t)i * 128,
            wtm1 + (size_t)i * 8192, blk_bm1 + (size_t)i * 64, aggb);
        k_upd<<<NODES / 64, 256, 0, stream>>>(nin, aggb,
            wtu0 + (size_t)i * 16384, blk_bu0 + (size_t)i * 128,
            wtu1 + (size_t)i * 8192, blk_bu1 + (size_t)i * 64,
            blk_lng + (size_t)i * 64, blk_lnb + (size_t)i * 64, nout);
        unsigned short* tmp = nin; nin = nout; nout = tmp;
    }

    k_head2<<<BB * NT / 64, 256, 0, stream>>>(nin, wth0, hd_b0, wth1, hd_b1,
                                              hd_W2, hd_b2, (float*)d_out);
}

// Round 5
// 388.118 us; speedup vs baseline: 5.4709x; 1.6403x over previous
//
#include <hip/hip_runtime.h>
#include <math.h>

#define BB 4
#define NC 4096
#define NT 1024
#define NN (NC + NT)      // 5120
#define NODES (BB * NN)   // 20480
#define DD 64
#define KNN 10
#define NBLK 6
#define BIGF 3.0e38f

typedef __attribute__((ext_vector_type(8))) short short8;
typedef __attribute__((ext_vector_type(4))) float f32x4;
typedef __attribute__((ext_vector_type(4))) int int4v;

__device__ __forceinline__ unsigned short f2bf(float f) {
    unsigned int u = __float_as_uint(f);
    unsigned int r = (u + 0x7fffu + ((u >> 16) & 1u)) >> 16;
    return (unsigned short)r;
}
__device__ __forceinline__ float bf2f(unsigned short h) {
    return __uint_as_float(((unsigned int)h) << 16);
}

__device__ __forceinline__ float gelu_f(float x) {
    const float c0 = 0.7978845608028654f;
    float x3 = x * x * x;
    float z2 = 2.0f * c0 * (x + 0.044715f * x3);
    float e = __expf(z2);
    float r = __builtin_amdgcn_rcpf(1.0f + e);
    return x - x * r;
}

__device__ __forceinline__ float wave_sum(float v) {
#pragma unroll
    for (int off = 32; off > 0; off >>= 1) v += __shfl_xor(v, off, 64);
    return v;
}

__device__ __forceinline__ f32x4 mfma_bf16(short8 a, short8 b, f32x4 c) {
    asm("v_mfma_f32_16x16x32_bf16 %0, %1, %2, %0" : "+v"(c) : "v"(a), "v"(b));
    return c;
}

// perm(col) = (col&15)*8 + (col>>4)  (C-frag lane-contiguous store order, 128-wide)
// invperm(cp) = (cp&7)*16 + (cp>>3)

// ---------------- weight convert ----------------
__global__ __launch_bounds__(256) void k_convw(
    const float* __restrict__ Wm0, const float* __restrict__ Wm1,
    const float* __restrict__ Wu0, const float* __restrict__ Wu1,
    const float* __restrict__ bm0,
    const float* __restrict__ eW0, const float* __restrict__ eW1,
    const float* __restrict__ eW2,
    const float* __restrict__ hW0, const float* __restrict__ hW1,
    unsigned short* __restrict__ wtm0, unsigned short* __restrict__ wtm1p,
    unsigned short* __restrict__ wtu0, unsigned short* __restrict__ wtu1,
    float* __restrict__ wdp, float* __restrict__ bm0p,
    unsigned short* __restrict__ wte0, unsigned short* __restrict__ wte1,
    unsigned short* __restrict__ wte2,
    unsigned short* __restrict__ wth0, unsigned short* __restrict__ wth1)
{
    int t = blockIdx.x * 256 + threadIdx.x;
    if (t < 49152) {                 // wtm0 [6][128][64] <- Wm0[i][k][n], k<64
        int i = t / 8192, r = t % 8192, n = r / 64, k = r % 64;
        wtm0[t] = f2bf(Wm0[(i * 65 + k) * 128 + n]);
    } else if (t < 98304) {          // wtm1p [6][64][128]: [n][cp] = Wm1[i][invperm(cp)][n]
        int u = t - 49152;
        int i = u / 8192, r = u % 8192, n = r / 128, cp = r % 128;
        int col = ((cp & 7) << 4) | (cp >> 3);
        wtm1p[u] = f2bf(Wm1[(i * 128 + col) * 64 + n]);
    } else if (t < 196608) {         // wtu0 [6][128][128]
        int u = t - 98304;
        int i = u / 16384, r = u % 16384, n = r / 128, k = r % 128;
        wtu0[u] = f2bf(Wu0[(i * 128 + k) * 128 + n]);
    } else if (t < 245760) {         // wtu1 [6][64][128]
        int u = t - 196608;
        int i = u / 8192, r = u % 8192, n = r / 128, k = r % 128;
        wtu1[u] = f2bf(Wu1[(i * 128 + k) * 64 + n]);
    } else if (t < 246528) {         // wdp [6][128] perm
        int u = t - 245760;
        int i = u / 128, cp = u % 128;
        int col = ((cp & 7) << 4) | (cp >> 3);
        wdp[u] = Wm0[(i * 65 + 64) * 128 + col];
    } else if (t < 247296) {         // bm0p [6][128] perm
        int u = t - 246528;
        int i = u / 128, cp = u % 128;
        int col = ((cp & 7) << 4) | (cp >> 3);
        bm0p[u] = bm0[i * 128 + col];
    } else if (t < 255488) {         // wte0 [256][32], k<11 else 0
        int u = t - 247296;
        int n = u / 32, k = u % 32;
        wte0[u] = (k < 11) ? f2bf(eW0[k * 256 + n]) : 0;
    } else if (t < 288256) {         // wte1 [128][256]
        int u = t - 255488;
        int n = u / 256, k = u % 256;
        wte1[u] = f2bf(eW1[k * 128 + n]);
    } else if (t < 296448) {         // wte2 [64][128]
        int u = t - 288256;
        int n = u / 128, k = u % 128;
        wte2[u] = f2bf(eW2[k * 64 + n]);
    } else if (t < 312832) {         // wth0 [256][64]
        int u = t - 296448;
        int n = u / 64, k = u % 64;
        wth0[u] = f2bf(hW0[k * 256 + n]);
    } else if (t < 329216) {         // wth1 [64][256]
        int u = t - 312832;
        int n = u / 256, k = u % 256;
        wth1[u] = f2bf(hW1[k * 64 + n]);
    }
}

// ---------------- prep: pack sender coords into aligned float4 ----------------
__global__ __launch_bounds__(256) void k_prep(
    const float* __restrict__ sctx, float4* __restrict__ s4)
{
    int t = blockIdx.x * 256 + threadIdx.x;
    if (t < BB * NC) {
        float x = sctx[t * 3], y = sctx[t * 3 + 1], z = sctx[t * 3 + 2];
        s4[t] = make_float4(x, y, z, 0.0f);
    }
}

// ---------------- embed (MFMA) + P0: 64 nodes per WG, 4 waves, barrier-free ----------------
__global__ __launch_bounds__(256) void k_embed2(
    const float* __restrict__ s_ctx, const float* __restrict__ f_ctx,
    const float* __restrict__ s_test, const float* __restrict__ emb_obs,
    const unsigned short* __restrict__ WT0, const float* __restrict__ b0,
    const unsigned short* __restrict__ WT1, const float* __restrict__ b1,
    const unsigned short* __restrict__ WT2, const float* __restrict__ b2,
    const float* __restrict__ g, const float* __restrict__ bta,
    const unsigned short* __restrict__ Wm0n,     // [128][64] (block 0)
    unsigned short* __restrict__ nodes,
    unsigned short* __restrict__ Pout)           // bf16 [NODES][128] perm
{
    __shared__ unsigned short H0[4][16 * 256];
    __shared__ unsigned short H1[4][16 * 128];
    __shared__ unsigned short XO[4][16 * 64];
    int t = threadIdx.x;
    int wave = t >> 6, lane = t & 63, lr = lane & 15, lk = lane >> 4;
    int rb = wave * 16;
    int n0 = blockIdx.x * 64;
    int bq = n0 / NN, nloc0 = n0 % NN;
    bool is_ctx = nloc0 < NC;
    int nr = nloc0 + rb + lr;
    float xv[8];
#pragma unroll
    for (int j = 0; j < 8; ++j) xv[j] = 0.0f;
    if (lk == 0) {
        const float* eb = emb_obs + (is_ctx ? 4 : 0);
        xv[0] = eb[0]; xv[1] = eb[1]; xv[2] = eb[2]; xv[3] = eb[3];
        if (is_ctx) {
            const float* sp = s_ctx + ((size_t)(bq * NC + nr)) * 3;
            const float* fp = f_ctx + ((size_t)(bq * NC + nr)) * 4;
            xv[4] = sp[0]; xv[5] = sp[1]; xv[6] = sp[2]; xv[7] = fp[0];
        } else {
            const float* sp = s_test + ((size_t)(bq * NT + nr - NC)) * 3;
            xv[4] = sp[0]; xv[5] = sp[1]; xv[6] = sp[2];
        }
    } else if (lk == 1 && is_ctx) {
        const float* fp = f_ctx + ((size_t)(bq * NC + nr)) * 4;
        xv[0] = fp[1]; xv[1] = fp[2]; xv[2] = fp[3];
    }
    short8 a;
#pragma unroll
    for (int j = 0; j < 8; ++j) a[j] = (short)f2bf(xv[j]);

    f32x4 acc0[16];
#pragma unroll
    for (int nt = 0; nt < 16; ++nt) {
        short8 bb = *(const short8*)(WT0 + (nt * 16 + lr) * 32 + lk * 8);
        f32x4 z = (f32x4){0.f, 0.f, 0.f, 0.f};
        acc0[nt] = mfma_bf16(a, bb, z);
    }
    unsigned short* h0 = &H0[wave][0];
#pragma unroll
    for (int nt = 0; nt < 16; ++nt) {
        int col = nt * 16 + lr;
        float bias = b0[col];
        int u = col >> 3;
#pragma unroll
        for (int j = 0; j < 4; ++j) {
            int row = lk * 4 + j;
            float v = gelu_f(acc0[nt][j] + bias);
            int us = (u & 16) | ((u ^ row) & 15);
            h0[row * 256 + us * 8 + (col & 7)] = f2bf(v);
        }
    }
    f32x4 acc1[8];
#pragma unroll
    for (int nt = 0; nt < 8; ++nt) acc1[nt] = (f32x4){0.f, 0.f, 0.f, 0.f};
#pragma unroll
    for (int ks = 0; ks < 8; ++ks) {
        int u = ks * 4 + lk;
        int us = (u & 16) | ((u ^ lr) & 15);
        short8 aa = *(const short8*)(&h0[lr * 256 + us * 8]);
#pragma unroll
        for (int nt = 0; nt < 8; ++nt) {
            short8 bb = *(const short8*)(WT1 + (nt * 16 + lr) * 256 + ks * 32 + lk * 8);
            acc1[nt] = mfma_bf16(aa, bb, acc1[nt]);
        }
    }
    unsigned short* h1 = &H1[wave][0];
#pragma unroll
    for (int nt = 0; nt < 8; ++nt) {
        int col = nt * 16 + lr;
        float bias = b1[col];
        int u = col >> 3;
#pragma unroll
        for (int j = 0; j < 4; ++j) {
            int row = lk * 4 + j;
            float v = gelu_f(acc1[nt][j] + bias);
            int us = (u ^ row) & 15;
            h1[row * 128 + us * 8 + (col & 7)] = f2bf(v);
        }
    }
    f32x4 acc2[4];
#pragma unroll
    for (int nt = 0; nt < 4; ++nt) acc2[nt] = (f32x4){0.f, 0.f, 0.f, 0.f};
#pragma unroll
    for (int ks = 0; ks < 4; ++ks) {
        int u = ks * 4 + lk;
        int us = (u ^ lr) & 15;
        short8 aa = *(const short8*)(&h1[lr * 128 + us * 8]);
#pragma unroll
        for (int nt = 0; nt < 4; ++nt) {
            short8 bb = *(const short8*)(WT2 + (nt * 16 + lr) * 128 + ks * 32 + lk * 8);
            acc2[nt] = mfma_bf16(aa, bb, acc2[nt]);
        }
    }
    float vals[4][4];
#pragma unroll
    for (int j = 0; j < 4; ++j)
#pragma unroll
        for (int nt = 0; nt < 4; ++nt)
            vals[j][nt] = acc2[nt][j] + b2[nt * 16 + lr];
    unsigned short* xo = &XO[wave][0];
#pragma unroll
    for (int j = 0; j < 4; ++j) {
        float s = vals[j][0] + vals[j][1] + vals[j][2] + vals[j][3];
#pragma unroll
        for (int m = 1; m < 16; m <<= 1) s += __shfl_xor(s, m, 64);
        float mean = s * (1.0f / 64.0f);
        float vs = 0.0f;
#pragma unroll
        for (int nt = 0; nt < 4; ++nt) { float d = vals[j][nt] - mean; vs += d * d; }
#pragma unroll
        for (int m = 1; m < 16; m <<= 1) vs += __shfl_xor(vs, m, 64);
        float inv = rsqrtf(vs * (1.0f / 64.0f) + 1e-6f);
        int row = lk * 4 + j;
        int node = n0 + rb + row;
#pragma unroll
        for (int nt = 0; nt < 4; ++nt) {
            int col = nt * 16 + lr;
            float o = (vals[j][nt] - mean) * inv * g[col] + bta[col];
            unsigned short ob = f2bf(o);
            nodes[(size_t)node * 64 + col] = ob;
            xo[row * 64 + ((col >> 3) ^ (row & 7)) * 8 + (col & 7)] = ob;
        }
    }
    // P0 = ln_out @ Wm0[0][0:64]
    f32x4 accP[8];
#pragma unroll
    for (int nt = 0; nt < 8; ++nt) accP[nt] = (f32x4){0.f, 0.f, 0.f, 0.f};
#pragma unroll
    for (int ks = 0; ks < 2; ++ks) {
        short8 aa = *(const short8*)(&xo[lr * 64 + ((ks * 4 + lk) ^ (lr & 7)) * 8]);
#pragma unroll
        for (int nt = 0; nt < 8; ++nt) {
            short8 bb = *(const short8*)(Wm0n + (nt * 16 + lr) * 64 + ks * 32 + lk * 8);
            accP[nt] = mfma_bf16(aa, bb, accP[nt]);
        }
    }
#pragma unroll
    for (int j = 0; j < 4; ++j) {
        int node = n0 + rb + lk * 4 + j;
        short8 ps;
#pragma unroll
        for (int nt = 0; nt < 8; ++nt) ps[nt] = (short)f2bf(accP[nt][j]);
        *(short8*)(Pout + (size_t)node * 128 + lr * 8) = ps;
    }
}

// ---------------- top-K: one wave per receiver, med3 insert + skip branches ----------------
__global__ __launch_bounds__(256) void k_topk(
    const float4* __restrict__ s4, const float* __restrict__ s_ctx,
    const float* __restrict__ s_test, const int* __restrict__ valid_lens,
    float* __restrict__ dists, int* __restrict__ senders, float* __restrict__ wout)
{
    __shared__ float cd[4 * 64 * 11];
    __shared__ float seld[4][12];
    __shared__ int   seli[4][12];
    __shared__ int   eqis[4][12];
    int wave = threadIdx.x >> 6;
    int lane = threadIdx.x & 63;
    int r = blockIdx.x * 4 + wave;
    int b = r / NN, n = r % NN;
    float px, py, pz;
    if (n < NC) {
        const float* p = &s_ctx[(size_t)(b * NC + n) * 3];
        px = p[0]; py = p[1]; pz = p[2];
    } else {
        const float* p = &s_test[(size_t)(b * NT + (n - NC)) * 3];
        px = p[0]; py = p[1]; pz = p[2];
    }
    int vl = valid_lens[b];
    const float4* sc = s4 + (size_t)b * NC;
    float v_[64];
    float b_[KNN];
#pragma unroll
    for (int k = 0; k < KNN; ++k) b_[k] = BIGF;
#pragma unroll
    for (int i = 0; i < 64; ++i) {
        int j = lane + (i << 6);
        float4 s = sc[j];
        float dx = px - s.x, dy = py - s.y, dz = pz - s.z;
        float d2 = fmaf(dx, dx, fmaf(dy, dy, dz * dz));
        d2 = (j < vl) ? d2 : BIGF;
        v_[i] = d2;
        if (__ballot(d2 < b_[KNN - 1])) {
#pragma unroll
            for (int k = KNN - 1; k >= 1; --k)
                b_[k] = __builtin_amdgcn_fmed3f(b_[k - 1], b_[k], d2);
            b_[0] = fminf(b_[0], d2);
        }
    }
    int base = (wave * 64 + lane) * 11;
#pragma unroll
    for (int k = 0; k < KNN; ++k) cd[base + k] = b_[k];
    __builtin_amdgcn_wave_barrier();
    int head = 0;
    float myd = 0.0f;
#pragma unroll
    for (int rr = 0; rr < KNN; ++rr) {
        float v = cd[base + head];
        float mv = v;
#pragma unroll
        for (int off = 32; off > 0; off >>= 1) mv = fminf(mv, __shfl_xor(mv, off, 64));
        unsigned long long ball = __ballot(v == mv);
        int win = __ffsll(ball) - 1;
        if (lane == win) head++;
        if (lane == rr) myd = mv;
    }
    float T = __shfl(myd, 9, 64);
    float d2min = __shfl(myd, 0, 64);
    int m = __popcll(__ballot(lane < KNN && myd < T));
    unsigned long long below = (lane == 63) ? 0x7FFFFFFFFFFFFFFFull
                                            : ((1ull << lane) - 1);
    int cless = 0, ceq = 0;
#pragma unroll
    for (int i = 0; i < 64; ++i) {
        float v = v_[i];
        unsigned long long ml = __ballot(v < T);
        unsigned long long me = __ballot(v == T);
        if (ml | me) {
            if (v < T) {
                int slot = cless + __popcll(ml & below);
                seld[wave][slot] = v;
                seli[wave][slot] = lane + (i << 6);
            }
            if (v == T) {
                int q = ceq + __popcll(me & below);
                if (q < 12) eqis[wave][q] = lane + (i << 6);
            }
            cless += __popcll(ml);
            ceq += __popcll(me);
        }
    }
    __builtin_amdgcn_wave_barrier();
    float e = 0.0f, d = 0.0f;
    int isel = 0;
    float dmin = sqrtf(d2min);
    if (lane < KNN) {
        float vsel;
        if (lane < m) { vsel = seld[wave][lane]; isel = seli[wave][lane]; }
        else          { vsel = T;                isel = eqis[wave][lane - m]; }
        d = sqrtf(vsel);
        e = __expf(-(d - dmin));
    }
    float ssum = wave_sum(e);
    if (lane < KNN) {
        size_t o = (size_t)r * KNN + lane;
        dists[o] = d;
        senders[o] = isel;
        wout[o] = e / ssum;
    }
}

// ---------------- per-edge gather + gelu + weighted sum: 16 nodes/block ----------------
__global__ __launch_bounds__(256) void k_msg2(
    const unsigned short* __restrict__ P,       // bf16 [NODES][128] perm cols
    const float* __restrict__ dists, const int* __restrict__ senders,
    const float* __restrict__ w,
    const float* __restrict__ wdp, const float* __restrict__ bm0p,
    unsigned short* __restrict__ gagg)          // bf16 [NODES][128] perm cols
{
    int t = threadIdx.x, wave = t >> 6, lane = t & 63;
    int nb = blockIdx.x * 16 + wave * 4;
    int b = nb / NN;
    int sidv = 0; float dv = 0.0f, wv = 0.0f;
    if (lane < 4 * KNN) {
        int e = nb * KNN + lane;
        sidv = senders[e]; dv = dists[e]; wv = w[e];
    }
    int cp = lane * 2;
    float wd0 = wdp[cp], wd1 = wdp[cp + 1];
    float bb0 = bm0p[cp], bb1 = bm0p[cp + 1];
    float acc[4][2] = {};
    const unsigned int* Pb = (const unsigned int*)P;
    size_t bbase = (size_t)b * NN;
#pragma unroll
    for (int k = 0; k < 4 * KNN; ++k) {
        int sid = __shfl(sidv, k, 64);
        float dd = __shfl(dv, k, 64);
        float ww = __shfl(wv, k, 64);
        unsigned int pr = Pb[(bbase + sid) * 64 + lane];
        float p0 = bf2f((unsigned short)(pr & 0xFFFF));
        float p1 = bf2f((unsigned short)(pr >> 16));
        float g0 = gelu_f(fmaf(dd, wd0, p0 + bb0));
        float g1 = gelu_f(fmaf(dd, wd1, p1 + bb1));
        acc[k / KNN][0] = fmaf(ww, g0, acc[k / KNN][0]);
        acc[k / KNN][1] = fmaf(ww, g1, acc[k / KNN][1]);
    }
    unsigned int* gb = (unsigned int*)gagg;
#pragma unroll
    for (int nn = 0; nn < 4; ++nn) {
        unsigned int pk = (unsigned int)f2bf(acc[nn][0]) |
                          ((unsigned int)f2bf(acc[nn][1]) << 16);
        gb[(size_t)(nb + nn) * 64 + lane] = pk;
    }
}

// ---------------- agg GEMM + update MLP + LN + next-P: 16 nodes, 1 wave ----------------
__global__ __launch_bounds__(64) void k_updp(
    const unsigned short* __restrict__ nodes_in,
    const unsigned short* __restrict__ gagg,    // bf16 [NODES][128] perm
    const unsigned short* __restrict__ Wm1p,    // [64][128] (perm k)
    const float* __restrict__ bm1,
    const unsigned short* __restrict__ WTu0,    // [128][128]
    const float* __restrict__ bu0,
    const unsigned short* __restrict__ WTu1,    // [64][128]
    const float* __restrict__ bu1,
    const float* __restrict__ lng, const float* __restrict__ lnb,
    const unsigned short* __restrict__ Wm0n,    // [128][64] next-iter
    const int doP,
    unsigned short* __restrict__ nodes_out,
    unsigned short* __restrict__ Pout)          // bf16 [NODES][128] perm
{
    __shared__ unsigned short X[16 * 64];
    __shared__ unsigned short G[16 * 128];
    __shared__ unsigned short AG[16 * 64];
    __shared__ unsigned short H[16 * 128];
    __shared__ unsigned short XO[16 * 64];
    int l = threadIdx.x;
    int lr = l & 15, lk = l >> 4;
    int n0 = blockIdx.x * 16;
    // stage X [16][64] swizzled
#pragma unroll
    for (int c0 = 0; c0 < 2; ++c0) {
        int c = c0 * 64 + l;
        int row = c >> 3, u = c & 7;
        int4v v = *(const int4v*)(nodes_in + ((size_t)(n0 + row)) * 64 + u * 8);
        *(int4v*)(&X[row * 64 + (u ^ (row & 7)) * 8]) = v;
    }
    // stage G [16][128] swizzled
#pragma unroll
    for (int c0 = 0; c0 < 4; ++c0) {
        int c = c0 * 64 + l;
        int row = c >> 4, u = c & 15;
        int4v v = *(const int4v*)(gagg + ((size_t)(n0 + row)) * 128 + u * 8);
        *(int4v*)(&G[row * 128 + (u ^ row) * 8]) = v;
    }
    // GEMM_A: agg = gagg @ Wm1  (K=128 over perm space)
    f32x4 accA[4];
#pragma unroll
    for (int nt = 0; nt < 4; ++nt) accA[nt] = (f32x4){0.f, 0.f, 0.f, 0.f};
#pragma unroll
    for (int ks = 0; ks < 4; ++ks) {
        short8 a = *(const short8*)(&G[lr * 128 + ((ks * 4 + lk) ^ lr) * 8]);
#pragma unroll
        for (int nt = 0; nt < 4; ++nt) {
            short8 bb = *(const short8*)(Wm1p + (nt * 16 + lr) * 128 + ks * 32 + lk * 8);
            accA[nt] = mfma_bf16(a, bb, accA[nt]);
        }
    }
#pragma unroll
    for (int nt = 0; nt < 4; ++nt) {
        int col = nt * 16 + lr;
        float bias = bm1[col];
#pragma unroll
        for (int j = 0; j < 4; ++j) {
            int row = lk * 4 + j;
            AG[row * 64 + ((col >> 3) ^ (row & 7)) * 8 + (col & 7)] =
                f2bf(accA[nt][j] + bias);
        }
    }
    // GEMM3: u=[x|agg] @ Wu0
    f32x4 acc[8];
#pragma unroll
    for (int nt = 0; nt < 8; ++nt) acc[nt] = (f32x4){0.f, 0.f, 0.f, 0.f};
#pragma unroll
    for (int ks = 0; ks < 4; ++ks) {
        short8 a;
        if (ks < 2) a = *(const short8*)(&X[lr * 64 + ((ks * 4 + lk) ^ (lr & 7)) * 8]);
        else        a = *(const short8*)(&AG[lr * 64 + (((ks - 2) * 4 + lk) ^ (lr & 7)) * 8]);
#pragma unroll
        for (int nt = 0; nt < 8; ++nt) {
            short8 bb = *(const short8*)(WTu0 + (nt * 16 + lr) * 128 + ks * 32 + lk * 8);
            acc[nt] = mfma_bf16(a, bb, acc[nt]);
        }
    }
#pragma unroll
    for (int nt = 0; nt < 8; ++nt) {
        int col = nt * 16 + lr;
        float bias = bu0[col];
#pragma unroll
        for (int j = 0; j < 4; ++j) {
            int lrow = lk * 4 + j;
            float v = gelu_f(acc[nt][j] + bias);
            H[lrow * 128 + ((col >> 3) ^ lrow) * 8 + (col & 7)] = f2bf(v);
        }
    }
    // GEMM4: h @ Wu1
    f32x4 acc2[4];
#pragma unroll
    for (int nt = 0; nt < 4; ++nt) acc2[nt] = (f32x4){0.f, 0.f, 0.f, 0.f};
#pragma unroll
    for (int ks = 0; ks < 4; ++ks) {
        short8 a = *(const short8*)(&H[lr * 128 + ((ks * 4 + lk) ^ lr) * 8]);
#pragma unroll
        for (int nt = 0; nt < 4; ++nt) {
            short8 bb = *(const short8*)(WTu1 + (nt * 16 + lr) * 128 + ks * 32 + lk * 8);
            acc2[nt] = mfma_bf16(a, bb, acc2[nt]);
        }
    }
    // residual + LN
    float vals[4][4];
#pragma unroll
    for (int j = 0; j < 4; ++j) {
        int row = lk * 4 + j;
#pragma unroll
        for (int nt = 0; nt < 4; ++nt) {
            int col = nt * 16 + lr;
            float x = bf2f(X[row * 64 + ((col >> 3) ^ (row & 7)) * 8 + (col & 7)]);
            vals[j][nt] = x + acc2[nt][j] + bu1[col];
        }
    }
#pragma unroll
    for (int j = 0; j < 4; ++j) {
        int row = lk * 4 + j;
        float s = vals[j][0] + vals[j][1] + vals[j][2] + vals[j][3];
#pragma unroll
        for (int m = 1; m < 16; m <<= 1) s += __shfl_xor(s, m, 64);
        float mean = s * (1.0f / 64.0f);
        float vs = 0.0f;
#pragma unroll
        for (int nt = 0; nt < 4; ++nt) { float d = vals[j][nt] - mean; vs += d * d; }
#pragma unroll
        for (int m = 1; m < 16; m <<= 1) vs += __shfl_xor(vs, m, 64);
        float inv = rsqrtf(vs * (1.0f / 64.0f) + 1e-6f);
#pragma unroll
        for (int nt = 0; nt < 4; ++nt) {
            int col = nt * 16 + lr;
            float o = (vals[j][nt] - mean) * inv * lng[col] + lnb[col];
            unsigned short ob = f2bf(o);
            nodes_out[((size_t)(n0 + row)) * 64 + col] = ob;
            XO[row * 64 + ((col >> 3) ^ (row & 7)) * 8 + (col & 7)] = ob;
        }
    }
    // next-iteration P = ln_out @ Wm0next[0:64]
    if (doP) {
        f32x4 accP[8];
#pragma unroll
        for (int nt = 0; nt < 8; ++nt) accP[nt] = (f32x4){0.f, 0.f, 0.f, 0.f};
#pragma unroll
        for (int ks = 0; ks < 2; ++ks) {
            short8 aa = *(const short8*)(&XO[lr * 64 + ((ks * 4 + lk) ^ (lr & 7)) * 8]);
#pragma unroll
            for (int nt = 0; nt < 8; ++nt) {
                short8 bb = *(const short8*)(Wm0n + (nt * 16 + lr) * 64 + ks * 32 + lk * 8);
                accP[nt] = mfma_bf16(aa, bb, accP[nt]);
            }
        }
#pragma unroll
        for (int j = 0; j < 4; ++j) {
            int node = n0 + lk * 4 + j;
            short8 ps;
#pragma unroll
            for (int nt = 0; nt < 8; ++nt) ps[nt] = (short)f2bf(accP[nt][j]);
            *(short8*)(Pout + (size_t)node * 128 + lr * 8) = ps;
        }
    }
}

// ---------------- head (MFMA): 64 test nodes per WG ----------------
__global__ __launch_bounds__(256) void k_head2(
    const unsigned short* __restrict__ nodes,
    const unsigned short* __restrict__ WT0, const float* __restrict__ b0,
    const unsigned short* __restrict__ WT1, const float* __restrict__ b1,
    const float* __restrict__ W2, const float* __restrict__ b2,
    float* __restrict__ out)
{
    __shared__ unsigned short H0[4][16 * 256];
    __shared__ unsigned short H1[4][16 * 72];
    int t = threadIdx.x;
    int wave = t >> 6, lane = t & 63, lr = lane & 15, lk = lane >> 4;
    int rb = wave * 16;
    int n0 = blockIdx.x * 64;
    int bq = n0 / NT, nloc0 = n0 % NT;
    size_t grow = (size_t)(bq * NN + NC + nloc0 + rb);
    short8 a0 = *(const short8*)(nodes + (grow + lr) * 64 + lk * 8);
    short8 a1 = *(const short8*)(nodes + (grow + lr) * 64 + 32 + lk * 8);
    f32x4 acc0[16];
#pragma unroll
    for (int nt = 0; nt < 16; ++nt) {
        short8 bb0 = *(const short8*)(WT0 + (nt * 16 + lr) * 64 + lk * 8);
        short8 bb1 = *(const short8*)(WT0 + (nt * 16 + lr) * 64 + 32 + lk * 8);
        f32x4 z = (f32x4){0.f, 0.f, 0.f, 0.f};
        z = mfma_bf16(a0, bb0, z);
        acc0[nt] = mfma_bf16(a1, bb1, z);
    }
    unsigned short* h0 = &H0[wave][0];
#pragma unroll
    for (int nt = 0; nt < 16; ++nt) {
        int col = nt * 16 + lr;
        float bias = b0[col];
        int u = col >> 3;
#pragma unroll
        for (int j = 0; j < 4; ++j) {
            int row = lk * 4 + j;
            float v = gelu_f(acc0[nt][j] + bias);
            int us = (u & 16) | ((u ^ row) & 15);
            h0[row * 256 + us * 8 + (col & 7)] = f2bf(v);
        }
    }
    f32x4 acc1[4];
#pragma unroll
    for (int nt = 0; nt < 4; ++nt) acc1[nt] = (f32x4){0.f, 0.f, 0.f, 0.f};
#pragma unroll
    for (int ks = 0; ks < 8; ++ks) {
        int u = ks * 4 + lk;
        int us = (u & 16) | ((u ^ lr) & 15);
        short8 aa = *(const short8*)(&h0[lr * 256 + us * 8]);
#pragma unroll
        for (int nt = 0; nt < 4; ++nt) {
            short8 bb = *(const short8*)(WT1 + (nt * 16 + lr) * 256 + ks * 32 + lk * 8);
            acc1[nt] = mfma_bf16(aa, bb, acc1[nt]);
        }
    }
    unsigned short* h1 = &H1[wave][0];
#pragma unroll
    for (int nt = 0; nt < 4; ++nt) {
        int col = nt * 16 + lr;
        float bias = b1[col];
#pragma unroll
        for (int j = 0; j < 4; ++j) {
            int row = lk * 4 + j;
            h1[row * 72 + col] = f2bf(gelu_f(acc1[nt][j] + bias));
        }
    }
    int task = lane >> 1;
    int row = task >> 1;
    int o = task & 1;
    int t2 = lane & 1;
    float p = 0.0f;
#pragma unroll
    for (int d = 0; d < 32; ++d) {
        int dd = t2 * 32 + d;
        p += bf2f(h1[row * 72 + dd]) * W2[dd * 2 + o];
    }
    p += __shfl_xor(p, 1, 64);
    if (t2 == 0) {
        int gg = n0 + rb + row;
        if (o == 0) out[gg] = p + b2[0];
        else        out[BB * NT + gg] = __expf(0.5f * (p + b2[1]));
    }
}

extern "C" void kernel_launch(void* const* d_in, const int* in_sizes, int n_in,
                              void* d_out, int out_size, void* d_ws, size_t ws_size,
                              hipStream_t stream)
{
    (void)in_sizes; (void)n_in; (void)out_size; (void)ws_size;
    const float* s_ctx   = (const float*)d_in[0];
    const float* f_ctx   = (const float*)d_in[1];
    const float* s_test  = (const float*)d_in[2];
    const int*   valid   = (const int*)d_in[3];
    const float* emb_obs = (const float*)d_in[4];
    const float* ea_W0   = (const float*)d_in[5];
    const float* ea_b0   = (const float*)d_in[6];
    const float* ea_W1   = (const float*)d_in[7];
    const float* ea_b1   = (const float*)d_in[8];
    const float* ea_W2   = (const float*)d_in[9];
    const float* ea_b2   = (const float*)d_in[10];
    const float* ln_g    = (const float*)d_in[11];
    const float* ln_b    = (const float*)d_in[12];
    const float* blk_Wm0 = (const float*)d_in[13];
    const float* blk_bm0 = (const float*)d_in[14];
    const float* blk_Wm1 = (const float*)d_in[15];
    const float* blk_bm1 = (const float*)d_in[16];
    const float* blk_Wu0 = (const float*)d_in[17];
    const float* blk_bu0 = (const float*)d_in[18];
    const float* blk_Wu1 = (const float*)d_in[19];
    const float* blk_bu1 = (const float*)d_in[20];
    const float* blk_lng = (const float*)d_in[21];
    const float* blk_lnb = (const float*)d_in[22];
    const float* hd_W0   = (const float*)d_in[23];
    const float* hd_b0   = (const float*)d_in[24];
    const float* hd_W1   = (const float*)d_in[25];
    const float* hd_b1   = (const float*)d_in[26];
    const float* hd_W2   = (const float*)d_in[27];
    const float* hd_b2   = (const float*)d_in[28];

    char* p = (char*)d_ws;
    auto alloc = [&](size_t bytes) { char* r = p; p += (bytes + 255) & ~(size_t)255; return r; };
    unsigned short* nodesA = (unsigned short*)alloc((size_t)NODES * 64 * 2);
    unsigned short* nodesB = (unsigned short*)alloc((size_t)NODES * 64 * 2);
    unsigned short* Pbuf   = (unsigned short*)alloc((size_t)NODES * 128 * 2);
    unsigned short* gaggb  = (unsigned short*)alloc((size_t)NODES * 128 * 2);
    float* dists   = (float*)alloc((size_t)NODES * KNN * 4);
    float* wbuf    = (float*)alloc((size_t)NODES * KNN * 4);
    int*   senders = (int*)alloc((size_t)NODES * KNN * 4);
    unsigned short* wtm0  = (unsigned short*)alloc((size_t)6 * 8192 * 2);
    unsigned short* wtm1p = (unsigned short*)alloc((size_t)6 * 8192 * 2);
    unsigned short* wtu0  = (unsigned short*)alloc((size_t)6 * 16384 * 2);
    unsigned short* wtu1  = (unsigned short*)alloc((size_t)6 * 8192 * 2);
    float* wdp  = (float*)alloc((size_t)6 * 128 * 4);
    float* bm0p = (float*)alloc((size_t)6 * 128 * 4);
    unsigned short* wte0 = (unsigned short*)alloc((size_t)8192 * 2);
    unsigned short* wte1 = (unsigned short*)alloc((size_t)32768 * 2);
    unsigned short* wte2 = (unsigned short*)alloc((size_t)8192 * 2);
    unsigned short* wth0 = (unsigned short*)alloc((size_t)16384 * 2);
    unsigned short* wth1 = (unsigned short*)alloc((size_t)16384 * 2);
    float4* s4 = (float4*)alloc((size_t)BB * NC * 16);

    k_convw<<<1286, 256, 0, stream>>>(
        blk_Wm0, blk_Wm1, blk_Wu0, blk_Wu1, blk_bm0,
        ea_W0, ea_W1, ea_W2, hd_W0, hd_W1,
        wtm0, wtm1p, wtu0, wtu1, wdp, bm0p, wte0, wte1, wte2, wth0, wth1);

    k_prep<<<(BB * NC + 255) / 256, 256, 0, stream>>>(s_ctx, s4);

    k_embed2<<<NODES / 64, 256, 0, stream>>>(s_ctx, f_ctx, s_test, emb_obs,
        wte0, ea_b0, wte1, ea_b1, wte2, ea_b2, ln_g, ln_b, wtm0, nodesA, Pbuf);

    k_topk<<<NODES / 4, 256, 0, stream>>>(s4, s_ctx, s_test, valid,
                                          dists, senders, wbuf);

    unsigned short* nin = nodesA; unsigned short* nout = nodesB;
    for (int i = 0; i < NBLK; ++i) {
        k_msg2<<<NODES / 16, 256, 0, stream>>>(Pbuf, dists, senders, wbuf,
            wdp + (size_t)i * 128, bm0p + (size_t)i * 128, gaggb);
        int doP = (i < NBLK - 1) ? 1 : 0;
        const unsigned short* wm0n = wtm0 + (size_t)((i + 1) % NBLK) * 8192;
        k_updp<<<NODES / 16, 64, 0, stream>>>(nin, gaggb,
            wtm1p + (size_t)i * 8192, blk_bm1 + (size_t)i * 64,
            wtu0 + (size_t)i * 16384, blk_bu0 + (size_t)i * 128,
            wtu1 + (size_t)i * 8192, blk_bu1 + (size_t)i * 64,
            blk_lng + (size_t)i * 64, blk_lnb + (size_t)i * 64,
            wm0n, doP, nout, Pbuf);
        unsigned short* tmp = nin; nin = nout; nout = tmp;
    }

    k_head2<<<BB * NT / 64, 256, 0, stream>>>(nin, wth0, hd_b0, wth1, hd_b1,
                                              hd_W2, hd_b2, (float*)d_out);
}

// Round 6
// 385.530 us; speedup vs baseline: 5.5076x; 1.0067x over previous
//
#include <hip/hip_runtime.h>
#include <math.h>

#define BB 4
#define NC 4096
#define NT 1024
#define NN (NC + NT)      // 5120
#define NODES (BB * NN)   // 20480
#define DD 64
#define KNN 10
#define NBLK 6
#define BIGF 3.0e38f

typedef __attribute__((ext_vector_type(8))) short short8;
typedef __attribute__((ext_vector_type(4))) float f32x4;
typedef __attribute__((ext_vector_type(4))) int int4v;

__device__ __forceinline__ unsigned short f2bf(float f) {
    unsigned int u = __float_as_uint(f);
    unsigned int r = (u + 0x7fffu + ((u >> 16) & 1u)) >> 16;
    return (unsigned short)r;
}
__device__ __forceinline__ float bf2f(unsigned short h) {
    return __uint_as_float(((unsigned int)h) << 16);
}

__device__ __forceinline__ float gelu_f(float x) {
    const float c0 = 0.7978845608028654f;
    float x3 = x * x * x;
    float z2 = 2.0f * c0 * (x + 0.044715f * x3);
    float e = __expf(z2);
    float r = __builtin_amdgcn_rcpf(1.0f + e);
    return x - x * r;
}

__device__ __forceinline__ float wave_sum(float v) {
#pragma unroll
    for (int off = 32; off > 0; off >>= 1) v += __shfl_xor(v, off, 64);
    return v;
}

__device__ __forceinline__ f32x4 mfma_bf16(short8 a, short8 b, f32x4 c) {
    asm("v_mfma_f32_16x16x32_bf16 %0, %1, %2, %0" : "+v"(c) : "v"(a), "v"(b));
    return c;
}

// perm(col) = (col&15)*8 + (col>>4); invperm(cp) = ((cp&7)<<4) | (cp>>3)

// ---------------- weight convert ----------------
__global__ __launch_bounds__(256) void k_convw(
    const float* __restrict__ Wm0, const float* __restrict__ Wm1,
    const float* __restrict__ Wu0, const float* __restrict__ Wu1,
    const float* __restrict__ bm0,
    const float* __restrict__ eW0, const float* __restrict__ eW1,
    const float* __restrict__ eW2,
    const float* __restrict__ hW0, const float* __restrict__ hW1,
    unsigned short* __restrict__ wtm0, unsigned short* __restrict__ wtm1p,
    unsigned short* __restrict__ wtu0, unsigned short* __restrict__ wtu1,
    float* __restrict__ wdp, float* __restrict__ bm0p,
    unsigned short* __restrict__ wte0, unsigned short* __restrict__ wte1,
    unsigned short* __restrict__ wte2,
    unsigned short* __restrict__ wth0, unsigned short* __restrict__ wth1)
{
    int t = blockIdx.x * 256 + threadIdx.x;
    if (t < 49152) {                 // wtm0 [6][128][64] <- Wm0[i][k][n], k<64
        int i = t / 8192, r = t % 8192, n = r / 64, k = r % 64;
        wtm0[t] = f2bf(Wm0[(i * 65 + k) * 128 + n]);
    } else if (t < 98304) {          // wtm1p [6][64][128]: [n][cp] = Wm1[i][invperm(cp)][n]
        int u = t - 49152;
        int i = u / 8192, r = u % 8192, n = r / 128, cp = r % 128;
        int col = ((cp & 7) << 4) | (cp >> 3);
        wtm1p[u] = f2bf(Wm1[(i * 128 + col) * 64 + n]);
    } else if (t < 196608) {         // wtu0 [6][128][128]
        int u = t - 98304;
        int i = u / 16384, r = u % 16384, n = r / 128, k = r % 128;
        wtu0[u] = f2bf(Wu0[(i * 128 + k) * 128 + n]);
    } else if (t < 245760) {         // wtu1 [6][64][128]
        int u = t - 196608;
        int i = u / 8192, r = u % 8192, n = r / 128, k = r % 128;
        wtu1[u] = f2bf(Wu1[(i * 128 + k) * 64 + n]);
    } else if (t < 246528) {         // wdp [6][128] perm
        int u = t - 245760;
        int i = u / 128, cp = u % 128;
        int col = ((cp & 7) << 4) | (cp >> 3);
        wdp[u] = Wm0[(i * 65 + 64) * 128 + col];
    } else if (t < 247296) {         // bm0p [6][128] perm
        int u = t - 246528;
        int i = u / 128, cp = u % 128;
        int col = ((cp & 7) << 4) | (cp >> 3);
        bm0p[u] = bm0[i * 128 + col];
    } else if (t < 255488) {         // wte0 [256][32], k<11 else 0
        int u = t - 247296;
        int n = u / 32, k = u % 32;
        wte0[u] = (k < 11) ? f2bf(eW0[k * 256 + n]) : 0;
    } else if (t < 288256) {         // wte1 [128][256]
        int u = t - 255488;
        int n = u / 256, k = u % 256;
        wte1[u] = f2bf(eW1[k * 128 + n]);
    } else if (t < 296448) {         // wte2 [64][128]
        int u = t - 288256;
        int n = u / 128, k = u % 128;
        wte2[u] = f2bf(eW2[k * 64 + n]);
    } else if (t < 312832) {         // wth0 [256][64]
        int u = t - 296448;
        int n = u / 64, k = u % 64;
        wth0[u] = f2bf(hW0[k * 256 + n]);
    } else if (t < 329216) {         // wth1 [64][256]
        int u = t - 312832;
        int n = u / 256, k = u % 256;
        wth1[u] = f2bf(hW1[k * 64 + n]);
    }
}

// ---------------- prep: pack sender coords into aligned float4 ----------------
__global__ __launch_bounds__(256) void k_prep(
    const float* __restrict__ sctx, float4* __restrict__ s4)
{
    int t = blockIdx.x * 256 + threadIdx.x;
    if (t < BB * NC) {
        float x = sctx[t * 3], y = sctx[t * 3 + 1], z = sctx[t * 3 + 2];
        s4[t] = make_float4(x, y, z, 0.0f);
    }
}

// ---------------- embed (MFMA) + P0: 64 nodes per WG, 4 waves, barrier-free ----------------
__global__ __launch_bounds__(256) void k_embed2(
    const float* __restrict__ s_ctx, const float* __restrict__ f_ctx,
    const float* __restrict__ s_test, const float* __restrict__ emb_obs,
    const unsigned short* __restrict__ WT0, const float* __restrict__ b0,
    const unsigned short* __restrict__ WT1, const float* __restrict__ b1,
    const unsigned short* __restrict__ WT2, const float* __restrict__ b2,
    const float* __restrict__ g, const float* __restrict__ bta,
    const unsigned short* __restrict__ Wm0n,     // [128][64] (block 0)
    unsigned short* __restrict__ nodes,
    unsigned short* __restrict__ Pout)           // bf16 [NODES][128] perm
{
    __shared__ unsigned short H0[4][16 * 256];
    __shared__ unsigned short H1[4][16 * 128];
    __shared__ unsigned short XO[4][16 * 64];
    int t = threadIdx.x;
    int wave = t >> 6, lane = t & 63, lr = lane & 15, lk = lane >> 4;
    int rb = wave * 16;
    int n0 = blockIdx.x * 64;
    int bq = n0 / NN, nloc0 = n0 % NN;
    bool is_ctx = nloc0 < NC;
    int nr = nloc0 + rb + lr;
    float xv[8];
#pragma unroll
    for (int j = 0; j < 8; ++j) xv[j] = 0.0f;
    if (lk == 0) {
        const float* eb = emb_obs + (is_ctx ? 4 : 0);
        xv[0] = eb[0]; xv[1] = eb[1]; xv[2] = eb[2]; xv[3] = eb[3];
        if (is_ctx) {
            const float* sp = s_ctx + ((size_t)(bq * NC + nr)) * 3;
            const float* fp = f_ctx + ((size_t)(bq * NC + nr)) * 4;
            xv[4] = sp[0]; xv[5] = sp[1]; xv[6] = sp[2]; xv[7] = fp[0];
        } else {
            const float* sp = s_test + ((size_t)(bq * NT + nr - NC)) * 3;
            xv[4] = sp[0]; xv[5] = sp[1]; xv[6] = sp[2];
        }
    } else if (lk == 1 && is_ctx) {
        const float* fp = f_ctx + ((size_t)(bq * NC + nr)) * 4;
        xv[0] = fp[1]; xv[1] = fp[2]; xv[2] = fp[3];
    }
    short8 a;
#pragma unroll
    for (int j = 0; j < 8; ++j) a[j] = (short)f2bf(xv[j]);

    f32x4 acc0[16];
#pragma unroll
    for (int nt = 0; nt < 16; ++nt) {
        short8 bb = *(const short8*)(WT0 + (nt * 16 + lr) * 32 + lk * 8);
        f32x4 z = (f32x4){0.f, 0.f, 0.f, 0.f};
        acc0[nt] = mfma_bf16(a, bb, z);
    }
    unsigned short* h0 = &H0[wave][0];
#pragma unroll
    for (int nt = 0; nt < 16; ++nt) {
        int col = nt * 16 + lr;
        float bias = b0[col];
        int u = col >> 3;
#pragma unroll
        for (int j = 0; j < 4; ++j) {
            int row = lk * 4 + j;
            float v = gelu_f(acc0[nt][j] + bias);
            int us = (u & 16) | ((u ^ row) & 15);
            h0[row * 256 + us * 8 + (col & 7)] = f2bf(v);
        }
    }
    f32x4 acc1[8];
#pragma unroll
    for (int nt = 0; nt < 8; ++nt) acc1[nt] = (f32x4){0.f, 0.f, 0.f, 0.f};
#pragma unroll
    for (int ks = 0; ks < 8; ++ks) {
        int u = ks * 4 + lk;
        int us = (u & 16) | ((u ^ lr) & 15);
        short8 aa = *(const short8*)(&h0[lr * 256 + us * 8]);
#pragma unroll
        for (int nt = 0; nt < 8; ++nt) {
            short8 bb = *(const short8*)(WT1 + (nt * 16 + lr) * 256 + ks * 32 + lk * 8);
            acc1[nt] = mfma_bf16(aa, bb, acc1[nt]);
        }
    }
    unsigned short* h1 = &H1[wave][0];
#pragma unroll
    for (int nt = 0; nt < 8; ++nt) {
        int col = nt * 16 + lr;
        float bias = b1[col];
        int u = col >> 3;
#pragma unroll
        for (int j = 0; j < 4; ++j) {
            int row = lk * 4 + j;
            float v = gelu_f(acc1[nt][j] + bias);
            int us = (u ^ row) & 15;
            h1[row * 128 + us * 8 + (col & 7)] = f2bf(v);
        }
    }
    f32x4 acc2[4];
#pragma unroll
    for (int nt = 0; nt < 4; ++nt) acc2[nt] = (f32x4){0.f, 0.f, 0.f, 0.f};
#pragma unroll
    for (int ks = 0; ks < 4; ++ks) {
        int u = ks * 4 + lk;
        int us = (u ^ lr) & 15;
        short8 aa = *(const short8*)(&h1[lr * 128 + us * 8]);
#pragma unroll
        for (int nt = 0; nt < 4; ++nt) {
            short8 bb = *(const short8*)(WT2 + (nt * 16 + lr) * 128 + ks * 32 + lk * 8);
            acc2[nt] = mfma_bf16(aa, bb, acc2[nt]);
        }
    }
    float vals[4][4];
#pragma unroll
    for (int j = 0; j < 4; ++j)
#pragma unroll
        for (int nt = 0; nt < 4; ++nt)
            vals[j][nt] = acc2[nt][j] + b2[nt * 16 + lr];
    unsigned short* xo = &XO[wave][0];
#pragma unroll
    for (int j = 0; j < 4; ++j) {
        float s = vals[j][0] + vals[j][1] + vals[j][2] + vals[j][3];
#pragma unroll
        for (int m = 1; m < 16; m <<= 1) s += __shfl_xor(s, m, 64);
        float mean = s * (1.0f / 64.0f);
        float vs = 0.0f;
#pragma unroll
        for (int nt = 0; nt < 4; ++nt) { float d = vals[j][nt] - mean; vs += d * d; }
#pragma unroll
        for (int m = 1; m < 16; m <<= 1) vs += __shfl_xor(vs, m, 64);
        float inv = rsqrtf(vs * (1.0f / 64.0f) + 1e-6f);
        int row = lk * 4 + j;
        int node = n0 + rb + row;
#pragma unroll
        for (int nt = 0; nt < 4; ++nt) {
            int col = nt * 16 + lr;
            float o = (vals[j][nt] - mean) * inv * g[col] + bta[col];
            unsigned short ob = f2bf(o);
            nodes[(size_t)node * 64 + col] = ob;
            xo[row * 64 + ((col >> 3) ^ (row & 7)) * 8 + (col & 7)] = ob;
        }
    }
    // P0 = ln_out @ Wm0[0][0:64]
    f32x4 accP[8];
#pragma unroll
    for (int nt = 0; nt < 8; ++nt) accP[nt] = (f32x4){0.f, 0.f, 0.f, 0.f};
#pragma unroll
    for (int ks = 0; ks < 2; ++ks) {
        short8 aa = *(const short8*)(&xo[lr * 64 + ((ks * 4 + lk) ^ (lr & 7)) * 8]);
#pragma unroll
        for (int nt = 0; nt < 8; ++nt) {
            short8 bb = *(const short8*)(Wm0n + (nt * 16 + lr) * 64 + ks * 32 + lk * 8);
            accP[nt] = mfma_bf16(aa, bb, accP[nt]);
        }
    }
#pragma unroll
    for (int j = 0; j < 4; ++j) {
        int node = n0 + rb + lk * 4 + j;
        short8 ps;
#pragma unroll
        for (int nt = 0; nt < 8; ++nt) ps[nt] = (short)f2bf(accP[nt][j]);
        *(short8*)(Pout + (size_t)node * 128 + lr * 8) = ps;
    }
}

// ---------------- top-K: one wave per receiver, branchless med3 insert ----------------
__global__ __launch_bounds__(256) void k_topk(
    const float4* __restrict__ s4, const float* __restrict__ s_ctx,
    const float* __restrict__ s_test, const int* __restrict__ valid_lens,
    float* __restrict__ dists, int* __restrict__ senders, float* __restrict__ wout)
{
    __shared__ float cd[4 * 64 * 11];
    __shared__ float seld[4][12];
    __shared__ int   seli[4][12];
    __shared__ int   eqis[4][12];
    int wave = threadIdx.x >> 6;
    int lane = threadIdx.x & 63;
    int r = blockIdx.x * 4 + wave;
    int b = r / NN, n = r % NN;
    float px, py, pz;
    if (n < NC) {
        const float* p = &s_ctx[(size_t)(b * NC + n) * 3];
        px = p[0]; py = p[1]; pz = p[2];
    } else {
        const float* p = &s_test[(size_t)(b * NT + (n - NC)) * 3];
        px = p[0]; py = p[1]; pz = p[2];
    }
    int vl = valid_lens[b];
    const float4* sc = s4 + (size_t)b * NC;
    float b_[KNN];
#pragma unroll
    for (int k = 0; k < KNN; ++k) b_[k] = BIGF;
#pragma unroll 16
    for (int i = 0; i < 64; ++i) {
        int j = lane + (i << 6);
        float4 s = sc[j];
        float dx = px - s.x, dy = py - s.y, dz = pz - s.z;
        float d2 = fmaf(dx, dx, fmaf(dy, dy, dz * dz));
        d2 = (j < vl) ? d2 : BIGF;
        // branchless sorted insert: new[k] = med3(old[k-1], old[k], d2)
#pragma unroll
        for (int k = KNN - 1; k >= 1; --k)
            b_[k] = __builtin_amdgcn_fmed3f(b_[k - 1], b_[k], d2);
        b_[0] = fminf(b_[0], d2);
    }
    int base = (wave * 64 + lane) * 11;
#pragma unroll
    for (int k = 0; k < KNN; ++k) cd[base + k] = b_[k];
    __builtin_amdgcn_wave_barrier();
    int head = 0;
    float myd = 0.0f;
#pragma unroll
    for (int rr = 0; rr < KNN; ++rr) {
        float v = cd[base + head];
        float mv = v;
#pragma unroll
        for (int off = 32; off > 0; off >>= 1) mv = fminf(mv, __shfl_xor(mv, off, 64));
        unsigned long long ball = __ballot(v == mv);
        int win = __ffsll(ball) - 1;
        if (lane == win) head++;
        if (lane == rr) myd = mv;
    }
    float T = __shfl(myd, 9, 64);
    float d2min = __shfl(myd, 0, 64);
    int m = __popcll(__ballot(lane < KNN && myd < T));
    unsigned long long below = (lane == 63) ? 0x7FFFFFFFFFFFFFFFull
                                            : ((1ull << lane) - 1);
    int cless = 0, ceq = 0;
#pragma unroll 8
    for (int i = 0; i < 64; ++i) {
        int j = lane + (i << 6);
        float4 s = sc[j];
        float dx = px - s.x, dy = py - s.y, dz = pz - s.z;
        float v = fmaf(dx, dx, fmaf(dy, dy, dz * dz));
        v = (j < vl) ? v : BIGF;
        unsigned long long ml = __ballot(v < T);
        unsigned long long me = __ballot(v == T);
        if (v < T) {
            int slot = cless + __popcll(ml & below);
            seld[wave][slot] = v;
            seli[wave][slot] = j;
        }
        if (v == T) {
            int q = ceq + __popcll(me & below);
            if (q < 12) eqis[wave][q] = j;
        }
        cless += __popcll(ml);
        ceq += __popcll(me);
    }
    __builtin_amdgcn_wave_barrier();
    float e = 0.0f, d = 0.0f;
    int isel = 0;
    float dmin = sqrtf(d2min);
    if (lane < KNN) {
        float vsel;
        if (lane < m) { vsel = seld[wave][lane]; isel = seli[wave][lane]; }
        else          { vsel = T;                isel = eqis[wave][lane - m]; }
        d = sqrtf(vsel);
        e = __expf(-(d - dmin));
    }
    float ssum = wave_sum(e);
    if (lane < KNN) {
        size_t o = (size_t)r * KNN + lane;
        dists[o] = d;
        senders[o] = isel;
        wout[o] = e / ssum;
    }
}

// ---------------- fused block: gather+gelu+wsum + GEMMs + LN + next-P ----------------
// 16 nodes per 64-thread (1-wave) block, barrier-free
__global__ __launch_bounds__(64) void k_blk(
    const unsigned short* __restrict__ nodes_in,
    const unsigned short* __restrict__ P,        // bf16 [NODES][128] perm
    const float* __restrict__ dists, const int* __restrict__ senders,
    const float* __restrict__ w,
    const float* __restrict__ wdp, const float* __restrict__ bm0p,
    const unsigned short* __restrict__ Wm1p,     // [64][128] (perm k)
    const float* __restrict__ bm1,
    const unsigned short* __restrict__ WTu0,     // [128][128]
    const float* __restrict__ bu0,
    const unsigned short* __restrict__ WTu1,     // [64][128]
    const float* __restrict__ bu1,
    const float* __restrict__ lng, const float* __restrict__ lnb,
    const unsigned short* __restrict__ Wm0n,     // [128][64] next-iter
    const int doP,
    unsigned short* __restrict__ nodes_out,
    unsigned short* __restrict__ Pout)
{
    __shared__ unsigned short X[16 * 64];
    __shared__ unsigned short G[16 * 128];
    __shared__ unsigned short AG[16 * 64];
    __shared__ unsigned short H[16 * 128];
    __shared__ unsigned short XO[16 * 64];
    __shared__ int   sidE[160];
    __shared__ float dE[160], wE[160];
    int l = threadIdx.x;
    int lr = l & 15, lk = l >> 4;
    int n0 = blockIdx.x * 16;
    int b = n0 / NN;
    size_t bbase = (size_t)b * NN;
    int e0 = n0 * KNN;
    // edge meta staging
#pragma unroll
    for (int e0i = 0; e0i < 3; ++e0i) {
        int e = e0i * 64 + l;
        if (e < 160) {
            sidE[e] = senders[e0 + e];
            dE[e]   = dists[e0 + e];
            wE[e]   = w[e0 + e];
        }
    }
    // stage X [16][64] swizzled
#pragma unroll
    for (int c0 = 0; c0 < 2; ++c0) {
        int c = c0 * 64 + l;
        int row = c >> 3, u = c & 7;
        int4v v = *(const int4v*)(nodes_in + ((size_t)(n0 + row)) * 64 + u * 8);
        *(int4v*)(&X[row * 64 + (u ^ (row & 7)) * 8]) = v;
    }
    // gather + gelu + weighted sum -> G (perm cols, GEMM_A swizzle layout)
    float wd0 = wdp[2 * l], wd1 = wdp[2 * l + 1];
    float bb0 = bm0p[2 * l], bb1 = bm0p[2 * l + 1];
    const unsigned int* Pb = (const unsigned int*)P;
    unsigned int* G32 = (unsigned int*)G;
    for (int n = 0; n < 16; ++n) {
        float a0 = 0.0f, a1 = 0.0f;
#pragma unroll
        for (int k = 0; k < KNN; ++k) {
            int e = n * KNN + k;
            int sid = sidE[e];
            float dd = dE[e], ww = wE[e];
            unsigned int pr = Pb[(bbase + sid) * 64 + l];
            float p0 = __uint_as_float(pr << 16);
            float p1 = __uint_as_float(pr & 0xFFFF0000u);
            float g0 = gelu_f(fmaf(dd, wd0, p0 + bb0));
            float g1 = gelu_f(fmaf(dd, wd1, p1 + bb1));
            a0 = fmaf(ww, g0, a0);
            a1 = fmaf(ww, g1, a1);
        }
        unsigned int pk = (unsigned int)f2bf(a0) | ((unsigned int)f2bf(a1) << 16);
        G32[n * 64 + ((l >> 2) ^ n) * 4 + (l & 3)] = pk;
    }
    // GEMM_A: agg = gagg @ Wm1  (K=128 over perm space)
    f32x4 accA[4];
#pragma unroll
    for (int nt = 0; nt < 4; ++nt) accA[nt] = (f32x4){0.f, 0.f, 0.f, 0.f};
#pragma unroll
    for (int ks = 0; ks < 4; ++ks) {
        short8 a = *(const short8*)(&G[lr * 128 + ((ks * 4 + lk) ^ lr) * 8]);
#pragma unroll
        for (int nt = 0; nt < 4; ++nt) {
            short8 bb = *(const short8*)(Wm1p + (nt * 16 + lr) * 128 + ks * 32 + lk * 8);
            accA[nt] = mfma_bf16(a, bb, accA[nt]);
        }
    }
#pragma unroll
    for (int nt = 0; nt < 4; ++nt) {
        int col = nt * 16 + lr;
        float bias = bm1[col];
#pragma unroll
        for (int j = 0; j < 4; ++j) {
            int row = lk * 4 + j;
            AG[row * 64 + ((col >> 3) ^ (row & 7)) * 8 + (col & 7)] =
                f2bf(accA[nt][j] + bias);
        }
    }
    // GEMM3: u=[x|agg] @ Wu0
    f32x4 acc[8];
#pragma unroll
    for (int nt = 0; nt < 8; ++nt) acc[nt] = (f32x4){0.f, 0.f, 0.f, 0.f};
#pragma unroll
    for (int ks = 0; ks < 4; ++ks) {
        short8 a;
        if (ks < 2) a = *(const short8*)(&X[lr * 64 + ((ks * 4 + lk) ^ (lr & 7)) * 8]);
        else        a = *(const short8*)(&AG[lr * 64 + (((ks - 2) * 4 + lk) ^ (lr & 7)) * 8]);
#pragma unroll
        for (int nt = 0; nt < 8; ++nt) {
            short8 bb = *(const short8*)(WTu0 + (nt * 16 + lr) * 128 + ks * 32 + lk * 8);
            acc[nt] = mfma_bf16(a, bb, acc[nt]);
        }
    }
#pragma unroll
    for (int nt = 0; nt < 8; ++nt) {
        int col = nt * 16 + lr;
        float bias = bu0[col];
#pragma unroll
        for (int j = 0; j < 4; ++j) {
            int lrow = lk * 4 + j;
            float v = gelu_f(acc[nt][j] + bias);
            H[lrow * 128 + ((col >> 3) ^ lrow) * 8 + (col & 7)] = f2bf(v);
        }
    }
    // GEMM4: h @ Wu1
    f32x4 acc2[4];
#pragma unroll
    for (int nt = 0; nt < 4; ++nt) acc2[nt] = (f32x4){0.f, 0.f, 0.f, 0.f};
#pragma unroll
    for (int ks = 0; ks < 4; ++ks) {
        short8 a = *(const short8*)(&H[lr * 128 + ((ks * 4 + lk) ^ lr) * 8]);
#pragma unroll
        for (int nt = 0; nt < 4; ++nt) {
            short8 bb = *(const short8*)(WTu1 + (nt * 16 + lr) * 128 + ks * 32 + lk * 8);
            acc2[nt] = mfma_bf16(a, bb, acc2[nt]);
        }
    }
    // residual + LN
    float vals[4][4];
#pragma unroll
    for (int j = 0; j < 4; ++j) {
        int row = lk * 4 + j;
#pragma unroll
        for (int nt = 0; nt < 4; ++nt) {
            int col = nt * 16 + lr;
            float x = bf2f(X[row * 64 + ((col >> 3) ^ (row & 7)) * 8 + (col & 7)]);
            vals[j][nt] = x + acc2[nt][j] + bu1[col];
        }
    }
#pragma unroll
    for (int j = 0; j < 4; ++j) {
        int row = lk * 4 + j;
        float s = vals[j][0] + vals[j][1] + vals[j][2] + vals[j][3];
#pragma unroll
        for (int m = 1; m < 16; m <<= 1) s += __shfl_xor(s, m, 64);
        float mean = s * (1.0f / 64.0f);
        float vs = 0.0f;
#pragma unroll
        for (int nt = 0; nt < 4; ++nt) { float d = vals[j][nt] - mean; vs += d * d; }
#pragma unroll
        for (int m = 1; m < 16; m <<= 1) vs += __shfl_xor(vs, m, 64);
        float inv = rsqrtf(vs * (1.0f / 64.0f) + 1e-6f);
#pragma unroll
        for (int nt = 0; nt < 4; ++nt) {
            int col = nt * 16 + lr;
            float o = (vals[j][nt] - mean) * inv * lng[col] + lnb[col];
            unsigned short ob = f2bf(o);
            nodes_out[((size_t)(n0 + row)) * 64 + col] = ob;
            XO[row * 64 + ((col >> 3) ^ (row & 7)) * 8 + (col & 7)] = ob;
        }
    }
    // next-iteration P = ln_out @ Wm0next[0:64]
    if (doP) {
        f32x4 accP[8];
#pragma unroll
        for (int nt = 0; nt < 8; ++nt) accP[nt] = (f32x4){0.f, 0.f, 0.f, 0.f};
#pragma unroll
        for (int ks = 0; ks < 2; ++ks) {
            short8 aa = *(const short8*)(&XO[lr * 64 + ((ks * 4 + lk) ^ (lr & 7)) * 8]);
#pragma unroll
            for (int nt = 0; nt < 8; ++nt) {
                short8 bb = *(const short8*)(Wm0n + (nt * 16 + lr) * 64 + ks * 32 + lk * 8);
                accP[nt] = mfma_bf16(aa, bb, accP[nt]);
            }
        }
#pragma unroll
        for (int j = 0; j < 4; ++j) {
            int node = n0 + lk * 4 + j;
            short8 ps;
#pragma unroll
            for (int nt = 0; nt < 8; ++nt) ps[nt] = (short)f2bf(accP[nt][j]);
            *(short8*)(Pout + (size_t)node * 128 + lr * 8) = ps;
        }
    }
}

// ---------------- head (MFMA): 64 test nodes per WG ----------------
__global__ __launch_bounds__(256) void k_head2(
    const unsigned short* __restrict__ nodes,
    const unsigned short* __restrict__ WT0, const float* __restrict__ b0,
    const unsigned short* __restrict__ WT1, const float* __restrict__ b1,
    const float* __restrict__ W2, const float* __restrict__ b2,
    float* __restrict__ out)
{
    __shared__ unsigned short H0[4][16 * 256];
    __shared__ unsigned short H1[4][16 * 72];
    int t = threadIdx.x;
    int wave = t >> 6, lane = t & 63, lr = lane & 15, lk = lane >> 4;
    int rb = wave * 16;
    int n0 = blockIdx.x * 64;
    int bq = n0 / NT, nloc0 = n0 % NT;
    size_t grow = (size_t)(bq * NN + NC + nloc0 + rb);
    short8 a0 = *(const short8*)(nodes + (grow + lr) * 64 + lk * 8);
    short8 a1 = *(const short8*)(nodes + (grow + lr) * 64 + 32 + lk * 8);
    f32x4 acc0[16];
#pragma unroll
    for (int nt = 0; nt < 16; ++nt) {
        short8 bb0 = *(const short8*)(WT0 + (nt * 16 + lr) * 64 + lk * 8);
        short8 bb1 = *(const short8*)(WT0 + (nt * 16 + lr) * 64 + 32 + lk * 8);
        f32x4 z = (f32x4){0.f, 0.f, 0.f, 0.f};
        z = mfma_bf16(a0, bb0, z);
        acc0[nt] = mfma_bf16(a1, bb1, z);
    }
    unsigned short* h0 = &H0[wave][0];
#pragma unroll
    for (int nt = 0; nt < 16; ++nt) {
        int col = nt * 16 + lr;
        float bias = b0[col];
        int u = col >> 3;
#pragma unroll
        for (int j = 0; j < 4; ++j) {
            int row = lk * 4 + j;
            float v = gelu_f(acc0[nt][j] + bias);
            int us = (u & 16) | ((u ^ row) & 15);
            h0[row * 256 + us * 8 + (col & 7)] = f2bf(v);
        }
    }
    f32x4 acc1[4];
#pragma unroll
    for (int nt = 0; nt < 4; ++nt) acc1[nt] = (f32x4){0.f, 0.f, 0.f, 0.f};
#pragma unroll
    for (int ks = 0; ks < 8; ++ks) {
        int u = ks * 4 + lk;
        int us = (u & 16) | ((u ^ lr) & 15);
        short8 aa = *(const short8*)(&h0[lr * 256 + us * 8]);
#pragma unroll
        for (int nt = 0; nt < 4; ++nt) {
            short8 bb = *(const short8*)(WT1 + (nt * 16 + lr) * 256 + ks * 32 + lk * 8);
            acc1[nt] = mfma_bf16(aa, bb, acc1[nt]);
        }
    }
    unsigned short* h1 = &H1[wave][0];
#pragma unroll
    for (int nt = 0; nt < 4; ++nt) {
        int col = nt * 16 + lr;
        float bias = b1[col];
#pragma unroll
        for (int j = 0; j < 4; ++j) {
            int row = lk * 4 + j;
            h1[row * 72 + col] = f2bf(gelu_f(acc1[nt][j] + bias));
        }
    }
    int task = lane >> 1;
    int row = task >> 1;
    int o = task & 1;
    int t2 = lane & 1;
    float p = 0.0f;
#pragma unroll
    for (int d = 0; d < 32; ++d) {
        int dd = t2 * 32 + d;
        p += bf2f(h1[row * 72 + dd]) * W2[dd * 2 + o];
    }
    p += __shfl_xor(p, 1, 64);
    if (t2 == 0) {
        int gg = n0 + rb + row;
        if (o == 0) out[gg] = p + b2[0];
        else        out[BB * NT + gg] = __expf(0.5f * (p + b2[1]));
    }
}

extern "C" void kernel_launch(void* const* d_in, const int* in_sizes, int n_in,
                              void* d_out, int out_size, void* d_ws, size_t ws_size,
                              hipStream_t stream)
{
    (void)in_sizes; (void)n_in; (void)out_size; (void)ws_size;
    const float* s_ctx   = (const float*)d_in[0];
    const float* f_ctx   = (const float*)d_in[1];
    const float* s_test  = (const float*)d_in[2];
    const int*   valid   = (const int*)d_in[3];
    const float* emb_obs = (const float*)d_in[4];
    const float* ea_W0   = (const float*)d_in[5];
    const float* ea_b0   = (const float*)d_in[6];
    const float* ea_W1   = (const float*)d_in[7];
    const float* ea_b1   = (const float*)d_in[8];
    const float* ea_W2   = (const float*)d_in[9];
    const float* ea_b2   = (const float*)d_in[10];
    const float* ln_g    = (const float*)d_in[11];
    const float* ln_b    = (const float*)d_in[12];
    const float* blk_Wm0 = (const float*)d_in[13];
    const float* blk_bm0 = (const float*)d_in[14];
    const float* blk_Wm1 = (const float*)d_in[15];
    const float* blk_bm1 = (const float*)d_in[16];
    const float* blk_Wu0 = (const float*)d_in[17];
    const float* blk_bu0 = (const float*)d_in[18];
    const float* blk_Wu1 = (const float*)d_in[19];
    const float* blk_bu1 = (const float*)d_in[20];
    const float* blk_lng = (const float*)d_in[21];
    const float* blk_lnb = (const float*)d_in[22];
    const float* hd_W0   = (const float*)d_in[23];
    const float* hd_b0   = (const float*)d_in[24];
    const float* hd_W1   = (const float*)d_in[25];
    const float* hd_b1   = (const float*)d_in[26];
    const float* hd_W2   = (const float*)d_in[27];
    const float* hd_b2   = (const float*)d_in[28];

    char* p = (char*)d_ws;
    auto alloc = [&](size_t bytes) { char* r = p; p += (bytes + 255) & ~(size_t)255; return r; };
    unsigned short* nodesA = (unsigned short*)alloc((size_t)NODES * 64 * 2);
    unsigned short* nodesB = (unsigned short*)alloc((size_t)NODES * 64 * 2);
    unsigned short* Pbuf   = (unsigned short*)alloc((size_t)NODES * 128 * 2);
    float* dists   = (float*)alloc((size_t)NODES * KNN * 4);
    float* wbuf    = (float*)alloc((size_t)NODES * KNN * 4);
    int*   senders = (int*)alloc((size_t)NODES * KNN * 4);
    unsigned short* wtm0  = (unsigned short*)alloc((size_t)6 * 8192 * 2);
    unsigned short* wtm1p = (unsigned short*)alloc((size_t)6 * 8192 * 2);
    unsigned short* wtu0  = (unsigned short*)alloc((size_t)6 * 16384 * 2);
    unsigned short* wtu1  = (unsigned short*)alloc((size_t)6 * 8192 * 2);
    float* wdp  = (float*)alloc((size_t)6 * 128 * 4);
    float* bm0p = (float*)alloc((size_t)6 * 128 * 4);
    unsigned short* wte0 = (unsigned short*)alloc((size_t)8192 * 2);
    unsigned short* wte1 = (unsigned short*)alloc((size_t)32768 * 2);
    unsigned short* wte2 = (unsigned short*)alloc((size_t)8192 * 2);
    unsigned short* wth0 = (unsigned short*)alloc((size_t)16384 * 2);
    unsigned short* wth1 = (unsigned short*)alloc((size_t)16384 * 2);
    float4* s4 = (float4*)alloc((size_t)BB * NC * 16);

    k_convw<<<1286, 256, 0, stream>>>(
        blk_Wm0, blk_Wm1, blk_Wu0, blk_Wu1, blk_bm0,
        ea_W0, ea_W1, ea_W2, hd_W0, hd_W1,
        wtm0, wtm1p, wtu0, wtu1, wdp, bm0p, wte0, wte1, wte2, wth0, wth1);

    k_prep<<<(BB * NC + 255) / 256, 256, 0, stream>>>(s_ctx, s4);

    k_embed2<<<NODES / 64, 256, 0, stream>>>(s_ctx, f_ctx, s_test, emb_obs,
        wte0, ea_b0, wte1, ea_b1, wte2, ea_b2, ln_g, ln_b, wtm0, nodesA, Pbuf);

    k_topk<<<NODES / 4, 256, 0, stream>>>(s4, s_ctx, s_test, valid,
                                          dists, senders, wbuf);

    unsigned short* nin = nodesA; unsigned short* nout = nodesB;
    for (int i = 0; i < NBLK; ++i) {
        int doP = (i < NBLK - 1) ? 1 : 0;
        const unsigned short* wm0n = wtm0 + (size_t)((i + 1) % NBLK) * 8192;
        k_blk<<<NODES / 16, 64, 0, stream>>>(nin, Pbuf, dists, senders, wbuf,
            wdp + (size_t)i * 128, bm0p + (size_t)i * 128,
            wtm1p + (size_t)i * 8192, blk_bm1 + (size_t)i * 64,
            wtu0 + (size_t)i * 16384, blk_bu0 + (size_t)i * 128,
            wtu1 + (size_t)i * 8192, blk_bu1 + (size_t)i * 64,
            blk_lng + (size_t)i * 64, blk_lnb + (size_t)i * 64,
            wm0n, doP, nout, Pbuf);
        unsigned short* tmp = nin; nin = nout; nout = tmp;
    }

    k_head2<<<BB * NT / 64, 256, 0, stream>>>(nin, wth0, hd_b0, wth1, hd_b1,
                                              hd_W2, hd_b2, (float*)d_out);
}

// Round 7
// 304.911 us; speedup vs baseline: 6.9639x; 1.2644x over previous
//
#include <hip/hip_runtime.h>
#include <math.h>

#define BB 4
#define NC 4096
#define NT 1024
#define NN (NC + NT)      // 5120
#define NODES (BB * NN)   // 20480
#define DD 64
#define KNN 10
#define NBLK 6
#define BIGF 3.0e38f

typedef __attribute__((ext_vector_type(8))) short short8;
typedef __attribute__((ext_vector_type(4))) float f32x4;
typedef __attribute__((ext_vector_type(4))) int int4v;

__device__ __forceinline__ unsigned short f2bf(float f) {
    unsigned int u = __float_as_uint(f);
    unsigned int r = (u + 0x7fffu + ((u >> 16) & 1u)) >> 16;
    return (unsigned short)r;
}
__device__ __forceinline__ float bf2f(unsigned short h) {
    return __uint_as_float(((unsigned int)h) << 16);
}

__device__ __forceinline__ float gelu_f(float x) {
    const float c0 = 0.7978845608028654f;
    float x3 = x * x * x;
    float z2 = 2.0f * c0 * (x + 0.044715f * x3);
    float e = __expf(z2);
    float r = __builtin_amdgcn_rcpf(1.0f + e);
    return x - x * r;
}

__device__ __forceinline__ float wave_sum(float v) {
#pragma unroll
    for (int off = 32; off > 0; off >>= 1) v += __shfl_xor(v, off, 64);
    return v;
}

__device__ __forceinline__ f32x4 mfma_bf16(short8 a, short8 b, f32x4 c) {
    asm("v_mfma_f32_16x16x32_bf16 %0, %1, %2, %0" : "+v"(c) : "v"(a), "v"(b));
    return c;
}

// perm(col) = (col&15)*8 + (col>>4); invperm(cp) = ((cp&7)<<4) | (cp>>3)

// ---------------- weight convert + s4 pack ----------------
__global__ __launch_bounds__(256) void k_convw(
    const float* __restrict__ Wm0, const float* __restrict__ Wm1,
    const float* __restrict__ Wu0, const float* __restrict__ Wu1,
    const float* __restrict__ bm0,
    const float* __restrict__ eW0, const float* __restrict__ eW1,
    const float* __restrict__ eW2,
    const float* __restrict__ hW0, const float* __restrict__ hW1,
    const float* __restrict__ sctx,
    unsigned short* __restrict__ wtm0, unsigned short* __restrict__ wtm1p,
    unsigned short* __restrict__ wtu0, unsigned short* __restrict__ wtu1,
    float* __restrict__ wdp, float* __restrict__ bm0p,
    unsigned short* __restrict__ wte0, unsigned short* __restrict__ wte1,
    unsigned short* __restrict__ wte2,
    unsigned short* __restrict__ wth0, unsigned short* __restrict__ wth1,
    float4* __restrict__ s4)
{
    int t = blockIdx.x * 256 + threadIdx.x;
    if (t < 49152) {                 // wtm0 [6][128][64] <- Wm0[i][k][n], k<64
        int i = t / 8192, r = t % 8192, n = r / 64, k = r % 64;
        wtm0[t] = f2bf(Wm0[(i * 65 + k) * 128 + n]);
    } else if (t < 98304) {          // wtm1p [6][64][128]: [n][cp] = Wm1[i][invperm(cp)][n]
        int u = t - 49152;
        int i = u / 8192, r = u % 8192, n = r / 128, cp = r % 128;
        int col = ((cp & 7) << 4) | (cp >> 3);
        wtm1p[u] = f2bf(Wm1[(i * 128 + col) * 64 + n]);
    } else if (t < 196608) {         // wtu0 [6][128][128]
        int u = t - 98304;
        int i = u / 16384, r = u % 16384, n = r / 128, k = r % 128;
        wtu0[u] = f2bf(Wu0[(i * 128 + k) * 128 + n]);
    } else if (t < 245760) {         // wtu1 [6][64][128]
        int u = t - 196608;
        int i = u / 8192, r = u % 8192, n = r / 128, k = r % 128;
        wtu1[u] = f2bf(Wu1[(i * 128 + k) * 64 + n]);
    } else if (t < 246528) {         // wdp [6][128] perm
        int u = t - 245760;
        int i = u / 128, cp = u % 128;
        int col = ((cp & 7) << 4) | (cp >> 3);
        wdp[u] = Wm0[(i * 65 + 64) * 128 + col];
    } else if (t < 247296) {         // bm0p [6][128] perm
        int u = t - 246528;
        int i = u / 128, cp = u % 128;
        int col = ((cp & 7) << 4) | (cp >> 3);
        bm0p[u] = bm0[i * 128 + col];
    } else if (t < 255488) {         // wte0 [256][32], k<11 else 0
        int u = t - 247296;
        int n = u / 32, k = u % 32;
        wte0[u] = (k < 11) ? f2bf(eW0[k * 256 + n]) : 0;
    } else if (t < 288256) {         // wte1 [128][256]
        int u = t - 255488;
        int n = u / 256, k = u % 256;
        wte1[u] = f2bf(eW1[k * 128 + n]);
    } else if (t < 296448) {         // wte2 [64][128]
        int u = t - 288256;
        int n = u / 128, k = u % 128;
        wte2[u] = f2bf(eW2[k * 64 + n]);
    } else if (t < 312832) {         // wth0 [256][64]
        int u = t - 296448;
        int n = u / 64, k = u % 64;
        wth0[u] = f2bf(hW0[k * 256 + n]);
    } else if (t < 329216) {         // wth1 [64][256]
        int u = t - 312832;
        int n = u / 256, k = u % 256;
        wth1[u] = f2bf(hW1[k * 64 + n]);
    } else if (t < 329216 + BB * NC) {  // s4 pack
        int u = t - 329216;
        float x = sctx[u * 3], y = sctx[u * 3 + 1], z = sctx[u * 3 + 2];
        s4[u] = make_float4(x, y, z, 0.0f);
    }
}

// ---------------- embed (MFMA) + P0: 64 nodes per WG, 4 waves, barrier-free ----------------
__global__ __launch_bounds__(256) void k_embed2(
    const float* __restrict__ s_ctx, const float* __restrict__ f_ctx,
    const float* __restrict__ s_test, const float* __restrict__ emb_obs,
    const unsigned short* __restrict__ WT0, const float* __restrict__ b0,
    const unsigned short* __restrict__ WT1, const float* __restrict__ b1,
    const unsigned short* __restrict__ WT2, const float* __restrict__ b2,
    const float* __restrict__ g, const float* __restrict__ bta,
    const unsigned short* __restrict__ Wm0n,     // [128][64] (block 0)
    unsigned short* __restrict__ nodes,
    unsigned short* __restrict__ Pout)           // bf16 [NODES][128] perm
{
    __shared__ unsigned short H0[4][16 * 256];
    __shared__ unsigned short H1[4][16 * 128];
    __shared__ unsigned short XO[4][16 * 64];
    int t = threadIdx.x;
    int wave = t >> 6, lane = t & 63, lr = lane & 15, lk = lane >> 4;
    int rb = wave * 16;
    int n0 = blockIdx.x * 64;
    int bq = n0 / NN, nloc0 = n0 % NN;
    bool is_ctx = nloc0 < NC;
    int nr = nloc0 + rb + lr;
    float xv[8];
#pragma unroll
    for (int j = 0; j < 8; ++j) xv[j] = 0.0f;
    if (lk == 0) {
        const float* eb = emb_obs + (is_ctx ? 4 : 0);
        xv[0] = eb[0]; xv[1] = eb[1]; xv[2] = eb[2]; xv[3] = eb[3];
        if (is_ctx) {
            const float* sp = s_ctx + ((size_t)(bq * NC + nr)) * 3;
            const float* fp = f_ctx + ((size_t)(bq * NC + nr)) * 4;
            xv[4] = sp[0]; xv[5] = sp[1]; xv[6] = sp[2]; xv[7] = fp[0];
        } else {
            const float* sp = s_test + ((size_t)(bq * NT + nr - NC)) * 3;
            xv[4] = sp[0]; xv[5] = sp[1]; xv[6] = sp[2];
        }
    } else if (lk == 1 && is_ctx) {
        const float* fp = f_ctx + ((size_t)(bq * NC + nr)) * 4;
        xv[0] = fp[1]; xv[1] = fp[2]; xv[2] = fp[3];
    }
    short8 a;
#pragma unroll
    for (int j = 0; j < 8; ++j) a[j] = (short)f2bf(xv[j]);

    f32x4 acc0[16];
#pragma unroll
    for (int nt = 0; nt < 16; ++nt) {
        short8 bb = *(const short8*)(WT0 + (nt * 16 + lr) * 32 + lk * 8);
        f32x4 z = (f32x4){0.f, 0.f, 0.f, 0.f};
        acc0[nt] = mfma_bf16(a, bb, z);
    }
    unsigned short* h0 = &H0[wave][0];
#pragma unroll
    for (int nt = 0; nt < 16; ++nt) {
        int col = nt * 16 + lr;
        float bias = b0[col];
        int u = col >> 3;
#pragma unroll
        for (int j = 0; j < 4; ++j) {
            int row = lk * 4 + j;
            float v = gelu_f(acc0[nt][j] + bias);
            int us = (u & 16) | ((u ^ row) & 15);
            h0[row * 256 + us * 8 + (col & 7)] = f2bf(v);
        }
    }
    f32x4 acc1[8];
#pragma unroll
    for (int nt = 0; nt < 8; ++nt) acc1[nt] = (f32x4){0.f, 0.f, 0.f, 0.f};
#pragma unroll
    for (int ks = 0; ks < 8; ++ks) {
        int u = ks * 4 + lk;
        int us = (u & 16) | ((u ^ lr) & 15);
        short8 aa = *(const short8*)(&h0[lr * 256 + us * 8]);
#pragma unroll
        for (int nt = 0; nt < 8; ++nt) {
            short8 bb = *(const short8*)(WT1 + (nt * 16 + lr) * 256 + ks * 32 + lk * 8);
            acc1[nt] = mfma_bf16(aa, bb, acc1[nt]);
        }
    }
    unsigned short* h1 = &H1[wave][0];
#pragma unroll
    for (int nt = 0; nt < 8; ++nt) {
        int col = nt * 16 + lr;
        float bias = b1[col];
        int u = col >> 3;
#pragma unroll
        for (int j = 0; j < 4; ++j) {
            int row = lk * 4 + j;
            float v = gelu_f(acc1[nt][j] + bias);
            int us = (u ^ row) & 15;
            h1[row * 128 + us * 8 + (col & 7)] = f2bf(v);
        }
    }
    f32x4 acc2[4];
#pragma unroll
    for (int nt = 0; nt < 4; ++nt) acc2[nt] = (f32x4){0.f, 0.f, 0.f, 0.f};
#pragma unroll
    for (int ks = 0; ks < 4; ++ks) {
        int u = ks * 4 + lk;
        int us = (u ^ lr) & 15;
        short8 aa = *(const short8*)(&h1[lr * 128 + us * 8]);
#pragma unroll
        for (int nt = 0; nt < 4; ++nt) {
            short8 bb = *(const short8*)(WT2 + (nt * 16 + lr) * 128 + ks * 32 + lk * 8);
            acc2[nt] = mfma_bf16(aa, bb, acc2[nt]);
        }
    }
    float vals[4][4];
#pragma unroll
    for (int j = 0; j < 4; ++j)
#pragma unroll
        for (int nt = 0; nt < 4; ++nt)
            vals[j][nt] = acc2[nt][j] + b2[nt * 16 + lr];
    unsigned short* xo = &XO[wave][0];
#pragma unroll
    for (int j = 0; j < 4; ++j) {
        float s = vals[j][0] + vals[j][1] + vals[j][2] + vals[j][3];
#pragma unroll
        for (int m = 1; m < 16; m <<= 1) s += __shfl_xor(s, m, 64);
        float mean = s * (1.0f / 64.0f);
        float vs = 0.0f;
#pragma unroll
        for (int nt = 0; nt < 4; ++nt) { float d = vals[j][nt] - mean; vs += d * d; }
#pragma unroll
        for (int m = 1; m < 16; m <<= 1) vs += __shfl_xor(vs, m, 64);
        float inv = rsqrtf(vs * (1.0f / 64.0f) + 1e-6f);
        int row = lk * 4 + j;
        int node = n0 + rb + row;
#pragma unroll
        for (int nt = 0; nt < 4; ++nt) {
            int col = nt * 16 + lr;
            float o = (vals[j][nt] - mean) * inv * g[col] + bta[col];
            unsigned short ob = f2bf(o);
            nodes[(size_t)node * 64 + col] = ob;
            xo[row * 64 + ((col >> 3) ^ (row & 7)) * 8 + (col & 7)] = ob;
        }
    }
    // P0 = ln_out @ Wm0[0][0:64]
    f32x4 accP[8];
#pragma unroll
    for (int nt = 0; nt < 8; ++nt) accP[nt] = (f32x4){0.f, 0.f, 0.f, 0.f};
#pragma unroll
    for (int ks = 0; ks < 2; ++ks) {
        short8 aa = *(const short8*)(&xo[lr * 64 + ((ks * 4 + lk) ^ (lr & 7)) * 8]);
#pragma unroll
        for (int nt = 0; nt < 8; ++nt) {
            short8 bb = *(const short8*)(Wm0n + (nt * 16 + lr) * 64 + ks * 32 + lk * 8);
            accP[nt] = mfma_bf16(aa, bb, accP[nt]);
        }
    }
#pragma unroll
    for (int j = 0; j < 4; ++j) {
        int node = n0 + rb + lk * 4 + j;
        short8 ps;
#pragma unroll
        for (int nt = 0; nt < 8; ++nt) ps[nt] = (short)f2bf(accP[nt][j]);
        *(short8*)(Pout + (size_t)node * 128 + lr * 8) = ps;
    }
}

// ---------------- top-K: one wave per 4 receivers (R-tiled), med3 insert ----------------
__global__ __launch_bounds__(256) void k_topk(
    const float4* __restrict__ s4, const float* __restrict__ s_ctx,
    const float* __restrict__ s_test, const int* __restrict__ valid_lens,
    float* __restrict__ dists, int* __restrict__ senders, float* __restrict__ wout)
{
    __shared__ float cd[4 * 64 * 11];
    __shared__ float seld[4][4][12];
    __shared__ int   seli[4][4][12];
    __shared__ int   eqis[4][4][12];
    int wave = threadIdx.x >> 6;
    int lane = threadIdx.x & 63;
    int r0 = blockIdx.x * 16 + wave * 4;     // 4 consecutive receivers, same batch
    int b = r0 / NN;
    int vl = valid_lens[b];
    const float4* sc = s4 + (size_t)b * NC;
    float px[4], py[4], pz[4];
#pragma unroll
    for (int q = 0; q < 4; ++q) {
        int n = (r0 + q) % NN;
        const float* p = (n < NC) ? &s_ctx[(size_t)(b * NC + n) * 3]
                                  : &s_test[(size_t)(b * NT + (n - NC)) * 3];
        px[q] = p[0]; py[q] = p[1]; pz[q] = p[2];
    }
    float bq[4][KNN];
#pragma unroll
    for (int q = 0; q < 4; ++q)
#pragma unroll
        for (int k = 0; k < KNN; ++k) bq[q][k] = BIGF;
    // passA: one sender load serves 4 receivers
#pragma unroll 8
    for (int i = 0; i < 64; ++i) {
        int j = lane + (i << 6);
        float4 s = sc[j];
        bool ok = j < vl;
#pragma unroll
        for (int q = 0; q < 4; ++q) {
            float dx = px[q] - s.x, dy = py[q] - s.y, dz = pz[q] - s.z;
            float d2 = fmaf(dx, dx, fmaf(dy, dy, dz * dz));
            d2 = ok ? d2 : BIGF;
#pragma unroll
            for (int k = KNN - 1; k >= 1; --k)
                bq[q][k] = __builtin_amdgcn_fmed3f(bq[q][k - 1], bq[q][k], d2);
            bq[q][0] = fminf(bq[q][0], d2);
        }
    }
    // merge per receiver (cd is lane-private indexable storage; no cross-lane use)
    int base = (wave * 64 + lane) * 11;
    float T[4], dmin[4];
    int m[4];
#pragma unroll
    for (int q = 0; q < 4; ++q) {
#pragma unroll
        for (int k = 0; k < KNN; ++k) cd[base + k] = bq[q][k];
        __builtin_amdgcn_wave_barrier();
        int head = 0;
        float myd = 0.0f;
#pragma unroll
        for (int rr = 0; rr < KNN; ++rr) {
            float v = cd[base + head];
            float mv = v;
#pragma unroll
            for (int off = 32; off > 0; off >>= 1) mv = fminf(mv, __shfl_xor(mv, off, 64));
            unsigned long long ball = __ballot(v == mv);
            int win = __ffsll(ball) - 1;
            if (lane == win) head++;
            if (lane == rr) myd = mv;
        }
        T[q] = __shfl(myd, 9, 64);
        dmin[q] = sqrtf(__shfl(myd, 0, 64));
        m[q] = __popcll(__ballot(lane < KNN && myd < T[q]));
    }
    // passB: recompute distances, ballot-compact indices (index order; ties by index)
    unsigned long long below = (lane == 63) ? 0x7FFFFFFFFFFFFFFFull
                                            : ((1ull << lane) - 1);
    int cless[4] = {0, 0, 0, 0}, ceq[4] = {0, 0, 0, 0};
#pragma unroll 4
    for (int i = 0; i < 64; ++i) {
        int j = lane + (i << 6);
        float4 s = sc[j];
        bool ok = j < vl;
#pragma unroll
        for (int q = 0; q < 4; ++q) {
            float dx = px[q] - s.x, dy = py[q] - s.y, dz = pz[q] - s.z;
            float v = fmaf(dx, dx, fmaf(dy, dy, dz * dz));
            v = ok ? v : BIGF;
            unsigned long long ml = __ballot(v < T[q]);
            unsigned long long me = __ballot(v == T[q]);
            if (v < T[q]) {
                int slot = cless[q] + __popcll(ml & below);
                if (slot < 12) { seld[wave][q][slot] = v; seli[wave][q][slot] = j; }
            }
            if (v == T[q]) {
                int qq = ceq[q] + __popcll(me & below);
                if (qq < 12) eqis[wave][q][qq] = j;
            }
            cless[q] += __popcll(ml);
            ceq[q] += __popcll(me);
        }
    }
    __builtin_amdgcn_wave_barrier();
#pragma unroll
    for (int q = 0; q < 4; ++q) {
        float e = 0.0f, d = 0.0f;
        int isel = 0;
        if (lane < KNN) {
            float vsel;
            if (lane < m[q]) { vsel = seld[wave][q][lane]; isel = seli[wave][q][lane]; }
            else             { vsel = T[q];                isel = eqis[wave][q][lane - m[q]]; }
            d = sqrtf(vsel);
            e = __expf(-(d - dmin[q]));
        }
        float ssum = wave_sum(e);
        if (lane < KNN) {
            size_t o = (size_t)(r0 + q) * KNN + lane;
            dists[o] = d;
            senders[o] = isel;
            wout[o] = e / ssum;
        }
    }
}

// ---------------- fused block: 4-wave gather + wave-0 GEMM chain ----------------
// 16 nodes per 256-thread block
__global__ __launch_bounds__(256) void k_blk(
    const unsigned short* __restrict__ nodes_in,
    const unsigned short* __restrict__ P,        // bf16 [NODES][128] perm
    const float* __restrict__ dists, const int* __restrict__ senders,
    const float* __restrict__ w,
    const float* __restrict__ wdp, const float* __restrict__ bm0p,
    const unsigned short* __restrict__ Wm1p,     // [64][128] (perm k)
    const float* __restrict__ bm1,
    const unsigned short* __restrict__ WTu0,     // [128][128]
    const float* __restrict__ bu0,
    const unsigned short* __restrict__ WTu1,     // [64][128]
    const float* __restrict__ bu1,
    const float* __restrict__ lng, const float* __restrict__ lnb,
    const unsigned short* __restrict__ Wm0n,     // [128][64] next-iter
    const int doP,
    unsigned short* __restrict__ nodes_out,
    unsigned short* __restrict__ Pout)
{
    __shared__ unsigned short X[16 * 64];
    __shared__ unsigned short G[16 * 128];
    __shared__ unsigned short AG[16 * 64];
    __shared__ unsigned short H[16 * 128];
    __shared__ unsigned short XO[16 * 64];
    __shared__ int   sidE[160];
    __shared__ float dE[160], wE[160];
    int l = threadIdx.x;
    int wave = l >> 6, lane = l & 63;
    int n0 = blockIdx.x * 16;
    int b = n0 / NN;
    size_t bbase = (size_t)b * NN;
    int e0 = n0 * KNN;
    // edge meta staging (256 threads cover 160 edges)
    if (l < 160) {
        sidE[l] = senders[e0 + l];
        dE[l]   = dists[e0 + l];
        wE[l]   = w[e0 + l];
    }
    // stage X [16][64] swizzled (threads 0..127, 16B each)
    if (l < 128) {
        int row = l >> 3, u = l & 7;
        int4v v = *(const int4v*)(nodes_in + ((size_t)(n0 + row)) * 64 + u * 8);
        *(int4v*)(&X[row * 64 + (u ^ (row & 7)) * 8]) = v;
    }
    __syncthreads();
    // gather + gelu + weighted sum -> G; wave w handles nodes w*4 .. w*4+3
    float wd0 = wdp[2 * lane], wd1 = wdp[2 * lane + 1];
    float bb0 = bm0p[2 * lane], bb1 = bm0p[2 * lane + 1];
    const unsigned int* Pb = (const unsigned int*)P;
    unsigned int* G32 = (unsigned int*)G;
#pragma unroll
    for (int nn = 0; nn < 4; ++nn) {
        int n = wave * 4 + nn;
        float a0 = 0.0f, a1 = 0.0f;
#pragma unroll
        for (int k = 0; k < KNN; ++k) {
            int e = n * KNN + k;
            int sid = sidE[e];
            float dd = dE[e], ww = wE[e];
            unsigned int pr = Pb[(bbase + sid) * 64 + lane];
            float p0 = __uint_as_float(pr << 16);
            float p1 = __uint_as_float(pr & 0xFFFF0000u);
            float g0 = gelu_f(fmaf(dd, wd0, p0 + bb0));
            float g1 = gelu_f(fmaf(dd, wd1, p1 + bb1));
            a0 = fmaf(ww, g0, a0);
            a1 = fmaf(ww, g1, a1);
        }
        unsigned int pk = (unsigned int)f2bf(a0) | ((unsigned int)f2bf(a1) << 16);
        G32[n * 64 + ((lane >> 2) ^ n) * 4 + (lane & 3)] = pk;
    }
    __syncthreads();
    if (wave != 0) return;
    // ---- wave 0 only: GEMM chain + LN + next-P ----
    int lr = lane & 15, lk = lane >> 4;
    // GEMM_A: agg = gagg @ Wm1  (K=128 over perm space)
    f32x4 accA[4];
#pragma unroll
    for (int nt = 0; nt < 4; ++nt) accA[nt] = (f32x4){0.f, 0.f, 0.f, 0.f};
#pragma unroll
    for (int ks = 0; ks < 4; ++ks) {
        short8 a = *(const short8*)(&G[lr * 128 + ((ks * 4 + lk) ^ lr) * 8]);
#pragma unroll
        for (int nt = 0; nt < 4; ++nt) {
            short8 bb = *(const short8*)(Wm1p + (nt * 16 + lr) * 128 + ks * 32 + lk * 8);
            accA[nt] = mfma_bf16(a, bb, accA[nt]);
        }
    }
#pragma unroll
    for (int nt = 0; nt < 4; ++nt) {
        int col = nt * 16 + lr;
        float bias = bm1[col];
#pragma unroll
        for (int j = 0; j < 4; ++j) {
            int row = lk * 4 + j;
            AG[row * 64 + ((col >> 3) ^ (row & 7)) * 8 + (col & 7)] =
                f2bf(accA[nt][j] + bias);
        }
    }
    // GEMM3: u=[x|agg] @ Wu0
    f32x4 acc[8];
#pragma unroll
    for (int nt = 0; nt < 8; ++nt) acc[nt] = (f32x4){0.f, 0.f, 0.f, 0.f};
#pragma unroll
    for (int ks = 0; ks < 4; ++ks) {
        short8 a;
        if (ks < 2) a = *(const short8*)(&X[lr * 64 + ((ks * 4 + lk) ^ (lr & 7)) * 8]);
        else        a = *(const short8*)(&AG[lr * 64 + (((ks - 2) * 4 + lk) ^ (lr & 7)) * 8]);
#pragma unroll
        for (int nt = 0; nt < 8; ++nt) {
            short8 bb = *(const short8*)(WTu0 + (nt * 16 + lr) * 128 + ks * 32 + lk * 8);
            acc[nt] = mfma_bf16(a, bb, acc[nt]);
        }
    }
#pragma unroll
    for (int nt = 0; nt < 8; ++nt) {
        int col = nt * 16 + lr;
        float bias = bu0[col];
#pragma unroll
        for (int j = 0; j < 4; ++j) {
            int lrow = lk * 4 + j;
            float v = gelu_f(acc[nt][j] + bias);
            H[lrow * 128 + ((col >> 3) ^ lrow) * 8 + (col & 7)] = f2bf(v);
        }
    }
    // GEMM4: h @ Wu1
    f32x4 acc2[4];
#pragma unroll
    for (int nt = 0; nt < 4; ++nt) acc2[nt] = (f32x4){0.f, 0.f, 0.f, 0.f};
#pragma unroll
    for (int ks = 0; ks < 4; ++ks) {
        short8 a = *(const short8*)(&H[lr * 128 + ((ks * 4 + lk) ^ lr) * 8]);
#pragma unroll
        for (int nt = 0; nt < 4; ++nt) {
            short8 bb = *(const short8*)(WTu1 + (nt * 16 + lr) * 128 + ks * 32 + lk * 8);
            acc2[nt] = mfma_bf16(a, bb, acc2[nt]);
        }
    }
    // residual + LN
    float vals[4][4];
#pragma unroll
    for (int j = 0; j < 4; ++j) {
        int row = lk * 4 + j;
#pragma unroll
        for (int nt = 0; nt < 4; ++nt) {
            int col = nt * 16 + lr;
            float x = bf2f(X[row * 64 + ((col >> 3) ^ (row & 7)) * 8 + (col & 7)]);
            vals[j][nt] = x + acc2[nt][j] + bu1[col];
        }
    }
#pragma unroll
    for (int j = 0; j < 4; ++j) {
        int row = lk * 4 + j;
        float s = vals[j][0] + vals[j][1] + vals[j][2] + vals[j][3];
#pragma unroll
        for (int mm = 1; mm < 16; mm <<= 1) s += __shfl_xor(s, mm, 64);
        float mean = s * (1.0f / 64.0f);
        float vs = 0.0f;
#pragma unroll
        for (int nt = 0; nt < 4; ++nt) { float d = vals[j][nt] - mean; vs += d * d; }
#pragma unroll
        for (int mm = 1; mm < 16; mm <<= 1) vs += __shfl_xor(vs, mm, 64);
        float inv = rsqrtf(vs * (1.0f / 64.0f) + 1e-6f);
#pragma unroll
        for (int nt = 0; nt < 4; ++nt) {
            int col = nt * 16 + lr;
            float o = (vals[j][nt] - mean) * inv * lng[col] + lnb[col];
            unsigned short ob = f2bf(o);
            nodes_out[((size_t)(n0 + row)) * 64 + col] = ob;
            XO[row * 64 + ((col >> 3) ^ (row & 7)) * 8 + (col & 7)] = ob;
        }
    }
    // next-iteration P = ln_out @ Wm0next[0:64]
    if (doP) {
        f32x4 accP[8];
#pragma unroll
        for (int nt = 0; nt < 8; ++nt) accP[nt] = (f32x4){0.f, 0.f, 0.f, 0.f};
#pragma unroll
        for (int ks = 0; ks < 2; ++ks) {
            short8 aa = *(const short8*)(&XO[lr * 64 + ((ks * 4 + lk) ^ (lr & 7)) * 8]);
#pragma unroll
            for (int nt = 0; nt < 8; ++nt) {
                short8 bb = *(const short8*)(Wm0n + (nt * 16 + lr) * 64 + ks * 32 + lk * 8);
                accP[nt] = mfma_bf16(aa, bb, accP[nt]);
            }
        }
#pragma unroll
        for (int j = 0; j < 4; ++j) {
            int node = n0 + lk * 4 + j;
            short8 ps;
#pragma unroll
            for (int nt = 0; nt < 8; ++nt) ps[nt] = (short)f2bf(accP[nt][j]);
            *(short8*)(Pout + (size_t)node * 128 + lr * 8) = ps;
        }
    }
}

// ---------------- head (MFMA): 64 test nodes per WG ----------------
__global__ __launch_bounds__(256) void k_head2(
    const unsigned short* __restrict__ nodes,
    const unsigned short* __restrict__ WT0, const float* __restrict__ b0,
    const unsigned short* __restrict__ WT1, const float* __restrict__ b1,
    const float* __restrict__ W2, const float* __restrict__ b2,
    float* __restrict__ out)
{
    __shared__ unsigned short H0[4][16 * 256];
    __shared__ unsigned short H1[4][16 * 72];
    int t = threadIdx.x;
    int wave = t >> 6, lane = t & 63, lr = lane & 15, lk = lane >> 4;
    int rb = wave * 16;
    int n0 = blockIdx.x * 64;
    int bq = n0 / NT, nloc0 = n0 % NT;
    size_t grow = (size_t)(bq * NN + NC + nloc0 + rb);
    short8 a0 = *(const short8*)(nodes + (grow + lr) * 64 + lk * 8);
    short8 a1 = *(const short8*)(nodes + (grow + lr) * 64 + 32 + lk * 8);
    f32x4 acc0[16];
#pragma unroll
    for (int nt = 0; nt < 16; ++nt) {
        short8 bb0 = *(const short8*)(WT0 + (nt * 16 + lr) * 64 + lk * 8);
        short8 bb1 = *(const short8*)(WT0 + (nt * 16 + lr) * 64 + 32 + lk * 8);
        f32x4 z = (f32x4){0.f, 0.f, 0.f, 0.f};
        z = mfma_bf16(a0, bb0, z);
        acc0[nt] = mfma_bf16(a1, bb1, z);
    }
    unsigned short* h0 = &H0[wave][0];
#pragma unroll
    for (int nt = 0; nt < 16; ++nt) {
        int col = nt * 16 + lr;
        float bias = b0[col];
        int u = col >> 3;
#pragma unroll
        for (int j = 0; j < 4; ++j) {
            int row = lk * 4 + j;
            float v = gelu_f(acc0[nt][j] + bias);
            int us = (u & 16) | ((u ^ row) & 15);
            h0[row * 256 + us * 8 + (col & 7)] = f2bf(v);
        }
    }
    f32x4 acc1[4];
#pragma unroll
    for (int nt = 0; nt < 4; ++nt) acc1[nt] = (f32x4){0.f, 0.f, 0.f, 0.f};
#pragma unroll
    for (int ks = 0; ks < 8; ++ks) {
        int u = ks * 4 + lk;
        int us = (u & 16) | ((u ^ lr) & 15);
        short8 aa = *(const short8*)(&h0[lr * 256 + us * 8]);
#pragma unroll
        for (int nt = 0; nt < 4; ++nt) {
            short8 bb = *(const short8*)(WT1 + (nt * 16 + lr) * 256 + ks * 32 + lk * 8);
            acc1[nt] = mfma_bf16(aa, bb, acc1[nt]);
        }
    }
    unsigned short* h1 = &H1[wave][0];
#pragma unroll
    for (int nt = 0; nt < 4; ++nt) {
        int col = nt * 16 + lr;
        float bias = b1[col];
#pragma unroll
        for (int j = 0; j < 4; ++j) {
            int row = lk * 4 + j;
            h1[row * 72 + col] = f2bf(gelu_f(acc1[nt][j] + bias));
        }
    }
    int task = lane >> 1;
    int row = task >> 1;
    int o = task & 1;
    int t2 = lane & 1;
    float p = 0.0f;
#pragma unroll
    for (int d = 0; d < 32; ++d) {
        int dd = t2 * 32 + d;
        p += bf2f(h1[row * 72 + dd]) * W2[dd * 2 + o];
    }
    p += __shfl_xor(p, 1, 64);
    if (t2 == 0) {
        int gg = n0 + rb + row;
        if (o == 0) out[gg] = p + b2[0];
        else        out[BB * NT + gg] = __expf(0.5f * (p + b2[1]));
    }
}

extern "C" void kernel_launch(void* const* d_in, const int* in_sizes, int n_in,
                              void* d_out, int out_size, void* d_ws, size_t ws_size,
                              hipStream_t stream)
{
    (void)in_sizes; (void)n_in; (void)out_size; (void)ws_size;
    const float* s_ctx   = (const float*)d_in[0];
    const float* f_ctx   = (const float*)d_in[1];
    const float* s_test  = (const float*)d_in[2];
    const int*   valid   = (const int*)d_in[3];
    const float* emb_obs = (const float*)d_in[4];
    const float* ea_W0   = (const float*)d_in[5];
    const float* ea_b0   = (const float*)d_in[6];
    const float* ea_W1   = (const float*)d_in[7];
    const float* ea_b1   = (const float*)d_in[8];
    const float* ea_W2   = (const float*)d_in[9];
    const float* ea_b2   = (const float*)d_in[10];
    const float* ln_g    = (const float*)d_in[11];
    const float* ln_b    = (const float*)d_in[12];
    const float* blk_Wm0 = (const float*)d_in[13];
    const float* blk_bm0 = (const float*)d_in[14];
    const float* blk_Wm1 = (const float*)d_in[15];
    const float* blk_bm1 = (const float*)d_in[16];
    const float* blk_Wu0 = (const float*)d_in[17];
    const float* blk_bu0 = (const float*)d_in[18];
    const float* blk_Wu1 = (const float*)d_in[19];
    const float* blk_bu1 = (const float*)d_in[20];
    const float* blk_lng = (const float*)d_in[21];
    const float* blk_lnb = (const float*)d_in[22];
    const float* hd_W0   = (const float*)d_in[23];
    const float* hd_b0   = (const float*)d_in[24];
    const float* hd_W1   = (const float*)d_in[25];
    const float* hd_b1   = (const float*)d_in[26];
    const float* hd_W2   = (const float*)d_in[27];
    const float* hd_b2   = (const float*)d_in[28];

    char* p = (char*)d_ws;
    auto alloc = [&](size_t bytes) { char* r = p; p += (bytes + 255) & ~(size_t)255; return r; };
    unsigned short* nodesA = (unsigned short*)alloc((size_t)NODES * 64 * 2);
    unsigned short* nodesB = (unsigned short*)alloc((size_t)NODES * 64 * 2);
    unsigned short* Pbuf   = (unsigned short*)alloc((size_t)NODES * 128 * 2);
    float* dists   = (float*)alloc((size_t)NODES * KNN * 4);
    float* wbuf    = (float*)alloc((size_t)NODES * KNN * 4);
    int*   senders = (int*)alloc((size_t)NODES * KNN * 4);
    unsigned short* wtm0  = (unsigned short*)alloc((size_t)6 * 8192 * 2);
    unsigned short* wtm1p = (unsigned short*)alloc((size_t)6 * 8192 * 2);
    unsigned short* wtu0  = (unsigned short*)alloc((size_t)6 * 16384 * 2);
    unsigned short* wtu1  = (unsigned short*)alloc((size_t)6 * 8192 * 2);
    float* wdp  = (float*)alloc((size_t)6 * 128 * 4);
    float* bm0p = (float*)alloc((size_t)6 * 128 * 4);
    unsigned short* wte0 = (unsigned short*)alloc((size_t)8192 * 2);
    unsigned short* wte1 = (unsigned short*)alloc((size_t)32768 * 2);
    unsigned short* wte2 = (unsigned short*)alloc((size_t)8192 * 2);
    unsigned short* wth0 = (unsigned short*)alloc((size_t)16384 * 2);
    unsigned short* wth1 = (unsigned short*)alloc((size_t)16384 * 2);
    float4* s4 = (float4*)alloc((size_t)BB * NC * 16);

    k_convw<<<1350, 256, 0, stream>>>(
        blk_Wm0, blk_Wm1, blk_Wu0, blk_Wu1, blk_bm0,
        ea_W0, ea_W1, ea_W2, hd_W0, hd_W1, s_ctx,
        wtm0, wtm1p, wtu0, wtu1, wdp, bm0p, wte0, wte1, wte2, wth0, wth1, s4);

    k_embed2<<<NODES / 64, 256, 0, stream>>>(s_ctx, f_ctx, s_test, emb_obs,
        wte0, ea_b0, wte1, ea_b1, wte2, ea_b2, ln_g, ln_b, wtm0, nodesA, Pbuf);

    k_topk<<<NODES / 16, 256, 0, stream>>>(s4, s_ctx, s_test, valid,
                                           dists, senders, wbuf);

    unsigned short* nin = nodesA; unsigned short* nout = nodesB;
    for (int i = 0; i < NBLK; ++i) {
        int doP = (i < NBLK - 1) ? 1 : 0;
        const unsigned short* wm0n = wtm0 + (size_t)((i + 1) % NBLK) * 8192;
        k_blk<<<NODES / 16, 256, 0, stream>>>(nin, Pbuf, dists, senders, wbuf,
            wdp + (size_t)i * 128, bm0p + (size_t)i * 128,
            wtm1p + (size_t)i * 8192, blk_bm1 + (size_t)i * 64,
            wtu0 + (size_t)i * 16384, blk_bu0 + (size_t)i * 128,
            wtu1 + (size_t)i * 8192, blk_bu1 + (size_t)i * 64,
            blk_lng + (size_t)i * 64, blk_lnb + (size_t)i * 64,
            wm0n, doP, nout, Pbuf);
        unsigned short* tmp = nin; nin = nout; nout = tmp;
    }

    k_head2<<<BB * NT / 64, 256, 0, stream>>>(nin, wth0, hd_b0, wth1, hd_b1,
                                              hd_W2, hd_b2, (float*)d_out);
}